// Round 1
// baseline (6047.551 us; speedup 1.0000x reference)
//
#include <hip/hip_runtime.h>

#define HH 64

// ---------- prep: transposes + fused Wvo = Wo@Wv, bvo = Wo@bv + bo ----------
__global__ __launch_bounds__(256) void k_prep(
    const float* __restrict__ Wattn, const float* __restrict__ Wg1,
    const float* __restrict__ Wnh,   const float* __restrict__ Wo,
    const float* __restrict__ Wv,    const float* __restrict__ bv,
    const float* __restrict__ bo,
    float* __restrict__ WattnT, float* __restrict__ Wg1T,
    float* __restrict__ WnhT,   float* __restrict__ Wvo,
    float* __restrict__ bvo)
{
  int idx = blockIdx.x * 256 + threadIdx.x;
  if (idx < 64 * 128) {            // WattnT[128][64] <- Wattn[64][128]
    int j = idx >> 7, k = idx & 127;
    WattnT[k * 64 + j] = Wattn[idx];
  }
  if (idx < 64 * 64) {             // Wg1T[64][64] <- Wg1[64][64]
    int j = idx >> 6, k = idx & 63;
    Wg1T[k * 64 + j] = Wg1[idx];
  }
  if (idx < 640) {                 // WnhT[64][10] <- Wnh[10][64]
    int c = idx >> 6, j = idx & 63;
    WnhT[j * 10 + c] = Wnh[idx];
  }
  if (idx < 4096) {                // Wvo[j][k] = sum_l Wo[j][l] Wv[l][k]
    int j = idx >> 6, k = idx & 63;
    float a = 0.f;
    #pragma unroll 4
    for (int l = 0; l < 64; ++l) a = fmaf(Wo[j * 64 + l], Wv[l * 64 + k], a);
    Wvo[idx] = a;
  }
  if (idx < 64) {                  // bvo[j] = sum_l Wo[j][l] bv[l] + bo[j]
    float a = bo[idx];
    for (int l = 0; l < 64; ++l) a = fmaf(Wo[idx * 64 + l], bv[l], a);
    bvo[idx] = a;
  }
}

// ---------- node init: nf = nl @ Wproj^T + bproj ; agg = nf ----------
__global__ __launch_bounds__(256) void k_node_init(
    const float* __restrict__ nl, const float* __restrict__ Wproj,
    const float* __restrict__ bproj, float* __restrict__ nf,
    float* __restrict__ agg, int N)
{
  int i = blockIdx.x * 256 + threadIdx.x;
  if (i >= N) return;
  float x[10];
  #pragma unroll
  for (int k = 0; k < 10; ++k) x[k] = nl[(size_t)i * 10 + k];
  const size_t ib = (size_t)i * HH;
  #pragma unroll 1
  for (int j = 0; j < HH; ++j) {
    float a = bproj[j];
    #pragma unroll
    for (int k = 0; k < 10; ++k) a = fmaf(x[k], Wproj[j * 10 + k], a);
    nf[ib + j]  = a;
    agg[ib + j] = a;
  }
}

// ---------- edge init: ef = relu(el @ We1^T + be1) @ We2^T + be2 ----------
__global__ __launch_bounds__(256) void k_edge_init(
    const float* __restrict__ el, const float* __restrict__ We1,
    const float* __restrict__ be1, const float* __restrict__ We2,
    const float* __restrict__ be2, float* __restrict__ ef, int E)
{
  int e = blockIdx.x * 256 + threadIdx.x;
  if (e >= E) return;
  float x0 = el[(size_t)e * 5 + 0], x1 = el[(size_t)e * 5 + 1],
        x2 = el[(size_t)e * 5 + 2], x3 = el[(size_t)e * 5 + 3],
        x4 = el[(size_t)e * 5 + 4];
  float t[HH];
  #pragma unroll
  for (int j = 0; j < HH; ++j) {
    float a = be1[j];
    a = fmaf(x0, We1[j * 5 + 0], a);
    a = fmaf(x1, We1[j * 5 + 1], a);
    a = fmaf(x2, We1[j * 5 + 2], a);
    a = fmaf(x3, We1[j * 5 + 3], a);
    a = fmaf(x4, We1[j * 5 + 4], a);
    t[j] = fmaxf(a, 0.f);
  }
  const size_t eb = (size_t)e * HH;
  #pragma unroll 1
  for (int j = 0; j < HH; ++j) {
    const float* wr = We2 + j * HH;
    float a0 = be2[j], a1 = 0.f, a2 = 0.f, a3 = 0.f;
    #pragma unroll
    for (int k = 0; k < HH; k += 4) {
      a0 = fmaf(t[k    ], wr[k    ], a0);
      a1 = fmaf(t[k + 1], wr[k + 1], a1);
      a2 = fmaf(t[k + 2], wr[k + 2], a2);
      a3 = fmaf(t[k + 3], wr[k + 3], a3);
    }
    ef[eb + j] = (a0 + a1) + (a2 + a3);
  }
}

// ---------- per-iteration edge pipeline ----------
// c = WattnT^T @ [ns;nd] + battn ; msg = Wvo @ c + bvo
// ef' = relu(ef + msg) ; m = relu(ns + ef') -> atomicAdd agg[dst]
// LAST: also edge_out = ef' @ Weh^T + beh (and skip ef store)
template <bool LAST>
__global__ __launch_bounds__(256) void k_edge(
    const float* __restrict__ nf, float* __restrict__ ef,
    const int* __restrict__ ei,
    const float* __restrict__ WattnT, const float* __restrict__ battn,
    const float* __restrict__ Wvo, const float* __restrict__ bvo,
    const float* __restrict__ Weh, const float* __restrict__ beh,
    float* __restrict__ agg, float* __restrict__ edge_out,
    int N, int E)
{
  int e = blockIdx.x * 256 + threadIdx.x;
  if (e >= E) return;
  int src = ei[e];
  int dst = ei[(size_t)E + e];
  const float* ns = nf + (size_t)src * HH;
  const float* nd = nf + (size_t)dst * HH;

  float c[HH];
  #pragma unroll
  for (int j = 0; j < HH; ++j) c[j] = battn[j];

  #pragma unroll 1
  for (int k4 = 0; k4 < 16; ++k4) {
    float4 fs = *(const float4*)(ns + k4 * 4);
    float4 fd = *(const float4*)(nd + k4 * 4);
    const float* w0 = WattnT + (k4 * 4) * HH;
    const float* w1 = WattnT + (64 + k4 * 4) * HH;
    #pragma unroll
    for (int u = 0; u < 4; ++u) {
      float xs = (&fs.x)[u];
      float xd = (&fd.x)[u];
      #pragma unroll
      for (int j = 0; j < HH; ++j) {
        c[j] = fmaf(xs, w0[u * HH + j], c[j]);
        c[j] = fmaf(xd, w1[u * HH + j], c[j]);
      }
    }
  }

  float eo0 = 0.f, eo1 = 0.f, eo2 = 0.f, eo3 = 0.f, eo4 = 0.f;
  if (LAST) { eo0 = beh[0]; eo1 = beh[1]; eo2 = beh[2]; eo3 = beh[3]; eo4 = beh[4]; }

  const size_t eb = (size_t)e * HH;
  float* aggd = agg + (size_t)dst * HH;
  #pragma unroll 1
  for (int j = 0; j < HH; ++j) {
    const float* wr = Wvo + j * HH;
    float a0 = bvo[j], a1 = 0.f, a2 = 0.f, a3 = 0.f;
    #pragma unroll
    for (int k = 0; k < HH; k += 4) {
      a0 = fmaf(c[k    ], wr[k    ], a0);
      a1 = fmaf(c[k + 1], wr[k + 1], a1);
      a2 = fmaf(c[k + 2], wr[k + 2], a2);
      a3 = fmaf(c[k + 3], wr[k + 3], a3);
    }
    float msg = (a0 + a1) + (a2 + a3);
    float e1 = fmaxf(ef[eb + j] + msg, 0.f);   // GAMMA = 1
    if (!LAST) ef[eb + j] = e1;
    float m = fmaxf(ns[j] + e1, 0.f);
    atomicAdd(&aggd[j], m);
    if (LAST) {
      eo0 = fmaf(e1, Weh[0 * HH + j], eo0);
      eo1 = fmaf(e1, Weh[1 * HH + j], eo1);
      eo2 = fmaf(e1, Weh[2 * HH + j], eo2);
      eo3 = fmaf(e1, Weh[3 * HH + j], eo3);
      eo4 = fmaf(e1, Weh[4 * HH + j], eo4);
    }
  }
  if (LAST) {
    float* eout = edge_out + (size_t)e * 5;
    eout[0] = eo0; eout[1] = eo1; eout[2] = eo2; eout[3] = eo3; eout[4] = eo4;
  }
}

// ---------- node update: nf' = relu(relu(h@Wg1^T+bg1)@Wg2^T+bg2), h = agg ----------
// LAST: node_out = nf' @ Wnh^T + bnh instead of storing nf'
template <bool LAST>
__global__ __launch_bounds__(256) void k_node_update(
    const float* __restrict__ Wg1T, const float* __restrict__ bg1,
    const float* __restrict__ Wg2,  const float* __restrict__ bg2,
    const float* __restrict__ WnhT, const float* __restrict__ bnh,
    float* __restrict__ nf, float* __restrict__ agg,
    float* __restrict__ node_out, int N)
{
  int i = blockIdx.x * 256 + threadIdx.x;
  if (i >= N) return;
  const size_t ib = (size_t)i * HH;

  float t1[HH];
  #pragma unroll
  for (int j = 0; j < HH; ++j) t1[j] = bg1[j];

  #pragma unroll 1
  for (int k4 = 0; k4 < 16; ++k4) {
    float4 f = *(const float4*)(agg + ib + k4 * 4);
    #pragma unroll
    for (int u = 0; u < 4; ++u) {
      float x = (&f.x)[u];
      const float* wr = Wg1T + (k4 * 4 + u) * HH;
      #pragma unroll
      for (int j = 0; j < HH; ++j) t1[j] = fmaf(x, wr[j], t1[j]);
    }
  }
  #pragma unroll
  for (int j = 0; j < HH; ++j) t1[j] = fmaxf(t1[j], 0.f);

  float no[10];
  if (LAST) {
    #pragma unroll
    for (int cc = 0; cc < 10; ++cc) no[cc] = bnh[cc];
  }

  #pragma unroll 1
  for (int j = 0; j < HH; ++j) {
    const float* wr = Wg2 + j * HH;
    float a0 = bg2[j], a1 = 0.f, a2 = 0.f, a3 = 0.f;
    #pragma unroll
    for (int k = 0; k < HH; k += 4) {
      a0 = fmaf(t1[k    ], wr[k    ], a0);
      a1 = fmaf(t1[k + 1], wr[k + 1], a1);
      a2 = fmaf(t1[k + 2], wr[k + 2], a2);
      a3 = fmaf(t1[k + 3], wr[k + 3], a3);
    }
    float v = fmaxf((a0 + a1) + (a2 + a3), 0.f);
    if (!LAST) {
      nf[ib + j]  = v;
      agg[ib + j] = v;   // re-init agg = nf for next iteration
    } else {
      const float* wn = WnhT + j * 10;
      #pragma unroll
      for (int cc = 0; cc < 10; ++cc) no[cc] = fmaf(v, wn[cc], no[cc]);
    }
  }
  if (LAST) {
    #pragma unroll
    for (int cc = 0; cc < 10; ++cc) node_out[(size_t)i * 10 + cc] = no[cc];
  }
}

extern "C" void kernel_launch(void* const* d_in, const int* in_sizes, int n_in,
                              void* d_out, int out_size, void* d_ws, size_t ws_size,
                              hipStream_t stream)
{
  const float* node_logits = (const float*)d_in[0];
  const float* edge_logits = (const float*)d_in[1];
  const int*   ei          = (const int*)d_in[2];
  const float* Wproj = (const float*)d_in[3];
  const float* bproj = (const float*)d_in[4];
  const float* We1   = (const float*)d_in[5];
  const float* be1   = (const float*)d_in[6];
  const float* We2   = (const float*)d_in[7];
  const float* be2   = (const float*)d_in[8];
  const float* Wg1   = (const float*)d_in[9];
  const float* bg1   = (const float*)d_in[10];
  const float* Wg2   = (const float*)d_in[11];
  const float* bg2   = (const float*)d_in[12];
  const float* Wv    = (const float*)d_in[13];
  const float* bv    = (const float*)d_in[14];
  const float* Wo    = (const float*)d_in[15];
  const float* bo    = (const float*)d_in[16];
  const float* Wattn = (const float*)d_in[17];
  const float* battn = (const float*)d_in[18];
  const float* Wnh   = (const float*)d_in[19];
  const float* bnh   = (const float*)d_in[20];
  const float* Weh   = (const float*)d_in[21];
  const float* beh   = (const float*)d_in[22];

  const int N = in_sizes[0] / 10;
  const int E = in_sizes[1] / 5;

  float* ws = (float*)d_ws;
  size_t off = 0;
  float* nf     = ws + off; off += (size_t)N * HH;
  float* agg    = ws + off; off += (size_t)N * HH;
  float* WattnT = ws + off; off += 128 * 64;
  float* Wg1T   = ws + off; off += 64 * 64;
  float* WnhT   = ws + off; off += 640;
  float* Wvo    = ws + off; off += 64 * 64;
  float* bvo    = ws + off; off += 64;
  float* ef     = ws + off; off += (size_t)E * HH;

  float* node_out = (float*)d_out;
  float* edge_out = node_out + (size_t)N * 10;

  const int nb_n = (N + 255) / 256;
  const int nb_e = (E + 255) / 256;

  k_prep<<<32, 256, 0, stream>>>(Wattn, Wg1, Wnh, Wo, Wv, bv, bo,
                                 WattnT, Wg1T, WnhT, Wvo, bvo);
  k_node_init<<<nb_n, 256, 0, stream>>>(node_logits, Wproj, bproj, nf, agg, N);
  k_edge_init<<<nb_e, 256, 0, stream>>>(edge_logits, We1, be1, We2, be2, ef, E);

  // iteration 1
  k_edge<false><<<nb_e, 256, 0, stream>>>(nf, ef, ei, WattnT, battn, Wvo, bvo,
                                          Weh, beh, agg, edge_out, N, E);
  k_node_update<false><<<nb_n, 256, 0, stream>>>(Wg1T, bg1, Wg2, bg2, WnhT, bnh,
                                                 nf, agg, node_out, N);
  // iteration 2
  k_edge<true><<<nb_e, 256, 0, stream>>>(nf, ef, ei, WattnT, battn, Wvo, bvo,
                                         Weh, beh, agg, edge_out, N, E);
  k_node_update<true><<<nb_n, 256, 0, stream>>>(Wg1T, bg1, Wg2, bg2, WnhT, bnh,
                                                nf, agg, node_out, N);
}

// Round 2
// 1869.819 us; speedup vs baseline: 3.2343x; 3.2343x over previous
//
#include <hip/hip_runtime.h>

#define HH 64

// ---------- prep: transposes + fused Wvo = Wo@Wv, bvo = Wo@bv + bo ----------
__global__ __launch_bounds__(256) void k_prep(
    const float* __restrict__ Wattn, const float* __restrict__ Wg1,
    const float* __restrict__ Wnh,   const float* __restrict__ Wo,
    const float* __restrict__ Wv,    const float* __restrict__ bv,
    const float* __restrict__ bo,
    float* __restrict__ WattnT, float* __restrict__ Wg1T,
    float* __restrict__ WnhT,   float* __restrict__ Wvo,
    float* __restrict__ bvo)
{
  int idx = blockIdx.x * 256 + threadIdx.x;
  if (idx < 64 * 128) {            // WattnT[128][64] <- Wattn[64][128]
    int j = idx >> 7, k = idx & 127;
    WattnT[k * 64 + j] = Wattn[idx];
  }
  if (idx < 64 * 64) {             // Wg1T[64][64] <- Wg1[64][64]
    int j = idx >> 6, k = idx & 63;
    Wg1T[k * 64 + j] = Wg1[idx];
  }
  if (idx < 640) {                 // WnhT[64][10] <- Wnh[10][64]
    int c = idx >> 6, j = idx & 63;
    WnhT[j * 10 + c] = Wnh[idx];
  }
  if (idx < 4096) {                // Wvo[j][k] = sum_l Wo[j][l] Wv[l][k]
    int j = idx >> 6, k = idx & 63;
    float a = 0.f;
    #pragma unroll 4
    for (int l = 0; l < 64; ++l) a = fmaf(Wo[j * 64 + l], Wv[l * 64 + k], a);
    Wvo[idx] = a;
  }
  if (idx < 64) {                  // bvo[j] = sum_l Wo[j][l] bv[l] + bo[j]
    float a = bo[idx];
    for (int l = 0; l < 64; ++l) a = fmaf(Wo[idx * 64 + l], bv[l], a);
    bvo[idx] = a;
  }
}

// ---------- node init: nf = nl @ Wproj^T + bproj ----------
__global__ __launch_bounds__(256) void k_node_init(
    const float* __restrict__ nl, const float* __restrict__ Wproj,
    const float* __restrict__ bproj, float* __restrict__ nf, int N)
{
  int i = blockIdx.x * 256 + threadIdx.x;
  if (i >= N) return;
  float x[10];
  #pragma unroll
  for (int k = 0; k < 10; ++k) x[k] = nl[(size_t)i * 10 + k];
  const size_t ib = (size_t)i * HH;
  #pragma unroll 1
  for (int j = 0; j < HH; ++j) {
    float a = bproj[j];
    #pragma unroll
    for (int k = 0; k < 10; ++k) a = fmaf(x[k], Wproj[j * 10 + k], a);
    nf[ib + j] = a;
  }
}

// ---------- edge init: ef = relu(el @ We1^T + be1) @ We2^T + be2 ----------
__global__ __launch_bounds__(256) void k_edge_init(
    const float* __restrict__ el, const float* __restrict__ We1,
    const float* __restrict__ be1, const float* __restrict__ We2,
    const float* __restrict__ be2, float* __restrict__ ef, int E)
{
  int e = blockIdx.x * 256 + threadIdx.x;
  if (e >= E) return;
  float x0 = el[(size_t)e * 5 + 0], x1 = el[(size_t)e * 5 + 1],
        x2 = el[(size_t)e * 5 + 2], x3 = el[(size_t)e * 5 + 3],
        x4 = el[(size_t)e * 5 + 4];
  float t[HH];
  #pragma unroll
  for (int j = 0; j < HH; ++j) {
    float a = be1[j];
    a = fmaf(x0, We1[j * 5 + 0], a);
    a = fmaf(x1, We1[j * 5 + 1], a);
    a = fmaf(x2, We1[j * 5 + 2], a);
    a = fmaf(x3, We1[j * 5 + 3], a);
    a = fmaf(x4, We1[j * 5 + 4], a);
    t[j] = fmaxf(a, 0.f);
  }
  const size_t eb = (size_t)e * HH;
  #pragma unroll 1
  for (int j4 = 0; j4 < 16; ++j4) {
    float4 ov;
    #pragma unroll
    for (int u = 0; u < 4; ++u) {
      int j = j4 * 4 + u;
      const float* wr = We2 + j * HH;
      float a0 = be2[j], a1 = 0.f, a2 = 0.f, a3 = 0.f;
      #pragma unroll
      for (int k = 0; k < HH; k += 4) {
        a0 = fmaf(t[k    ], wr[k    ], a0);
        a1 = fmaf(t[k + 1], wr[k + 1], a1);
        a2 = fmaf(t[k + 2], wr[k + 2], a2);
        a3 = fmaf(t[k + 3], wr[k + 3], a3);
      }
      (&ov.x)[u] = (a0 + a1) + (a2 + a3);
    }
    *(float4*)(ef + eb + j4 * 4) = ov;
  }
}

// ---------- CSR build ----------
__global__ __launch_bounds__(256) void k_zero(int* __restrict__ p, int n)
{
  int i = blockIdx.x * 256 + threadIdx.x;
  if (i < n) p[i] = 0;
}

__global__ __launch_bounds__(256) void k_deg(
    const int* __restrict__ ei, int* __restrict__ deg, int E)
{
  int e = blockIdx.x * 256 + threadIdx.x;
  if (e >= E) return;
  atomicAdd(&deg[ei[(size_t)E + e]], 1);
}

__global__ __launch_bounds__(1024) void k_scan(
    const int* __restrict__ deg, int* __restrict__ rowptr,
    int* __restrict__ wofs, int N)
{
  __shared__ int part[1024];
  int t = threadIdx.x;
  int chunk = (N + 1023) / 1024;
  int lo = t * chunk;
  int hi = min(lo + chunk, N);
  int s = 0;
  for (int i = lo; i < hi; ++i) s += deg[i];
  part[t] = s;
  __syncthreads();
  for (int off = 1; off < 1024; off <<= 1) {
    int v = (t >= off) ? part[t - off] : 0;
    __syncthreads();
    part[t] += v;
    __syncthreads();
  }
  int base = (t == 0) ? 0 : part[t - 1];
  for (int i = lo; i < hi; ++i) {
    rowptr[i] = base;
    wofs[i]   = base;
    base += deg[i];
  }
  if (t == 1023) rowptr[N] = part[1023];
}

__global__ __launch_bounds__(256) void k_scatter(
    const int* __restrict__ ei, int* __restrict__ wofs,
    int* __restrict__ eidx, int E)
{
  int e = blockIdx.x * 256 + threadIdx.x;
  if (e >= E) return;
  int pos = atomicAdd(&wofs[ei[(size_t)E + e]], 1);
  eidx[pos] = e;
}

// ---------- per-iteration edge pipeline (no atomics) ----------
// c = WattnT^T @ [ns;nd] + battn ; msg = Wvo @ c + bvo
// ef' = relu(ef + msg) stored in place
// LAST: also edge_out = ef' @ Weh^T + beh
template <bool LAST>
__global__ __launch_bounds__(256) void k_edge(
    const float* __restrict__ nf, float* __restrict__ ef,
    const int* __restrict__ ei,
    const float* __restrict__ WattnT, const float* __restrict__ battn,
    const float* __restrict__ Wvo, const float* __restrict__ bvo,
    const float* __restrict__ Weh, const float* __restrict__ beh,
    float* __restrict__ edge_out, int N, int E)
{
  int e = blockIdx.x * 256 + threadIdx.x;
  if (e >= E) return;
  int src = ei[e];
  int dst = ei[(size_t)E + e];
  const float* ns = nf + (size_t)src * HH;
  const float* nd = nf + (size_t)dst * HH;

  float c[HH];
  #pragma unroll
  for (int j = 0; j < HH; ++j) c[j] = battn[j];

  #pragma unroll 1
  for (int k4 = 0; k4 < 16; ++k4) {
    float4 fs = *(const float4*)(ns + k4 * 4);
    float4 fd = *(const float4*)(nd + k4 * 4);
    const float* w0 = WattnT + (k4 * 4) * HH;
    const float* w1 = WattnT + (64 + k4 * 4) * HH;
    #pragma unroll
    for (int u = 0; u < 4; ++u) {
      float xs = (&fs.x)[u];
      float xd = (&fd.x)[u];
      #pragma unroll
      for (int j = 0; j < HH; ++j) {
        c[j] = fmaf(xs, w0[u * HH + j], c[j]);
        c[j] = fmaf(xd, w1[u * HH + j], c[j]);
      }
    }
  }

  float eo0 = 0.f, eo1 = 0.f, eo2 = 0.f, eo3 = 0.f, eo4 = 0.f;
  if (LAST) { eo0 = beh[0]; eo1 = beh[1]; eo2 = beh[2]; eo3 = beh[3]; eo4 = beh[4]; }

  const size_t eb = (size_t)e * HH;
  #pragma unroll 1
  for (int j4 = 0; j4 < 16; ++j4) {
    float4 efv = *(const float4*)(ef + eb + j4 * 4);
    float4 ov;
    #pragma unroll
    for (int u = 0; u < 4; ++u) {
      int j = j4 * 4 + u;
      const float* wr = Wvo + j * HH;
      float a0 = bvo[j], a1 = 0.f, a2 = 0.f, a3 = 0.f;
      #pragma unroll
      for (int k = 0; k < HH; k += 4) {
        a0 = fmaf(c[k    ], wr[k    ], a0);
        a1 = fmaf(c[k + 1], wr[k + 1], a1);
        a2 = fmaf(c[k + 2], wr[k + 2], a2);
        a3 = fmaf(c[k + 3], wr[k + 3], a3);
      }
      float msg = (a0 + a1) + (a2 + a3);
      float e1 = fmaxf((&efv.x)[u] + msg, 0.f);   // GAMMA = 1
      (&ov.x)[u] = e1;
      if (LAST) {
        eo0 = fmaf(e1, Weh[0 * HH + j], eo0);
        eo1 = fmaf(e1, Weh[1 * HH + j], eo1);
        eo2 = fmaf(e1, Weh[2 * HH + j], eo2);
        eo3 = fmaf(e1, Weh[3 * HH + j], eo3);
        eo4 = fmaf(e1, Weh[4 * HH + j], eo4);
      }
    }
    *(float4*)(ef + eb + j4 * 4) = ov;
  }
  if (LAST) {
    float* eout = edge_out + (size_t)e * 5;
    eout[0] = eo0; eout[1] = eo1; eout[2] = eo2; eout[3] = eo3; eout[4] = eo4;
  }
}

// ---------- node aggregation via CSR gather: agg[i] = nf[i] + sum relu(nf[src]+ef) ----------
// 16 lanes per node, float4 per lane -> fully coalesced 256B row reads
__global__ __launch_bounds__(256) void k_node_agg(
    const float* __restrict__ nf, const float* __restrict__ ef,
    const int* __restrict__ ei, const int* __restrict__ rowptr,
    const int* __restrict__ eidx, float* __restrict__ agg, int N, int E)
{
  int gid = blockIdx.x * 256 + threadIdx.x;
  int i = gid >> 4;
  int l = gid & 15;
  if (i >= N) return;
  int b = rowptr[i];
  int t = rowptr[i + 1];
  const size_t ib = (size_t)i * HH + l * 4;
  float4 h = *(const float4*)(nf + ib);
  for (int p = b; p < t; ++p) {
    int e = eidx[p];
    int src = ei[e];
    float4 efv = *(const float4*)(ef + (size_t)e * HH + l * 4);
    float4 nsv = *(const float4*)(nf + (size_t)src * HH + l * 4);
    h.x += fmaxf(nsv.x + efv.x, 0.f);
    h.y += fmaxf(nsv.y + efv.y, 0.f);
    h.z += fmaxf(nsv.z + efv.z, 0.f);
    h.w += fmaxf(nsv.w + efv.w, 0.f);
  }
  *(float4*)(agg + ib) = h;
}

// ---------- node update: nf' = relu(relu(agg@Wg1^T+bg1)@Wg2^T+bg2) ----------
// LAST: node_out = nf' @ Wnh^T + bnh instead of storing nf'
template <bool LAST>
__global__ __launch_bounds__(256) void k_node_update(
    const float* __restrict__ Wg1T, const float* __restrict__ bg1,
    const float* __restrict__ Wg2,  const float* __restrict__ bg2,
    const float* __restrict__ WnhT, const float* __restrict__ bnh,
    float* __restrict__ nf, const float* __restrict__ agg,
    float* __restrict__ node_out, int N)
{
  int i = blockIdx.x * 256 + threadIdx.x;
  if (i >= N) return;
  const size_t ib = (size_t)i * HH;

  float t1[HH];
  #pragma unroll
  for (int j = 0; j < HH; ++j) t1[j] = bg1[j];

  #pragma unroll 1
  for (int k4 = 0; k4 < 16; ++k4) {
    float4 f = *(const float4*)(agg + ib + k4 * 4);
    #pragma unroll
    for (int u = 0; u < 4; ++u) {
      float x = (&f.x)[u];
      const float* wr = Wg1T + (k4 * 4 + u) * HH;
      #pragma unroll
      for (int j = 0; j < HH; ++j) t1[j] = fmaf(x, wr[j], t1[j]);
    }
  }
  #pragma unroll
  for (int j = 0; j < HH; ++j) t1[j] = fmaxf(t1[j], 0.f);

  float no[10];
  if (LAST) {
    #pragma unroll
    for (int cc = 0; cc < 10; ++cc) no[cc] = bnh[cc];
  }

  #pragma unroll 1
  for (int j4 = 0; j4 < 16; ++j4) {
    float4 ov;
    #pragma unroll
    for (int u = 0; u < 4; ++u) {
      int j = j4 * 4 + u;
      const float* wr = Wg2 + j * HH;
      float a0 = bg2[j], a1 = 0.f, a2 = 0.f, a3 = 0.f;
      #pragma unroll
      for (int k = 0; k < HH; k += 4) {
        a0 = fmaf(t1[k    ], wr[k    ], a0);
        a1 = fmaf(t1[k + 1], wr[k + 1], a1);
        a2 = fmaf(t1[k + 2], wr[k + 2], a2);
        a3 = fmaf(t1[k + 3], wr[k + 3], a3);
      }
      float v = fmaxf((a0 + a1) + (a2 + a3), 0.f);
      (&ov.x)[u] = v;
      if (LAST) {
        const float* wn = WnhT + j * 10;
        #pragma unroll
        for (int cc = 0; cc < 10; ++cc) no[cc] = fmaf(v, wn[cc], no[cc]);
      }
    }
    if (!LAST) *(float4*)(nf + ib + j4 * 4) = ov;
  }
  if (LAST) {
    #pragma unroll
    for (int cc = 0; cc < 10; ++cc) node_out[(size_t)i * 10 + cc] = no[cc];
  }
}

extern "C" void kernel_launch(void* const* d_in, const int* in_sizes, int n_in,
                              void* d_out, int out_size, void* d_ws, size_t ws_size,
                              hipStream_t stream)
{
  const float* node_logits = (const float*)d_in[0];
  const float* edge_logits = (const float*)d_in[1];
  const int*   ei          = (const int*)d_in[2];
  const float* Wproj = (const float*)d_in[3];
  const float* bproj = (const float*)d_in[4];
  const float* We1   = (const float*)d_in[5];
  const float* be1   = (const float*)d_in[6];
  const float* We2   = (const float*)d_in[7];
  const float* be2   = (const float*)d_in[8];
  const float* Wg1   = (const float*)d_in[9];
  const float* bg1   = (const float*)d_in[10];
  const float* Wg2   = (const float*)d_in[11];
  const float* bg2   = (const float*)d_in[12];
  const float* Wv    = (const float*)d_in[13];
  const float* bv    = (const float*)d_in[14];
  const float* Wo    = (const float*)d_in[15];
  const float* bo    = (const float*)d_in[16];
  const float* Wattn = (const float*)d_in[17];
  const float* battn = (const float*)d_in[18];
  const float* Wnh   = (const float*)d_in[19];
  const float* bnh   = (const float*)d_in[20];
  const float* Weh   = (const float*)d_in[21];
  const float* beh   = (const float*)d_in[22];

  const int N = in_sizes[0] / 10;
  const int E = in_sizes[1] / 5;

  float* ws = (float*)d_ws;
  size_t off = 0;
  float* nf     = ws + off; off += (size_t)N * HH;
  float* agg    = ws + off; off += (size_t)N * HH;
  float* WattnT = ws + off; off += 128 * 64;
  float* Wg1T   = ws + off; off += 64 * 64;
  float* WnhT   = ws + off; off += 640;
  float* Wvo    = ws + off; off += 64 * 64;
  float* bvo    = ws + off; off += 64;
  float* ef     = ws + off; off += (size_t)E * HH;
  int* deg    = (int*)(ws + off); off += N;
  int* rowptr = (int*)(ws + off); off += N + 1;
  int* wofs   = (int*)(ws + off); off += N;
  int* eidx   = (int*)(ws + off); off += E;

  float* node_out = (float*)d_out;
  float* edge_out = node_out + (size_t)N * 10;

  const int nb_n = (N + 255) / 256;
  const int nb_e = (E + 255) / 256;
  const int nb_a = ((N * 16) + 255) / 256;

  // prep + CSR build (graph topology is per-call recomputed, deterministic work)
  k_prep<<<32, 256, 0, stream>>>(Wattn, Wg1, Wnh, Wo, Wv, bv, bo,
                                 WattnT, Wg1T, WnhT, Wvo, bvo);
  k_zero<<<nb_n, 256, 0, stream>>>(deg, N);
  k_node_init<<<nb_n, 256, 0, stream>>>(node_logits, Wproj, bproj, nf, N);
  k_edge_init<<<nb_e, 256, 0, stream>>>(edge_logits, We1, be1, We2, be2, ef, E);
  k_deg<<<nb_e, 256, 0, stream>>>(ei, deg, E);
  k_scan<<<1, 1024, 0, stream>>>(deg, rowptr, wofs, N);
  k_scatter<<<nb_e, 256, 0, stream>>>(ei, wofs, eidx, E);

  // iteration 1
  k_edge<false><<<nb_e, 256, 0, stream>>>(nf, ef, ei, WattnT, battn, Wvo, bvo,
                                          Weh, beh, edge_out, N, E);
  k_node_agg<<<nb_a, 256, 0, stream>>>(nf, ef, ei, rowptr, eidx, agg, N, E);
  k_node_update<false><<<nb_n, 256, 0, stream>>>(Wg1T, bg1, Wg2, bg2, WnhT, bnh,
                                                 nf, agg, node_out, N);
  // iteration 2
  k_edge<true><<<nb_e, 256, 0, stream>>>(nf, ef, ei, WattnT, battn, Wvo, bvo,
                                         Weh, beh, edge_out, N, E);
  k_node_agg<<<nb_a, 256, 0, stream>>>(nf, ef, ei, rowptr, eidx, agg, N, E);
  k_node_update<true><<<nb_n, 256, 0, stream>>>(Wg1T, bg1, Wg2, bg2, WnhT, bnh,
                                                nf, agg, node_out, N);
}

// Round 3
// 1851.162 us; speedup vs baseline: 3.2669x; 1.0101x over previous
//
#include <hip/hip_runtime.h>

#define HH 64

// ---------- prep: transposes + fused Wvo = Wo@Wv, bvo = Wo@bv + bo ----------
__global__ __launch_bounds__(256) void k_prep(
    const float* __restrict__ Wattn, const float* __restrict__ Wg1,
    const float* __restrict__ Wnh,   const float* __restrict__ Wo,
    const float* __restrict__ Wv,    const float* __restrict__ bv,
    const float* __restrict__ bo,
    float* __restrict__ WattnT, float* __restrict__ Wg1T,
    float* __restrict__ WnhT,   float* __restrict__ Wvo,
    float* __restrict__ bvo)
{
  int idx = blockIdx.x * 256 + threadIdx.x;
  if (idx < 64 * 128) {            // WattnT[128][64] <- Wattn[64][128]
    int j = idx >> 7, k = idx & 127;
    WattnT[k * 64 + j] = Wattn[idx];
  }
  if (idx < 64 * 64) {             // Wg1T[64][64] <- Wg1[64][64]
    int j = idx >> 6, k = idx & 63;
    Wg1T[k * 64 + j] = Wg1[idx];
  }
  if (idx < 640) {                 // WnhT[64][10] <- Wnh[10][64]
    int c = idx >> 6, j = idx & 63;
    WnhT[j * 10 + c] = Wnh[idx];
  }
  if (idx < 4096) {                // Wvo[j][k] = sum_l Wo[j][l] Wv[l][k]
    int j = idx >> 6, k = idx & 63;
    float a = 0.f;
    #pragma unroll 4
    for (int l = 0; l < 64; ++l) a = fmaf(Wo[j * 64 + l], Wv[l * 64 + k], a);
    Wvo[idx] = a;
  }
  if (idx < 64) {                  // bvo[j] = sum_l Wo[j][l] bv[l] + bo[j]
    float a = bo[idx];
    for (int l = 0; l < 64; ++l) a = fmaf(Wo[idx * 64 + l], bv[l], a);
    bvo[idx] = a;
  }
}

// ---------- node init: nf = nl @ Wproj^T + bproj ----------
__global__ __launch_bounds__(256) void k_node_init(
    const float* __restrict__ nl, const float* __restrict__ Wproj,
    const float* __restrict__ bproj, float* __restrict__ nf, int N)
{
  int i = blockIdx.x * 256 + threadIdx.x;
  if (i >= N) return;
  float x[10];
  #pragma unroll
  for (int k = 0; k < 10; ++k) x[k] = nl[(size_t)i * 10 + k];
  const size_t ib = (size_t)i * HH;
  #pragma unroll 1
  for (int j = 0; j < HH; ++j) {
    float a = bproj[j];
    #pragma unroll
    for (int k = 0; k < 10; ++k) a = fmaf(x[k], Wproj[j * 10 + k], a);
    nf[ib + j] = a;
  }
}

// ---------- edge init: ef = relu(el @ We1^T + be1) @ We2^T + be2 ----------
__global__ __launch_bounds__(256) void k_edge_init(
    const float* __restrict__ el, const float* __restrict__ We1,
    const float* __restrict__ be1, const float* __restrict__ We2,
    const float* __restrict__ be2, float* __restrict__ ef, int E)
{
  int e = blockIdx.x * 256 + threadIdx.x;
  if (e >= E) return;
  float x0 = el[(size_t)e * 5 + 0], x1 = el[(size_t)e * 5 + 1],
        x2 = el[(size_t)e * 5 + 2], x3 = el[(size_t)e * 5 + 3],
        x4 = el[(size_t)e * 5 + 4];
  float t[HH];
  #pragma unroll
  for (int j = 0; j < HH; ++j) {
    float a = be1[j];
    a = fmaf(x0, We1[j * 5 + 0], a);
    a = fmaf(x1, We1[j * 5 + 1], a);
    a = fmaf(x2, We1[j * 5 + 2], a);
    a = fmaf(x3, We1[j * 5 + 3], a);
    a = fmaf(x4, We1[j * 5 + 4], a);
    t[j] = fmaxf(a, 0.f);
  }
  const size_t eb = (size_t)e * HH;
  #pragma unroll 1
  for (int j4 = 0; j4 < 16; ++j4) {
    float4 ov;
    #pragma unroll
    for (int u = 0; u < 4; ++u) {
      int j = j4 * 4 + u;
      const float* wr = We2 + j * HH;
      float a0 = be2[j], a1 = 0.f, a2 = 0.f, a3 = 0.f;
      #pragma unroll
      for (int k = 0; k < HH; k += 4) {
        a0 = fmaf(t[k    ], wr[k    ], a0);
        a1 = fmaf(t[k + 1], wr[k + 1], a1);
        a2 = fmaf(t[k + 2], wr[k + 2], a2);
        a3 = fmaf(t[k + 3], wr[k + 3], a3);
      }
      (&ov.x)[u] = (a0 + a1) + (a2 + a3);
    }
    *(float4*)(ef + eb + j4 * 4) = ov;
  }
}

// ---------- CSR build ----------
__global__ __launch_bounds__(256) void k_zero(int* __restrict__ p, int n)
{
  int i = blockIdx.x * 256 + threadIdx.x;
  if (i < n) p[i] = 0;
}

__global__ __launch_bounds__(256) void k_deg(
    const int* __restrict__ ei, int* __restrict__ deg, int E)
{
  int e = blockIdx.x * 256 + threadIdx.x;
  if (e >= E) return;
  atomicAdd(&deg[ei[(size_t)E + e]], 1);
}

__global__ __launch_bounds__(1024) void k_scan(
    const int* __restrict__ deg, int* __restrict__ rowptr,
    int* __restrict__ wofs, int N)
{
  __shared__ int part[1024];
  int t = threadIdx.x;
  int chunk = (N + 1023) / 1024;
  int lo = t * chunk;
  int hi = min(lo + chunk, N);
  int s = 0;
  for (int i = lo; i < hi; ++i) s += deg[i];
  part[t] = s;
  __syncthreads();
  for (int off = 1; off < 1024; off <<= 1) {
    int v = (t >= off) ? part[t - off] : 0;
    __syncthreads();
    part[t] += v;
    __syncthreads();
  }
  int base = (t == 0) ? 0 : part[t - 1];
  for (int i = lo; i < hi; ++i) {
    rowptr[i] = base;
    wofs[i]   = base;
    base += deg[i];
  }
  if (t == 1023) rowptr[N] = part[1023];
}

__global__ __launch_bounds__(256) void k_scatter(
    const int* __restrict__ ei, int* __restrict__ wofs,
    int* __restrict__ eidx, int E)
{
  int e = blockIdx.x * 256 + threadIdx.x;
  if (e >= E) return;
  int pos = atomicAdd(&wofs[ei[(size_t)E + e]], 1);
  eidx[pos] = e;
}

// ---------- per-iteration edge pipeline (no atomics) ----------
// c = WattnT^T @ [ns;nd] + battn ; msg = Wvo @ c + bvo
// ef' = relu(ef + msg) stored in place
// LAST: also edge_out = ef' @ Weh^T + beh
template <bool LAST>
__global__ __launch_bounds__(256) void k_edge(
    const float* __restrict__ nf, float* __restrict__ ef,
    const int* __restrict__ ei,
    const float* __restrict__ WattnT, const float* __restrict__ battn,
    const float* __restrict__ Wvo, const float* __restrict__ bvo,
    const float* __restrict__ Weh, const float* __restrict__ beh,
    float* __restrict__ edge_out, int N, int E)
{
  int e = blockIdx.x * 256 + threadIdx.x;
  if (e >= E) return;
  int src = ei[e];
  int dst = ei[(size_t)E + e];
  const float* ns = nf + (size_t)src * HH;
  const float* nd = nf + (size_t)dst * HH;

  float c[HH];
  #pragma unroll
  for (int j = 0; j < HH; ++j) c[j] = battn[j];

  #pragma unroll 1
  for (int k4 = 0; k4 < 16; ++k4) {
    float4 fs = *(const float4*)(ns + k4 * 4);
    float4 fd = *(const float4*)(nd + k4 * 4);
    const float* w0 = WattnT + (k4 * 4) * HH;
    const float* w1 = WattnT + (64 + k4 * 4) * HH;
    #pragma unroll
    for (int u = 0; u < 4; ++u) {
      float xs = (&fs.x)[u];
      float xd = (&fd.x)[u];
      #pragma unroll
      for (int j = 0; j < HH; ++j) {
        c[j] = fmaf(xs, w0[u * HH + j], c[j]);
        c[j] = fmaf(xd, w1[u * HH + j], c[j]);
      }
    }
  }

  float eo0 = 0.f, eo1 = 0.f, eo2 = 0.f, eo3 = 0.f, eo4 = 0.f;
  if (LAST) { eo0 = beh[0]; eo1 = beh[1]; eo2 = beh[2]; eo3 = beh[3]; eo4 = beh[4]; }

  const size_t eb = (size_t)e * HH;
  #pragma unroll 1
  for (int j4 = 0; j4 < 16; ++j4) {
    float4 efv = *(const float4*)(ef + eb + j4 * 4);
    float4 ov;
    #pragma unroll
    for (int u = 0; u < 4; ++u) {
      int j = j4 * 4 + u;
      const float* wr = Wvo + j * HH;
      float a0 = bvo[j], a1 = 0.f, a2 = 0.f, a3 = 0.f;
      #pragma unroll
      for (int k = 0; k < HH; k += 4) {
        a0 = fmaf(c[k    ], wr[k    ], a0);
        a1 = fmaf(c[k + 1], wr[k + 1], a1);
        a2 = fmaf(c[k + 2], wr[k + 2], a2);
        a3 = fmaf(c[k + 3], wr[k + 3], a3);
      }
      float msg = (a0 + a1) + (a2 + a3);
      float e1 = fmaxf((&efv.x)[u] + msg, 0.f);   // GAMMA = 1
      (&ov.x)[u] = e1;
      if (LAST) {
        eo0 = fmaf(e1, Weh[0 * HH + j], eo0);
        eo1 = fmaf(e1, Weh[1 * HH + j], eo1);
        eo2 = fmaf(e1, Weh[2 * HH + j], eo2);
        eo3 = fmaf(e1, Weh[3 * HH + j], eo3);
        eo4 = fmaf(e1, Weh[4 * HH + j], eo4);
      }
    }
    *(float4*)(ef + eb + j4 * 4) = ov;
  }
  if (LAST) {
    float* eout = edge_out + (size_t)e * 5;
    eout[0] = eo0; eout[1] = eo1; eout[2] = eo2; eout[3] = eo3; eout[4] = eo4;
  }
}

// ---------- node aggregation via CSR gather: agg[i] = nf[i] + sum relu(nf[src]+ef) ----------
// 16 lanes per node, float4 per lane -> fully coalesced 256B row reads
__global__ __launch_bounds__(256) void k_node_agg(
    const float* __restrict__ nf, const float* __restrict__ ef,
    const int* __restrict__ ei, const int* __restrict__ rowptr,
    const int* __restrict__ eidx, float* __restrict__ agg, int N, int E)
{
  int gid = blockIdx.x * 256 + threadIdx.x;
  int i = gid >> 4;
  int l = gid & 15;
  if (i >= N) return;
  int b = rowptr[i];
  int t = rowptr[i + 1];
  const size_t ib = (size_t)i * HH + l * 4;
  float4 h = *(const float4*)(nf + ib);
  for (int p = b; p < t; ++p) {
    int e = eidx[p];
    int src = ei[e];
    float4 efv = *(const float4*)(ef + (size_t)e * HH + l * 4);
    float4 nsv = *(const float4*)(nf + (size_t)src * HH + l * 4);
    h.x += fmaxf(nsv.x + efv.x, 0.f);
    h.y += fmaxf(nsv.y + efv.y, 0.f);
    h.z += fmaxf(nsv.z + efv.z, 0.f);
    h.w += fmaxf(nsv.w + efv.w, 0.f);
  }
  *(float4*)(agg + ib) = h;
}

// ---------- node update: nf' = relu(relu(agg@Wg1^T+bg1)@Wg2^T+bg2) ----------
// LAST: node_out = nf' @ Wnh^T + bnh instead of storing nf'
template <bool LAST>
__global__ __launch_bounds__(256) void k_node_update(
    const float* __restrict__ Wg1T, const float* __restrict__ bg1,
    const float* __restrict__ Wg2,  const float* __restrict__ bg2,
    const float* __restrict__ WnhT, const float* __restrict__ bnh,
    float* __restrict__ nf, const float* __restrict__ agg,
    float* __restrict__ node_out, int N)
{
  int i = blockIdx.x * 256 + threadIdx.x;
  if (i >= N) return;
  const size_t ib = (size_t)i * HH;

  float t1[HH];
  #pragma unroll
  for (int j = 0; j < HH; ++j) t1[j] = bg1[j];

  #pragma unroll 1
  for (int k4 = 0; k4 < 16; ++k4) {
    float4 f = *(const float4*)(agg + ib + k4 * 4);
    #pragma unroll
    for (int u = 0; u < 4; ++u) {
      float x = (&f.x)[u];
      const float* wr = Wg1T + (k4 * 4 + u) * HH;
      #pragma unroll
      for (int j = 0; j < HH; ++j) t1[j] = fmaf(x, wr[j], t1[j]);
    }
  }
  #pragma unroll
  for (int j = 0; j < HH; ++j) t1[j] = fmaxf(t1[j], 0.f);

  float no[10];
  if (LAST) {
    #pragma unroll
    for (int cc = 0; cc < 10; ++cc) no[cc] = bnh[cc];
  }

  #pragma unroll 1
  for (int j4 = 0; j4 < 16; ++j4) {
    float4 ov;
    #pragma unroll
    for (int u = 0; u < 4; ++u) {
      int j = j4 * 4 + u;
      const float* wr = Wg2 + j * HH;
      float a0 = bg2[j], a1 = 0.f, a2 = 0.f, a3 = 0.f;
      #pragma unroll
      for (int k = 0; k < HH; k += 4) {
        a0 = fmaf(t1[k    ], wr[k    ], a0);
        a1 = fmaf(t1[k + 1], wr[k + 1], a1);
        a2 = fmaf(t1[k + 2], wr[k + 2], a2);
        a3 = fmaf(t1[k + 3], wr[k + 3], a3);
      }
      float v = fmaxf((a0 + a1) + (a2 + a3), 0.f);
      (&ov.x)[u] = v;
      if (LAST) {
        const float* wn = WnhT + j * 10;
        #pragma unroll
        for (int cc = 0; cc < 10; ++cc) no[cc] = fmaf(v, wn[cc], no[cc]);
      }
    }
    if (!LAST) *(float4*)(nf + ib + j4 * 4) = ov;
  }
  if (LAST) {
    #pragma unroll
    for (int cc = 0; cc < 10; ++cc) node_out[(size_t)i * 10 + cc] = no[cc];
  }
}

extern "C" void kernel_launch(void* const* d_in, const int* in_sizes, int n_in,
                              void* d_out, int out_size, void* d_ws, size_t ws_size,
                              hipStream_t stream)
{
  const float* node_logits = (const float*)d_in[0];
  const float* edge_logits = (const float*)d_in[1];
  const int*   ei          = (const int*)d_in[2];
  const float* Wproj = (const float*)d_in[3];
  const float* bproj = (const float*)d_in[4];
  const float* We1   = (const float*)d_in[5];
  const float* be1   = (const float*)d_in[6];
  const float* We2   = (const float*)d_in[7];
  const float* be2   = (const float*)d_in[8];
  const float* Wg1   = (const float*)d_in[9];
  const float* bg1   = (const float*)d_in[10];
  const float* Wg2   = (const float*)d_in[11];
  const float* bg2   = (const float*)d_in[12];
  const float* Wv    = (const float*)d_in[13];
  const float* bv    = (const float*)d_in[14];
  const float* Wo    = (const float*)d_in[15];
  const float* bo    = (const float*)d_in[16];
  const float* Wattn = (const float*)d_in[17];
  const float* battn = (const float*)d_in[18];
  const float* Wnh   = (const float*)d_in[19];
  const float* bnh   = (const float*)d_in[20];
  const float* Weh   = (const float*)d_in[21];
  const float* beh   = (const float*)d_in[22];

  const int N = in_sizes[0] / 10;
  const int E = in_sizes[1] / 5;

  float* ws = (float*)d_ws;
  size_t off = 0;
  float* nf     = ws + off; off += (size_t)N * HH;
  float* agg    = ws + off; off += (size_t)N * HH;
  float* WattnT = ws + off; off += 128 * 64;
  float* Wg1T   = ws + off; off += 64 * 64;
  float* WnhT   = ws + off; off += 640;
  float* Wvo    = ws + off; off += 64 * 64;
  float* bvo    = ws + off; off += 64;
  float* ef     = ws + off; off += (size_t)E * HH;
  int* deg    = (int*)(ws + off); off += N;
  int* rowptr = (int*)(ws + off); off += N + 1;
  int* wofs   = (int*)(ws + off); off += N;
  int* eidx   = (int*)(ws + off); off += E;

  float* node_out = (float*)d_out;
  float* edge_out = node_out + (size_t)N * 10;

  const int nb_n = (N + 255) / 256;
  const int nb_e = (E + 255) / 256;
  const int nb_a = ((N * 16) + 255) / 256;

  // prep + CSR build (graph topology is per-call recomputed, deterministic work)
  k_prep<<<32, 256, 0, stream>>>(Wattn, Wg1, Wnh, Wo, Wv, bv, bo,
                                 WattnT, Wg1T, WnhT, Wvo, bvo);
  k_zero<<<nb_n, 256, 0, stream>>>(deg, N);
  k_node_init<<<nb_n, 256, 0, stream>>>(node_logits, Wproj, bproj, nf, N);
  k_edge_init<<<nb_e, 256, 0, stream>>>(edge_logits, We1, be1, We2, be2, ef, E);
  k_deg<<<nb_e, 256, 0, stream>>>(ei, deg, E);
  k_scan<<<1, 1024, 0, stream>>>(deg, rowptr, wofs, N);
  k_scatter<<<nb_e, 256, 0, stream>>>(ei, wofs, eidx, E);

  // iteration 1
  k_edge<false><<<nb_e, 256, 0, stream>>>(nf, ef, ei, WattnT, battn, Wvo, bvo,
                                          Weh, beh, edge_out, N, E);
  k_node_agg<<<nb_a, 256, 0, stream>>>(nf, ef, ei, rowptr, eidx, agg, N, E);
  k_node_update<false><<<nb_n, 256, 0, stream>>>(Wg1T, bg1, Wg2, bg2, WnhT, bnh,
                                                 nf, agg, node_out, N);
  // iteration 2
  k_edge<true><<<nb_e, 256, 0, stream>>>(nf, ef, ei, WattnT, battn, Wvo, bvo,
                                         Weh, beh, edge_out, N, E);
  k_node_agg<<<nb_a, 256, 0, stream>>>(nf, ef, ei, rowptr, eidx, agg, N, E);
  k_node_update<true><<<nb_n, 256, 0, stream>>>(Wg1T, bg1, Wg2, bg2, WnhT, bnh,
                                                nf, agg, node_out, N);
}

// Round 4
// 1261.262 us; speedup vs baseline: 4.7948x; 1.4677x over previous
//
#include <hip/hip_runtime.h>

#define HH 64

typedef __attribute__((ext_vector_type(8))) short bf16x8;
typedef __attribute__((ext_vector_type(16))) float f32x16;

__device__ __forceinline__ unsigned short f2bf(float f) {
  unsigned u = __builtin_bit_cast(unsigned, f);
  return (unsigned short)((u + 0x7FFFu + ((u >> 16) & 1u)) >> 16);
}

// ---------- prep: transposes, Wvo = Wo@Wv, bvo = Wo@bv + bo, Bpack1 ----------
__global__ __launch_bounds__(256) void k_prep(
    const float* __restrict__ Wattn, const float* __restrict__ Wg1,
    const float* __restrict__ Wnh,   const float* __restrict__ Wo,
    const float* __restrict__ Wv,    const float* __restrict__ bv,
    const float* __restrict__ bo,
    float* __restrict__ Wg1T, float* __restrict__ WnhT,
    float* __restrict__ Wvo,  float* __restrict__ bvo,
    unsigned short* __restrict__ Bp1)
{
  int idx = blockIdx.x * 256 + threadIdx.x;
  if (idx < 64 * 64) {             // Wg1T[64][64] <- Wg1[64][64]
    int j = idx >> 6, k = idx & 63;
    Wg1T[k * 64 + j] = Wg1[idx];
  }
  if (idx < 640) {                 // WnhT[64][10] <- Wnh[10][64]
    int c = idx >> 6, j = idx & 63;
    WnhT[j * 10 + c] = Wnh[idx];
  }
  if (idx < 4096) {                // Wvo[j][k] = sum_l Wo[j][l] Wv[l][k]
    int j = idx >> 6, k = idx & 63;
    float a = 0.f;
    #pragma unroll 4
    for (int l = 0; l < 64; ++l) a = fmaf(Wo[j * 64 + l], Wv[l * 64 + k], a);
    Wvo[idx] = a;
  }
  if (idx < 64) {                  // bvo[j] = sum_l Wo[j][l] bv[l] + bo[j]
    float a = bo[idx];
    for (int l = 0; l < 64; ++l) a = fmaf(Wo[idx * 64 + l], bv[l], a);
    bvo[idx] = a;
  }
  if (idx < 8192) {                // Bpack1: B-fragment order for GEMM1 (K=128)
    int e8 = idx & 7, ln = (idx >> 3) & 63, t = (idx >> 9) & 1, s = idx >> 10;
    int n = t * 32 + (ln & 31);
    int k = s * 16 + (ln >> 5) * 8 + e8;
    Bp1[idx] = f2bf(Wattn[n * 128 + k]);
  }
}

// ---------- prep2: Bpack2 from Wvo (must run after k_prep) ----------
__global__ __launch_bounds__(256) void k_prep2(
    const float* __restrict__ Wvo, unsigned short* __restrict__ Bp2)
{
  int idx = blockIdx.x * 256 + threadIdx.x;
  if (idx < 4096) {
    int e8 = idx & 7, ln = (idx >> 3) & 63, t = (idx >> 9) & 1, s = idx >> 10;
    int n = t * 32 + (ln & 31);
    int k = s * 16 + (ln >> 5) * 8 + e8;
    Bp2[idx] = f2bf(Wvo[n * 64 + k]);
  }
}

// ---------- node init: nf = nl @ Wproj^T + bproj ----------
__global__ __launch_bounds__(256) void k_node_init(
    const float* __restrict__ nl, const float* __restrict__ Wproj,
    const float* __restrict__ bproj, float* __restrict__ nf, int N)
{
  int i = blockIdx.x * 256 + threadIdx.x;
  if (i >= N) return;
  float x[10];
  #pragma unroll
  for (int k = 0; k < 10; ++k) x[k] = nl[(size_t)i * 10 + k];
  const size_t ib = (size_t)i * HH;
  #pragma unroll 1
  for (int j = 0; j < HH; ++j) {
    float a = bproj[j];
    #pragma unroll
    for (int k = 0; k < 10; ++k) a = fmaf(x[k], Wproj[j * 10 + k], a);
    nf[ib + j] = a;
  }
}

// ---------- edge init: ef = relu(el @ We1^T + be1) @ We2^T + be2 ----------
__global__ __launch_bounds__(256) void k_edge_init(
    const float* __restrict__ el, const float* __restrict__ We1,
    const float* __restrict__ be1, const float* __restrict__ We2,
    const float* __restrict__ be2, float* __restrict__ ef, int E)
{
  int e = blockIdx.x * 256 + threadIdx.x;
  if (e >= E) return;
  float x0 = el[(size_t)e * 5 + 0], x1 = el[(size_t)e * 5 + 1],
        x2 = el[(size_t)e * 5 + 2], x3 = el[(size_t)e * 5 + 3],
        x4 = el[(size_t)e * 5 + 4];
  float t[HH];
  #pragma unroll
  for (int j = 0; j < HH; ++j) {
    float a = be1[j];
    a = fmaf(x0, We1[j * 5 + 0], a);
    a = fmaf(x1, We1[j * 5 + 1], a);
    a = fmaf(x2, We1[j * 5 + 2], a);
    a = fmaf(x3, We1[j * 5 + 3], a);
    a = fmaf(x4, We1[j * 5 + 4], a);
    t[j] = fmaxf(a, 0.f);
  }
  const size_t eb = (size_t)e * HH;
  #pragma unroll 1
  for (int j4 = 0; j4 < 16; ++j4) {
    float4 ov;
    #pragma unroll
    for (int u = 0; u < 4; ++u) {
      int j = j4 * 4 + u;
      const float* wr = We2 + j * HH;
      float a0 = be2[j], a1 = 0.f, a2 = 0.f, a3 = 0.f;
      #pragma unroll
      for (int k = 0; k < HH; k += 4) {
        a0 = fmaf(t[k    ], wr[k    ], a0);
        a1 = fmaf(t[k + 1], wr[k + 1], a1);
        a2 = fmaf(t[k + 2], wr[k + 2], a2);
        a3 = fmaf(t[k + 3], wr[k + 3], a3);
      }
      (&ov.x)[u] = (a0 + a1) + (a2 + a3);
    }
    *(float4*)(ef + eb + j4 * 4) = ov;
  }
}

// ---------- CSR build ----------
__global__ __launch_bounds__(256) void k_zero(int* __restrict__ p, int n)
{
  int i = blockIdx.x * 256 + threadIdx.x;
  if (i < n) p[i] = 0;
}

__global__ __launch_bounds__(256) void k_deg(
    const int* __restrict__ ei, int* __restrict__ deg, int E)
{
  int e = blockIdx.x * 256 + threadIdx.x;
  if (e >= E) return;
  atomicAdd(&deg[ei[(size_t)E + e]], 1);
}

__global__ __launch_bounds__(1024) void k_scan(
    const int* __restrict__ deg, int* __restrict__ rowptr,
    int* __restrict__ wofs, int N)
{
  __shared__ int part[1024];
  int t = threadIdx.x;
  int chunk = (N + 1023) / 1024;
  int lo = t * chunk;
  int hi = min(lo + chunk, N);
  int s = 0;
  for (int i = lo; i < hi; ++i) s += deg[i];
  part[t] = s;
  __syncthreads();
  for (int off = 1; off < 1024; off <<= 1) {
    int v = (t >= off) ? part[t - off] : 0;
    __syncthreads();
    part[t] += v;
    __syncthreads();
  }
  int base = (t == 0) ? 0 : part[t - 1];
  for (int i = lo; i < hi; ++i) {
    rowptr[i] = base;
    wofs[i]   = base;
    base += deg[i];
  }
  if (t == 1023) rowptr[N] = part[1023];
}

__global__ __launch_bounds__(256) void k_scatter(
    const int* __restrict__ ei, int* __restrict__ wofs,
    int* __restrict__ eidx, int E)
{
  int e = blockIdx.x * 256 + threadIdx.x;
  if (e >= E) return;
  int pos = atomicAdd(&wofs[ei[(size_t)E + e]], 1);
  eidx[pos] = e;
}

// ---------- per-iteration edge pipeline, MFMA version ----------
// Per wave: 32 edges. GEMM1: [32x128]@[128x64] (A = bf16([nf[src];nf[dst]])),
// c += battn -> LDS (bf16, XOR-swizzled). GEMM2: [32x64]@[64x64] (Wvo).
// Epilogue: ef = relu(ef + msg + bvo), coalesced via D-fragment layout.
__global__ __launch_bounds__(256) void k_edge_mfma(
    const float* __restrict__ nf, float* __restrict__ ef,
    const int* __restrict__ ei,
    const unsigned short* __restrict__ Bp1, const float* __restrict__ battn,
    const unsigned short* __restrict__ Bp2, const float* __restrict__ bvo,
    int E)
{
  __shared__ __align__(16) unsigned short c_lds[4 * 32 * 64];
  const int tid   = threadIdx.x;
  const int wave  = tid >> 6;
  const int lane  = tid & 63;
  const int er    = lane & 31;   // A row (edge) / D col (feature)
  const int kh    = lane >> 5;   // k-half selector
  const int ebase = blockIdx.x * 128 + wave * 32;

  int e = ebase + er;
  if (e >= E) e = E - 1;
  const int src = ei[e];
  const int dst = ei[(size_t)E + e];
  const float* ns = nf + (size_t)src * HH;
  const float* nd = nf + (size_t)dst * HH;

  f32x16 acc0 = {0,0,0,0,0,0,0,0,0,0,0,0,0,0,0,0};
  f32x16 acc1 = {0,0,0,0,0,0,0,0,0,0,0,0,0,0,0,0};

  // GEMM1: K=128 over 8 steps of 16 (steps 0-3 from ns, 4-7 from nd)
  #pragma unroll
  for (int s = 0; s < 8; ++s) {
    const float* ap = (s < 4) ? ns : nd;
    const int col = (s & 3) * 16 + kh * 8;
    float4 f0 = *(const float4*)(ap + col);
    float4 f1 = *(const float4*)(ap + col + 4);
    bf16x8 a;
    a[0] = (short)f2bf(f0.x); a[1] = (short)f2bf(f0.y);
    a[2] = (short)f2bf(f0.z); a[3] = (short)f2bf(f0.w);
    a[4] = (short)f2bf(f1.x); a[5] = (short)f2bf(f1.y);
    a[6] = (short)f2bf(f1.z); a[7] = (short)f2bf(f1.w);
    bf16x8 b0 = *(const bf16x8*)(Bp1 + (size_t)((s * 2 + 0) * 64 + lane) * 8);
    bf16x8 b1 = *(const bf16x8*)(Bp1 + (size_t)((s * 2 + 1) * 64 + lane) * 8);
    acc0 = __builtin_amdgcn_mfma_f32_32x32x16_bf16(a, b0, acc0, 0, 0, 0);
    acc1 = __builtin_amdgcn_mfma_f32_32x32x16_bf16(a, b1, acc1, 0, 0, 0);
  }

  // c = acc + battn -> LDS bf16, row-XOR swizzle (stride-128B bank fix)
  const float bt0 = battn[er], bt1 = battn[32 + er];
  unsigned short* cw = c_lds + wave * 2048;
  #pragma unroll
  for (int r = 0; r < 16; ++r) {
    const int m  = (r & 3) + 8 * (r >> 2) + 4 * kh;
    const int sw = (m & 7) << 3;
    cw[m * 64 + ((er     ) ^ sw)] = f2bf(acc0[r] + bt0);
    cw[m * 64 + ((32 + er) ^ sw)] = f2bf(acc1[r] + bt1);
  }
  // intra-wave producer->consumer: wait this wave's LDS writes (rule #18)
  asm volatile("s_waitcnt lgkmcnt(0)" ::: "memory");
  __builtin_amdgcn_sched_barrier(0);

  // GEMM2: K=64 over 4 steps of 16, A from LDS
  f32x16 d0 = {0,0,0,0,0,0,0,0,0,0,0,0,0,0,0,0};
  f32x16 d1 = {0,0,0,0,0,0,0,0,0,0,0,0,0,0,0,0};
  #pragma unroll
  for (int s = 0; s < 4; ++s) {
    const int k0 = s * 16 + kh * 8;
    bf16x8 a2 = *(const bf16x8*)(cw + er * 64 + (k0 ^ ((er & 7) << 3)));
    bf16x8 b0 = *(const bf16x8*)(Bp2 + (size_t)((s * 2 + 0) * 64 + lane) * 8);
    bf16x8 b1 = *(const bf16x8*)(Bp2 + (size_t)((s * 2 + 1) * 64 + lane) * 8);
    d0 = __builtin_amdgcn_mfma_f32_32x32x16_bf16(a2, b0, d0, 0, 0, 0);
    d1 = __builtin_amdgcn_mfma_f32_32x32x16_bf16(a2, b1, d1, 0, 0, 0);
  }

  // epilogue: ef = relu(ef + msg), coalesced (lane 0-31 span 128B)
  const float bv0 = bvo[er], bv1 = bvo[32 + er];
  #pragma unroll
  for (int r = 0; r < 16; ++r) {
    const int m  = (r & 3) + 8 * (r >> 2) + 4 * kh;
    const int eg = ebase + m;
    if (eg < E) {
      float* p = ef + (size_t)eg * HH + er;
      float o0 = p[0], o1 = p[32];
      p[0]  = fmaxf(o0 + d0[r] + bv0, 0.f);
      p[32] = fmaxf(o1 + d1[r] + bv1, 0.f);
    }
  }
}

// ---------- final edge head: edge_out = ef @ Weh^T + beh ----------
__global__ __launch_bounds__(256) void k_edge_out(
    const float* __restrict__ ef, const float* __restrict__ Weh,
    const float* __restrict__ beh, float* __restrict__ eout, int E)
{
  int e = blockIdx.x * 256 + threadIdx.x;
  if (e >= E) return;
  float a0 = beh[0], a1 = beh[1], a2 = beh[2], a3 = beh[3], a4 = beh[4];
  const float* r = ef + (size_t)e * HH;
  #pragma unroll 1
  for (int j4 = 0; j4 < 16; ++j4) {
    float4 v = *(const float4*)(r + j4 * 4);
    #pragma unroll
    for (int u = 0; u < 4; ++u) {
      int j = j4 * 4 + u;
      float x = (&v.x)[u];
      a0 = fmaf(x, Weh[0 * HH + j], a0);
      a1 = fmaf(x, Weh[1 * HH + j], a1);
      a2 = fmaf(x, Weh[2 * HH + j], a2);
      a3 = fmaf(x, Weh[3 * HH + j], a3);
      a4 = fmaf(x, Weh[4 * HH + j], a4);
    }
  }
  float* o = eout + (size_t)e * 5;
  o[0] = a0; o[1] = a1; o[2] = a2; o[3] = a3; o[4] = a4;
}

// ---------- node aggregation via CSR gather ----------
__global__ __launch_bounds__(256) void k_node_agg(
    const float* __restrict__ nf, const float* __restrict__ ef,
    const int* __restrict__ ei, const int* __restrict__ rowptr,
    const int* __restrict__ eidx, float* __restrict__ agg, int N, int E)
{
  int gid = blockIdx.x * 256 + threadIdx.x;
  int i = gid >> 4;
  int l = gid & 15;
  if (i >= N) return;
  int b = rowptr[i];
  int t = rowptr[i + 1];
  const size_t ib = (size_t)i * HH + l * 4;
  float4 h = *(const float4*)(nf + ib);
  for (int p = b; p < t; ++p) {
    int e = eidx[p];
    int src = ei[e];
    float4 efv = *(const float4*)(ef + (size_t)e * HH + l * 4);
    float4 nsv = *(const float4*)(nf + (size_t)src * HH + l * 4);
    h.x += fmaxf(nsv.x + efv.x, 0.f);
    h.y += fmaxf(nsv.y + efv.y, 0.f);
    h.z += fmaxf(nsv.z + efv.z, 0.f);
    h.w += fmaxf(nsv.w + efv.w, 0.f);
  }
  *(float4*)(agg + ib) = h;
}

// ---------- node update ----------
template <bool LAST>
__global__ __launch_bounds__(256) void k_node_update(
    const float* __restrict__ Wg1T, const float* __restrict__ bg1,
    const float* __restrict__ Wg2,  const float* __restrict__ bg2,
    const float* __restrict__ WnhT, const float* __restrict__ bnh,
    float* __restrict__ nf, const float* __restrict__ agg,
    float* __restrict__ node_out, int N)
{
  int i = blockIdx.x * 256 + threadIdx.x;
  if (i >= N) return;
  const size_t ib = (size_t)i * HH;

  float t1[HH];
  #pragma unroll
  for (int j = 0; j < HH; ++j) t1[j] = bg1[j];

  #pragma unroll 1
  for (int k4 = 0; k4 < 16; ++k4) {
    float4 f = *(const float4*)(agg + ib + k4 * 4);
    #pragma unroll
    for (int u = 0; u < 4; ++u) {
      float x = (&f.x)[u];
      const float* wr = Wg1T + (k4 * 4 + u) * HH;
      #pragma unroll
      for (int j = 0; j < HH; ++j) t1[j] = fmaf(x, wr[j], t1[j]);
    }
  }
  #pragma unroll
  for (int j = 0; j < HH; ++j) t1[j] = fmaxf(t1[j], 0.f);

  float no[10];
  if (LAST) {
    #pragma unroll
    for (int cc = 0; cc < 10; ++cc) no[cc] = bnh[cc];
  }

  #pragma unroll 1
  for (int j4 = 0; j4 < 16; ++j4) {
    float4 ov;
    #pragma unroll
    for (int u = 0; u < 4; ++u) {
      int j = j4 * 4 + u;
      const float* wr = Wg2 + j * HH;
      float a0 = bg2[j], a1 = 0.f, a2 = 0.f, a3 = 0.f;
      #pragma unroll
      for (int k = 0; k < HH; k += 4) {
        a0 = fmaf(t1[k    ], wr[k    ], a0);
        a1 = fmaf(t1[k + 1], wr[k + 1], a1);
        a2 = fmaf(t1[k + 2], wr[k + 2], a2);
        a3 = fmaf(t1[k + 3], wr[k + 3], a3);
      }
      float v = fmaxf((a0 + a1) + (a2 + a3), 0.f);
      (&ov.x)[u] = v;
      if (LAST) {
        const float* wn = WnhT + j * 10;
        #pragma unroll
        for (int cc = 0; cc < 10; ++cc) no[cc] = fmaf(v, wn[cc], no[cc]);
      }
    }
    if (!LAST) *(float4*)(nf + ib + j4 * 4) = ov;
  }
  if (LAST) {
    #pragma unroll
    for (int cc = 0; cc < 10; ++cc) node_out[(size_t)i * 10 + cc] = no[cc];
  }
}

extern "C" void kernel_launch(void* const* d_in, const int* in_sizes, int n_in,
                              void* d_out, int out_size, void* d_ws, size_t ws_size,
                              hipStream_t stream)
{
  const float* node_logits = (const float*)d_in[0];
  const float* edge_logits = (const float*)d_in[1];
  const int*   ei          = (const int*)d_in[2];
  const float* Wproj = (const float*)d_in[3];
  const float* bproj = (const float*)d_in[4];
  const float* We1   = (const float*)d_in[5];
  const float* be1   = (const float*)d_in[6];
  const float* We2   = (const float*)d_in[7];
  const float* be2   = (const float*)d_in[8];
  const float* Wg1   = (const float*)d_in[9];
  const float* bg1   = (const float*)d_in[10];
  const float* Wg2   = (const float*)d_in[11];
  const float* bg2   = (const float*)d_in[12];
  const float* Wv    = (const float*)d_in[13];
  const float* bv    = (const float*)d_in[14];
  const float* Wo    = (const float*)d_in[15];
  const float* bo    = (const float*)d_in[16];
  const float* Wattn = (const float*)d_in[17];
  const float* battn = (const float*)d_in[18];
  const float* Wnh   = (const float*)d_in[19];
  const float* bnh   = (const float*)d_in[20];
  const float* Weh   = (const float*)d_in[21];
  const float* beh   = (const float*)d_in[22];

  const int N = in_sizes[0] / 10;
  const int E = in_sizes[1] / 5;

  float* ws = (float*)d_ws;
  size_t off = 0;
  float* nf   = ws + off; off += (size_t)N * HH;
  float* agg  = ws + off; off += (size_t)N * HH;
  float* Wg1T = ws + off; off += 64 * 64;
  float* WnhT = ws + off; off += 640;
  float* Wvo  = ws + off; off += 64 * 64;
  float* bvo  = ws + off; off += 64;
  unsigned short* Bp1 = (unsigned short*)(ws + off); off += 4096;  // 8192 bf16
  unsigned short* Bp2 = (unsigned short*)(ws + off); off += 2048;  // 4096 bf16
  float* ef   = ws + off; off += (size_t)E * HH;
  int* deg    = (int*)(ws + off); off += N;
  int* rowptr = (int*)(ws + off); off += N + 1;
  int* wofs   = (int*)(ws + off); off += N;
  int* eidx   = (int*)(ws + off); off += E;

  float* node_out = (float*)d_out;
  float* edge_out = node_out + (size_t)N * 10;

  const int nb_n   = (N + 255) / 256;
  const int nb_e   = (E + 255) / 256;
  const int nb_a   = ((N * 16) + 255) / 256;
  const int nb_e128 = (E + 127) / 128;

  k_prep<<<32, 256, 0, stream>>>(Wattn, Wg1, Wnh, Wo, Wv, bv, bo,
                                 Wg1T, WnhT, Wvo, bvo, Bp1);
  k_prep2<<<16, 256, 0, stream>>>(Wvo, Bp2);
  k_zero<<<nb_n, 256, 0, stream>>>(deg, N);
  k_node_init<<<nb_n, 256, 0, stream>>>(node_logits, Wproj, bproj, nf, N);
  k_edge_init<<<nb_e, 256, 0, stream>>>(edge_logits, We1, be1, We2, be2, ef, E);
  k_deg<<<nb_e, 256, 0, stream>>>(ei, deg, E);
  k_scan<<<1, 1024, 0, stream>>>(deg, rowptr, wofs, N);
  k_scatter<<<nb_e, 256, 0, stream>>>(ei, wofs, eidx, E);

  // iteration 1
  k_edge_mfma<<<nb_e128, 256, 0, stream>>>(nf, ef, ei, Bp1, battn, Bp2, bvo, E);
  k_node_agg<<<nb_a, 256, 0, stream>>>(nf, ef, ei, rowptr, eidx, agg, N, E);
  k_node_update<false><<<nb_n, 256, 0, stream>>>(Wg1T, bg1, Wg2, bg2, WnhT, bnh,
                                                 nf, agg, node_out, N);
  // iteration 2
  k_edge_mfma<<<nb_e128, 256, 0, stream>>>(nf, ef, ei, Bp1, battn, Bp2, bvo, E);
  k_node_agg<<<nb_a, 256, 0, stream>>>(nf, ef, ei, rowptr, eidx, agg, N, E);
  k_node_update<true><<<nb_n, 256, 0, stream>>>(Wg1T, bg1, Wg2, bg2, WnhT, bnh,
                                                nf, agg, node_out, N);
  k_edge_out<<<nb_e, 256, 0, stream>>>(ef, Weh, beh, edge_out, E);
}

// Round 5
// 824.844 us; speedup vs baseline: 7.3318x; 1.5291x over previous
//
#include <hip/hip_runtime.h>

#define HH 64

typedef __attribute__((ext_vector_type(8))) short bf16x8;
typedef __attribute__((ext_vector_type(16))) float f32x16;
typedef __attribute__((ext_vector_type(4))) unsigned short ushx4;

__device__ __forceinline__ unsigned short f2bf(float f) {
  unsigned u = __builtin_bit_cast(unsigned, f);
  return (unsigned short)((u + 0x7FFFu + ((u >> 16) & 1u)) >> 16);
}
__device__ __forceinline__ float bf2f(unsigned short h) {
  unsigned u = ((unsigned)h) << 16;
  return __builtin_bit_cast(float, u);
}

// ---------- prep: transposes, Wvo = Wo@Wv, bvo = Wo@bv + bo, Bp1, Bp3 ----------
__global__ __launch_bounds__(256) void k_prep(
    const float* __restrict__ Wattn, const float* __restrict__ Wg1,
    const float* __restrict__ Wnh,   const float* __restrict__ Wo,
    const float* __restrict__ Wv,    const float* __restrict__ bv,
    const float* __restrict__ bo,    const float* __restrict__ We2,
    float* __restrict__ Wg1T, float* __restrict__ WnhT,
    float* __restrict__ Wvo,  float* __restrict__ bvo,
    unsigned short* __restrict__ Bp1, unsigned short* __restrict__ Bp3)
{
  int idx = blockIdx.x * 256 + threadIdx.x;
  if (idx < 64 * 64) {             // Wg1T[64][64] <- Wg1[64][64]
    int j = idx >> 6, k = idx & 63;
    Wg1T[k * 64 + j] = Wg1[idx];
  }
  if (idx < 640) {                 // WnhT[64][10] <- Wnh[10][64]
    int c = idx >> 6, j = idx & 63;
    WnhT[j * 10 + c] = Wnh[idx];
  }
  if (idx < 4096) {                // Wvo[j][k] = sum_l Wo[j][l] Wv[l][k]
    int j = idx >> 6, k = idx & 63;
    float a = 0.f;
    #pragma unroll 4
    for (int l = 0; l < 64; ++l) a = fmaf(Wo[j * 64 + l], Wv[l * 64 + k], a);
    Wvo[idx] = a;
  }
  if (idx < 64) {                  // bvo[j] = sum_l Wo[j][l] bv[l] + bo[j]
    float a = bo[idx];
    for (int l = 0; l < 64; ++l) a = fmaf(Wo[idx * 64 + l], bv[l], a);
    bvo[idx] = a;
  }
  if (idx < 8192) {                // Bp1: B-fragments of Wattn (K=128 GEMM)
    int e8 = idx & 7, ln = (idx >> 3) & 63, t = (idx >> 9) & 1, s = idx >> 10;
    int n = t * 32 + (ln & 31);
    int k = s * 16 + (ln >> 5) * 8 + e8;
    Bp1[idx] = f2bf(Wattn[n * 128 + k]);
  }
  if (idx < 4096) {                // Bp3: B-fragments of We2 (K=64 GEMM)
    int e8 = idx & 7, ln = (idx >> 3) & 63, t = (idx >> 9) & 1, s = idx >> 10;
    int n = t * 32 + (ln & 31);
    int k = s * 16 + (ln >> 5) * 8 + e8;
    Bp3[idx] = f2bf(We2[n * 64 + k]);
  }
}

// ---------- prep2: Bp2 from Wvo (must run after k_prep) ----------
__global__ __launch_bounds__(256) void k_prep2(
    const float* __restrict__ Wvo, unsigned short* __restrict__ Bp2)
{
  int idx = blockIdx.x * 256 + threadIdx.x;
  if (idx < 4096) {
    int e8 = idx & 7, ln = (idx >> 3) & 63, t = (idx >> 9) & 1, s = idx >> 10;
    int n = t * 32 + (ln & 31);
    int k = s * 16 + (ln >> 5) * 8 + e8;
    Bp2[idx] = f2bf(Wvo[n * 64 + k]);
  }
}

// ---------- node init: nf16 = bf16(nl @ Wproj^T + bproj) ----------
__global__ __launch_bounds__(256) void k_node_init(
    const float* __restrict__ nl, const float* __restrict__ Wproj,
    const float* __restrict__ bproj, unsigned short* __restrict__ nf16, int N)
{
  int i = blockIdx.x * 256 + threadIdx.x;
  if (i >= N) return;
  float x[10];
  #pragma unroll
  for (int k = 0; k < 10; ++k) x[k] = nl[(size_t)i * 10 + k];
  const size_t ib = (size_t)i * HH;
  #pragma unroll 1
  for (int j8 = 0; j8 < 8; ++j8) {
    bf16x8 v;
    #pragma unroll
    for (int u = 0; u < 8; ++u) {
      int j = j8 * 8 + u;
      float a = bproj[j];
      #pragma unroll
      for (int k = 0; k < 10; ++k) a = fmaf(x[k], Wproj[j * 10 + k], a);
      v[u] = (short)f2bf(a);
    }
    *(bf16x8*)(nf16 + ib + j8 * 8) = v;
  }
}

// ---------- edge init, MFMA: ef16 = bf16(relu(el@We1^T+be1) @ We2^T + be2) ----------
__global__ __launch_bounds__(256) void k_edge_init_mfma(
    const float* __restrict__ el, const float* __restrict__ We1,
    const float* __restrict__ be1, const unsigned short* __restrict__ Bp3,
    const float* __restrict__ be2, unsigned short* __restrict__ ef16, int E)
{
  const int tid   = threadIdx.x;
  const int wave  = tid >> 6;
  const int lane  = tid & 63;
  const int er    = lane & 31;
  const int kh    = lane >> 5;
  const int ebase = blockIdx.x * 128 + wave * 32;

  int e = ebase + er;
  if (e >= E) e = E - 1;
  const float x0 = el[(size_t)e * 5 + 0], x1 = el[(size_t)e * 5 + 1],
              x2 = el[(size_t)e * 5 + 2], x3 = el[(size_t)e * 5 + 3],
              x4 = el[(size_t)e * 5 + 4];

  // layer 1 (K=5, VALU) directly into A-fragments: k = s*16 + kh*8 + u
  bf16x8 afr[4];
  #pragma unroll
  for (int s = 0; s < 4; ++s) {
    #pragma unroll
    for (int u = 0; u < 8; ++u) {
      const int k = s * 16 + kh * 8 + u;
      float a = be1[k];
      a = fmaf(x0, We1[k * 5 + 0], a);
      a = fmaf(x1, We1[k * 5 + 1], a);
      a = fmaf(x2, We1[k * 5 + 2], a);
      a = fmaf(x3, We1[k * 5 + 3], a);
      a = fmaf(x4, We1[k * 5 + 4], a);
      afr[s][u] = (short)f2bf(fmaxf(a, 0.f));
    }
  }

  f32x16 d0 = {0,0,0,0,0,0,0,0,0,0,0,0,0,0,0,0};
  f32x16 d1 = {0,0,0,0,0,0,0,0,0,0,0,0,0,0,0,0};
  #pragma unroll
  for (int s = 0; s < 4; ++s) {
    bf16x8 b0 = *(const bf16x8*)(Bp3 + (size_t)((s * 2 + 0) * 64 + lane) * 8);
    bf16x8 b1 = *(const bf16x8*)(Bp3 + (size_t)((s * 2 + 1) * 64 + lane) * 8);
    d0 = __builtin_amdgcn_mfma_f32_32x32x16_bf16(afr[s], b0, d0, 0, 0, 0);
    d1 = __builtin_amdgcn_mfma_f32_32x32x16_bf16(afr[s], b1, d1, 0, 0, 0);
  }

  const float b20 = be2[er], b21 = be2[32 + er];
  #pragma unroll
  for (int r = 0; r < 16; ++r) {
    const int m  = (r & 3) + 8 * (r >> 2) + 4 * kh;
    const int eg = ebase + m;
    if (eg < E) {
      unsigned short* p = ef16 + (size_t)eg * HH + er;
      p[0]  = f2bf(d0[r] + b20);
      p[32] = f2bf(d1[r] + b21);
    }
  }
}

// ---------- CSR build ----------
__global__ __launch_bounds__(256) void k_zero(int* __restrict__ p, int n)
{
  int i = blockIdx.x * 256 + threadIdx.x;
  if (i < n) p[i] = 0;
}

__global__ __launch_bounds__(256) void k_deg(
    const int* __restrict__ ei, int* __restrict__ deg, int E)
{
  int e = blockIdx.x * 256 + threadIdx.x;
  if (e >= E) return;
  atomicAdd(&deg[ei[(size_t)E + e]], 1);
}

__global__ __launch_bounds__(1024) void k_scan(
    const int* __restrict__ deg, int* __restrict__ rowptr,
    int* __restrict__ wofs, int N)
{
  __shared__ int part[1024];
  int t = threadIdx.x;
  int chunk = (N + 1023) / 1024;
  int lo = t * chunk;
  int hi = min(lo + chunk, N);
  int s = 0;
  for (int i = lo; i < hi; ++i) s += deg[i];
  part[t] = s;
  __syncthreads();
  for (int off = 1; off < 1024; off <<= 1) {
    int v = (t >= off) ? part[t - off] : 0;
    __syncthreads();
    part[t] += v;
    __syncthreads();
  }
  int base = (t == 0) ? 0 : part[t - 1];
  for (int i = lo; i < hi; ++i) {
    rowptr[i] = base;
    wofs[i]   = base;
    base += deg[i];
  }
  if (t == 1023) rowptr[N] = part[1023];
}

__global__ __launch_bounds__(256) void k_scatter(
    const int* __restrict__ ei, int* __restrict__ wofs,
    int* __restrict__ eidx, int E)
{
  int e = blockIdx.x * 256 + threadIdx.x;
  if (e >= E) return;
  int pos = atomicAdd(&wofs[ei[(size_t)E + e]], 1);
  eidx[pos] = e;
}

// ---------- per-iteration edge pipeline, MFMA + bf16 storage ----------
__global__ __launch_bounds__(256) void k_edge_mfma(
    const unsigned short* __restrict__ nf16, unsigned short* __restrict__ ef16,
    const int* __restrict__ ei,
    const unsigned short* __restrict__ Bp1, const float* __restrict__ battn,
    const unsigned short* __restrict__ Bp2, const float* __restrict__ bvo,
    int E)
{
  __shared__ __align__(16) unsigned short c_lds[4 * 32 * 64];
  const int tid   = threadIdx.x;
  const int wave  = tid >> 6;
  const int lane  = tid & 63;
  const int er    = lane & 31;   // A row (edge) / D col (feature)
  const int kh    = lane >> 5;   // k-half selector
  const int ebase = blockIdx.x * 128 + wave * 32;

  int e = ebase + er;
  if (e >= E) e = E - 1;
  const int src = ei[e];
  const int dst = ei[(size_t)E + e];
  const unsigned short* ns = nf16 + (size_t)src * HH;
  const unsigned short* nd = nf16 + (size_t)dst * HH;

  f32x16 acc0 = {0,0,0,0,0,0,0,0,0,0,0,0,0,0,0,0};
  f32x16 acc1 = {0,0,0,0,0,0,0,0,0,0,0,0,0,0,0,0};

  // GEMM1: K=128 over 8 steps of 16 (0-3 from ns, 4-7 from nd); A is direct bf16x8
  #pragma unroll
  for (int s = 0; s < 8; ++s) {
    const unsigned short* ap = (s < 4) ? ns : nd;
    bf16x8 a = *(const bf16x8*)(ap + (s & 3) * 16 + kh * 8);
    bf16x8 b0 = *(const bf16x8*)(Bp1 + (size_t)((s * 2 + 0) * 64 + lane) * 8);
    bf16x8 b1 = *(const bf16x8*)(Bp1 + (size_t)((s * 2 + 1) * 64 + lane) * 8);
    acc0 = __builtin_amdgcn_mfma_f32_32x32x16_bf16(a, b0, acc0, 0, 0, 0);
    acc1 = __builtin_amdgcn_mfma_f32_32x32x16_bf16(a, b1, acc1, 0, 0, 0);
  }

  // c = acc + battn -> LDS bf16, row-XOR swizzle
  const float bt0 = battn[er], bt1 = battn[32 + er];
  unsigned short* cw = c_lds + wave * 2048;
  #pragma unroll
  for (int r = 0; r < 16; ++r) {
    const int m  = (r & 3) + 8 * (r >> 2) + 4 * kh;
    const int sw = (m & 7) << 3;
    cw[m * 64 + ((er     ) ^ sw)] = f2bf(acc0[r] + bt0);
    cw[m * 64 + ((32 + er) ^ sw)] = f2bf(acc1[r] + bt1);
  }
  asm volatile("s_waitcnt lgkmcnt(0)" ::: "memory");
  __builtin_amdgcn_sched_barrier(0);

  // GEMM2: K=64 over 4 steps, A from LDS
  f32x16 d0 = {0,0,0,0,0,0,0,0,0,0,0,0,0,0,0,0};
  f32x16 d1 = {0,0,0,0,0,0,0,0,0,0,0,0,0,0,0,0};
  #pragma unroll
  for (int s = 0; s < 4; ++s) {
    const int k0 = s * 16 + kh * 8;
    bf16x8 a2 = *(const bf16x8*)(cw + er * 64 + (k0 ^ ((er & 7) << 3)));
    bf16x8 b0 = *(const bf16x8*)(Bp2 + (size_t)((s * 2 + 0) * 64 + lane) * 8);
    bf16x8 b1 = *(const bf16x8*)(Bp2 + (size_t)((s * 2 + 1) * 64 + lane) * 8);
    d0 = __builtin_amdgcn_mfma_f32_32x32x16_bf16(a2, b0, d0, 0, 0, 0);
    d1 = __builtin_amdgcn_mfma_f32_32x32x16_bf16(a2, b1, d1, 0, 0, 0);
  }

  // epilogue: ef = relu(ef + msg), bf16 RMW, coalesced per 64B segment
  const float bv0 = bvo[er], bv1 = bvo[32 + er];
  #pragma unroll
  for (int r = 0; r < 16; ++r) {
    const int m  = (r & 3) + 8 * (r >> 2) + 4 * kh;
    const int eg = ebase + m;
    if (eg < E) {
      unsigned short* p = ef16 + (size_t)eg * HH + er;
      float o0 = bf2f(p[0]), o1 = bf2f(p[32]);
      p[0]  = f2bf(fmaxf(o0 + d0[r] + bv0, 0.f));
      p[32] = f2bf(fmaxf(o1 + d1[r] + bv1, 0.f));
    }
  }
}

// ---------- final edge head: edge_out = ef @ Weh^T + beh ----------
__global__ __launch_bounds__(256) void k_edge_out(
    const unsigned short* __restrict__ ef16, const float* __restrict__ Weh,
    const float* __restrict__ beh, float* __restrict__ eout, int E)
{
  int e = blockIdx.x * 256 + threadIdx.x;
  if (e >= E) return;
  float a0 = beh[0], a1 = beh[1], a2 = beh[2], a3 = beh[3], a4 = beh[4];
  const unsigned short* r = ef16 + (size_t)e * HH;
  #pragma unroll 1
  for (int j8 = 0; j8 < 8; ++j8) {
    ushx4 v0 = *(const ushx4*)(r + j8 * 8);
    ushx4 v1 = *(const ushx4*)(r + j8 * 8 + 4);
    #pragma unroll
    for (int u = 0; u < 4; ++u) {
      int j = j8 * 8 + u;
      float x = bf2f(v0[u]);
      a0 = fmaf(x, Weh[0 * HH + j], a0);
      a1 = fmaf(x, Weh[1 * HH + j], a1);
      a2 = fmaf(x, Weh[2 * HH + j], a2);
      a3 = fmaf(x, Weh[3 * HH + j], a3);
      a4 = fmaf(x, Weh[4 * HH + j], a4);
    }
    #pragma unroll
    for (int u = 0; u < 4; ++u) {
      int j = j8 * 8 + 4 + u;
      float x = bf2f(v1[u]);
      a0 = fmaf(x, Weh[0 * HH + j], a0);
      a1 = fmaf(x, Weh[1 * HH + j], a1);
      a2 = fmaf(x, Weh[2 * HH + j], a2);
      a3 = fmaf(x, Weh[3 * HH + j], a3);
      a4 = fmaf(x, Weh[4 * HH + j], a4);
    }
  }
  float* o = eout + (size_t)e * 5;
  o[0] = a0; o[1] = a1; o[2] = a2; o[3] = a3; o[4] = a4;
}

// ---------- node aggregation via CSR gather (bf16 inputs, f32 agg out) ----------
__global__ __launch_bounds__(256) void k_node_agg(
    const unsigned short* __restrict__ nf16, const unsigned short* __restrict__ ef16,
    const int* __restrict__ ei, const int* __restrict__ rowptr,
    const int* __restrict__ eidx, float* __restrict__ agg, int N, int E)
{
  int gid = blockIdx.x * 256 + threadIdx.x;
  int i = gid >> 4;
  int l = gid & 15;
  if (i >= N) return;
  int b = rowptr[i];
  int t = rowptr[i + 1];
  const int fo = l * 4;
  ushx4 hv = *(const ushx4*)(nf16 + (size_t)i * HH + fo);
  float h0 = bf2f(hv[0]), h1 = bf2f(hv[1]), h2 = bf2f(hv[2]), h3 = bf2f(hv[3]);
  for (int p = b; p < t; ++p) {
    int e = eidx[p];
    int src = ei[e];
    ushx4 ev = *(const ushx4*)(ef16 + (size_t)e * HH + fo);
    ushx4 sv = *(const ushx4*)(nf16 + (size_t)src * HH + fo);
    h0 += fmaxf(bf2f(sv[0]) + bf2f(ev[0]), 0.f);
    h1 += fmaxf(bf2f(sv[1]) + bf2f(ev[1]), 0.f);
    h2 += fmaxf(bf2f(sv[2]) + bf2f(ev[2]), 0.f);
    h3 += fmaxf(bf2f(sv[3]) + bf2f(ev[3]), 0.f);
  }
  float4 out = {h0, h1, h2, h3};
  *(float4*)(agg + (size_t)i * HH + fo) = out;
}

// ---------- node update ----------
template <bool LAST>
__global__ __launch_bounds__(256) void k_node_update(
    const float* __restrict__ Wg1T, const float* __restrict__ bg1,
    const float* __restrict__ Wg2,  const float* __restrict__ bg2,
    const float* __restrict__ WnhT, const float* __restrict__ bnh,
    unsigned short* __restrict__ nf16, const float* __restrict__ agg,
    float* __restrict__ node_out, int N)
{
  int i = blockIdx.x * 256 + threadIdx.x;
  if (i >= N) return;
  const size_t ib = (size_t)i * HH;

  float t1[HH];
  #pragma unroll
  for (int j = 0; j < HH; ++j) t1[j] = bg1[j];

  #pragma unroll 1
  for (int k4 = 0; k4 < 16; ++k4) {
    float4 f = *(const float4*)(agg + ib + k4 * 4);
    #pragma unroll
    for (int u = 0; u < 4; ++u) {
      float x = (&f.x)[u];
      const float* wr = Wg1T + (k4 * 4 + u) * HH;
      #pragma unroll
      for (int j = 0; j < HH; ++j) t1[j] = fmaf(x, wr[j], t1[j]);
    }
  }
  #pragma unroll
  for (int j = 0; j < HH; ++j) t1[j] = fmaxf(t1[j], 0.f);

  float no[10];
  if (LAST) {
    #pragma unroll
    for (int cc = 0; cc < 10; ++cc) no[cc] = bnh[cc];
  }

  #pragma unroll 1
  for (int j8 = 0; j8 < 8; ++j8) {
    bf16x8 ov;
    #pragma unroll
    for (int u = 0; u < 8; ++u) {
      int j = j8 * 8 + u;
      const float* wr = Wg2 + j * HH;
      float a0 = bg2[j], a1 = 0.f, a2 = 0.f, a3 = 0.f;
      #pragma unroll
      for (int k = 0; k < HH; k += 4) {
        a0 = fmaf(t1[k    ], wr[k    ], a0);
        a1 = fmaf(t1[k + 1], wr[k + 1], a1);
        a2 = fmaf(t1[k + 2], wr[k + 2], a2);
        a3 = fmaf(t1[k + 3], wr[k + 3], a3);
      }
      float v = fmaxf((a0 + a1) + (a2 + a3), 0.f);
      ov[u] = (short)f2bf(v);
      if (LAST) {
        const float* wn = WnhT + j * 10;
        #pragma unroll
        for (int cc = 0; cc < 10; ++cc) no[cc] = fmaf(v, wn[cc], no[cc]);
      }
    }
    if (!LAST) *(bf16x8*)(nf16 + ib + j8 * 8) = ov;
  }
  if (LAST) {
    #pragma unroll
    for (int cc = 0; cc < 10; ++cc) node_out[(size_t)i * 10 + cc] = no[cc];
  }
}

extern "C" void kernel_launch(void* const* d_in, const int* in_sizes, int n_in,
                              void* d_out, int out_size, void* d_ws, size_t ws_size,
                              hipStream_t stream)
{
  const float* node_logits = (const float*)d_in[0];
  const float* edge_logits = (const float*)d_in[1];
  const int*   ei          = (const int*)d_in[2];
  const float* Wproj = (const float*)d_in[3];
  const float* bproj = (const float*)d_in[4];
  const float* We1   = (const float*)d_in[5];
  const float* be1   = (const float*)d_in[6];
  const float* We2   = (const float*)d_in[7];
  const float* be2   = (const float*)d_in[8];
  const float* Wg1   = (const float*)d_in[9];
  const float* bg1   = (const float*)d_in[10];
  const float* Wg2   = (const float*)d_in[11];
  const float* bg2   = (const float*)d_in[12];
  const float* Wv    = (const float*)d_in[13];
  const float* bv    = (const float*)d_in[14];
  const float* Wo    = (const float*)d_in[15];
  const float* bo    = (const float*)d_in[16];
  const float* Wattn = (const float*)d_in[17];
  const float* battn = (const float*)d_in[18];
  const float* Wnh   = (const float*)d_in[19];
  const float* bnh   = (const float*)d_in[20];
  const float* Weh   = (const float*)d_in[21];
  const float* beh   = (const float*)d_in[22];

  const int N = in_sizes[0] / 10;
  const int E = in_sizes[1] / 5;

  float* ws = (float*)d_ws;
  size_t off = 0;
  unsigned short* nf16 = (unsigned short*)(ws + off); off += (size_t)N * (HH / 2);
  unsigned short* ef16 = (unsigned short*)(ws + off); off += (size_t)E * (HH / 2);
  float* agg  = ws + off; off += (size_t)N * HH;
  float* Wg1T = ws + off; off += 64 * 64;
  float* WnhT = ws + off; off += 640;
  float* Wvo  = ws + off; off += 64 * 64;
  float* bvo  = ws + off; off += 64;
  unsigned short* Bp1 = (unsigned short*)(ws + off); off += 4096;  // 8192 bf16
  unsigned short* Bp2 = (unsigned short*)(ws + off); off += 2048;  // 4096 bf16
  unsigned short* Bp3 = (unsigned short*)(ws + off); off += 2048;  // 4096 bf16
  int* deg    = (int*)(ws + off); off += N;
  int* rowptr = (int*)(ws + off); off += N + 1;
  int* wofs   = (int*)(ws + off); off += N;
  int* eidx   = (int*)(ws + off); off += E;

  float* node_out = (float*)d_out;
  float* edge_out = node_out + (size_t)N * 10;

  const int nb_n    = (N + 255) / 256;
  const int nb_e    = (E + 255) / 256;
  const int nb_a    = ((N * 16) + 255) / 256;
  const int nb_e128 = (E + 127) / 128;

  k_prep<<<32, 256, 0, stream>>>(Wattn, Wg1, Wnh, Wo, Wv, bv, bo, We2,
                                 Wg1T, WnhT, Wvo, bvo, Bp1, Bp3);
  k_prep2<<<16, 256, 0, stream>>>(Wvo, Bp2);
  k_zero<<<nb_n, 256, 0, stream>>>(deg, N);
  k_node_init<<<nb_n, 256, 0, stream>>>(node_logits, Wproj, bproj, nf16, N);
  k_edge_init_mfma<<<nb_e128, 256, 0, stream>>>(edge_logits, We1, be1, Bp3, be2,
                                                ef16, E);
  k_deg<<<nb_e, 256, 0, stream>>>(ei, deg, E);
  k_scan<<<1, 1024, 0, stream>>>(deg, rowptr, wofs, N);
  k_scatter<<<nb_e, 256, 0, stream>>>(ei, wofs, eidx, E);

  // iteration 1
  k_edge_mfma<<<nb_e128, 256, 0, stream>>>(nf16, ef16, ei, Bp1, battn, Bp2, bvo, E);
  k_node_agg<<<nb_a, 256, 0, stream>>>(nf16, ef16, ei, rowptr, eidx, agg, N, E);
  k_node_update<false><<<nb_n, 256, 0, stream>>>(Wg1T, bg1, Wg2, bg2, WnhT, bnh,
                                                 nf16, agg, node_out, N);
  // iteration 2
  k_edge_mfma<<<nb_e128, 256, 0, stream>>>(nf16, ef16, ei, Bp1, battn, Bp2, bvo, E);
  k_node_agg<<<nb_a, 256, 0, stream>>>(nf16, ef16, ei, rowptr, eidx, agg, N, E);
  k_node_update<true><<<nb_n, 256, 0, stream>>>(Wg1T, bg1, Wg2, bg2, WnhT, bnh,
                                                nf16, agg, node_out, N);
  k_edge_out<<<nb_e, 256, 0, stream>>>(ef16, Weh, beh, edge_out, E);
}

// Round 6
// 653.999 us; speedup vs baseline: 9.2470x; 1.2612x over previous
//
#include <hip/hip_runtime.h>

#define HH 64

typedef __attribute__((ext_vector_type(8))) short bf16x8;
typedef __attribute__((ext_vector_type(16))) float f32x16;
typedef __attribute__((ext_vector_type(4))) unsigned short ushx4;

__device__ __forceinline__ unsigned short f2bf(float f) {
  unsigned u = __builtin_bit_cast(unsigned, f);
  return (unsigned short)((u + 0x7FFFu + ((u >> 16) & 1u)) >> 16);
}
__device__ __forceinline__ float bf2f(unsigned short h) {
  unsigned u = ((unsigned)h) << 16;
  return __builtin_bit_cast(float, u);
}

// ---------- prep: transposes, Wvo = Wo@Wv, bvo = Wo@bv + bo, Bp1, Bp3 ----------
__global__ __launch_bounds__(256) void k_prep(
    const float* __restrict__ Wattn, const float* __restrict__ Wg1,
    const float* __restrict__ Wnh,   const float* __restrict__ Wo,
    const float* __restrict__ Wv,    const float* __restrict__ bv,
    const float* __restrict__ bo,    const float* __restrict__ We2,
    float* __restrict__ Wg1T, float* __restrict__ WnhT,
    float* __restrict__ Wvo,  float* __restrict__ bvo,
    unsigned short* __restrict__ Bp1, unsigned short* __restrict__ Bp3)
{
  int idx = blockIdx.x * 256 + threadIdx.x;
  if (idx < 64 * 64) {             // Wg1T[64][64] <- Wg1[64][64]
    int j = idx >> 6, k = idx & 63;
    Wg1T[k * 64 + j] = Wg1[idx];
  }
  if (idx < 640) {                 // WnhT[64][10] <- Wnh[10][64]
    int c = idx >> 6, j = idx & 63;
    WnhT[j * 10 + c] = Wnh[idx];
  }
  if (idx < 4096) {                // Wvo[j][k] = sum_l Wo[j][l] Wv[l][k]
    int j = idx >> 6, k = idx & 63;
    float a = 0.f;
    #pragma unroll 4
    for (int l = 0; l < 64; ++l) a = fmaf(Wo[j * 64 + l], Wv[l * 64 + k], a);
    Wvo[idx] = a;
  }
  if (idx < 64) {                  // bvo[j] = sum_l Wo[j][l] bv[l] + bo[j]
    float a = bo[idx];
    for (int l = 0; l < 64; ++l) a = fmaf(Wo[idx * 64 + l], bv[l], a);
    bvo[idx] = a;
  }
  if (idx < 8192) {                // Bp1: B-fragments of Wattn (K=128 GEMM)
    int e8 = idx & 7, ln = (idx >> 3) & 63, t = (idx >> 9) & 1, s = idx >> 10;
    int n = t * 32 + (ln & 31);
    int k = s * 16 + (ln >> 5) * 8 + e8;
    Bp1[idx] = f2bf(Wattn[n * 128 + k]);
  }
  if (idx < 4096) {                // Bp3: B-fragments of We2 (K=64 GEMM)
    int e8 = idx & 7, ln = (idx >> 3) & 63, t = (idx >> 9) & 1, s = idx >> 10;
    int n = t * 32 + (ln & 31);
    int k = s * 16 + (ln >> 5) * 8 + e8;
    Bp3[idx] = f2bf(We2[n * 64 + k]);
  }
}

// ---------- prep2: Bp2 from Wvo (must run after k_prep) ----------
__global__ __launch_bounds__(256) void k_prep2(
    const float* __restrict__ Wvo, unsigned short* __restrict__ Bp2)
{
  int idx = blockIdx.x * 256 + threadIdx.x;
  if (idx < 4096) {
    int e8 = idx & 7, ln = (idx >> 3) & 63, t = (idx >> 9) & 1, s = idx >> 10;
    int n = t * 32 + (ln & 31);
    int k = s * 16 + (ln >> 5) * 8 + e8;
    Bp2[idx] = f2bf(Wvo[n * 64 + k]);
  }
}

// ---------- node init: nf16 = bf16(nl @ Wproj^T + bproj) ----------
__global__ __launch_bounds__(256) void k_node_init(
    const float* __restrict__ nl, const float* __restrict__ Wproj,
    const float* __restrict__ bproj, unsigned short* __restrict__ nf16, int N)
{
  int i = blockIdx.x * 256 + threadIdx.x;
  if (i >= N) return;
  float x[10];
  #pragma unroll
  for (int k = 0; k < 10; ++k) x[k] = nl[(size_t)i * 10 + k];
  const size_t ib = (size_t)i * HH;
  #pragma unroll 1
  for (int j8 = 0; j8 < 8; ++j8) {
    bf16x8 v;
    #pragma unroll
    for (int u = 0; u < 8; ++u) {
      int j = j8 * 8 + u;
      float a = bproj[j];
      #pragma unroll
      for (int k = 0; k < 10; ++k) a = fmaf(x[k], Wproj[j * 10 + k], a);
      v[u] = (short)f2bf(a);
    }
    *(bf16x8*)(nf16 + ib + j8 * 8) = v;
  }
}

// ---------- edge init, MFMA: ef16 = bf16(relu(el@We1^T+be1) @ We2^T + be2) ----------
__global__ __launch_bounds__(256) void k_edge_init_mfma(
    const float* __restrict__ el, const float* __restrict__ We1,
    const float* __restrict__ be1, const unsigned short* __restrict__ Bp3,
    const float* __restrict__ be2, unsigned short* __restrict__ ef16, int E)
{
  const int tid   = threadIdx.x;
  const int wave  = tid >> 6;
  const int lane  = tid & 63;
  const int er    = lane & 31;
  const int kh    = lane >> 5;
  const int ebase = blockIdx.x * 128 + wave * 32;

  int e = ebase + er;
  if (e >= E) e = E - 1;
  const float x0 = el[(size_t)e * 5 + 0], x1 = el[(size_t)e * 5 + 1],
              x2 = el[(size_t)e * 5 + 2], x3 = el[(size_t)e * 5 + 3],
              x4 = el[(size_t)e * 5 + 4];

  // layer 1 (K=5, VALU) directly into A-fragments: k = s*16 + kh*8 + u
  bf16x8 afr[4];
  #pragma unroll
  for (int s = 0; s < 4; ++s) {
    #pragma unroll
    for (int u = 0; u < 8; ++u) {
      const int k = s * 16 + kh * 8 + u;
      float a = be1[k];
      a = fmaf(x0, We1[k * 5 + 0], a);
      a = fmaf(x1, We1[k * 5 + 1], a);
      a = fmaf(x2, We1[k * 5 + 2], a);
      a = fmaf(x3, We1[k * 5 + 3], a);
      a = fmaf(x4, We1[k * 5 + 4], a);
      afr[s][u] = (short)f2bf(fmaxf(a, 0.f));
    }
  }

  f32x16 d0 = {0,0,0,0,0,0,0,0,0,0,0,0,0,0,0,0};
  f32x16 d1 = {0,0,0,0,0,0,0,0,0,0,0,0,0,0,0,0};
  #pragma unroll
  for (int s = 0; s < 4; ++s) {
    bf16x8 b0 = *(const bf16x8*)(Bp3 + (size_t)((s * 2 + 0) * 64 + lane) * 8);
    bf16x8 b1 = *(const bf16x8*)(Bp3 + (size_t)((s * 2 + 1) * 64 + lane) * 8);
    d0 = __builtin_amdgcn_mfma_f32_32x32x16_bf16(afr[s], b0, d0, 0, 0, 0);
    d1 = __builtin_amdgcn_mfma_f32_32x32x16_bf16(afr[s], b1, d1, 0, 0, 0);
  }

  const float b20 = be2[er], b21 = be2[32 + er];
  #pragma unroll
  for (int r = 0; r < 16; ++r) {
    const int m  = (r & 3) + 8 * (r >> 2) + 4 * kh;
    const int eg = ebase + m;
    if (eg < E) {
      unsigned short* p = ef16 + (size_t)eg * HH + er;
      p[0]  = f2bf(d0[r] + b20);
      p[32] = f2bf(d1[r] + b21);
    }
  }
}

// ---------- CSR build ----------
__global__ __launch_bounds__(256) void k_zero(int* __restrict__ p, int n)
{
  int i = blockIdx.x * 256 + threadIdx.x;
  if (i < n) p[i] = 0;
}

__global__ __launch_bounds__(256) void k_deg(
    const int* __restrict__ ei, int* __restrict__ deg, int E)
{
  int e = blockIdx.x * 256 + threadIdx.x;
  if (e >= E) return;
  atomicAdd(&deg[ei[(size_t)E + e]], 1);
}

// --- multi-block exclusive scan of deg (N<=65536: PB<=256 partials) ---
__global__ __launch_bounds__(256) void k_part(
    const int* __restrict__ deg, int* __restrict__ bpart, int N)
{
  __shared__ int s[256];
  int t = threadIdx.x;
  int i = blockIdx.x * 256 + t;
  s[t] = (i < N) ? deg[i] : 0;
  __syncthreads();
  #pragma unroll
  for (int o = 128; o > 0; o >>= 1) {
    if (t < o) s[t] += s[t + o];
    __syncthreads();
  }
  if (t == 0) bpart[blockIdx.x] = s[0];
}

__global__ __launch_bounds__(256) void k_scanpart(
    const int* __restrict__ bpart, int* __restrict__ bbase,
    int* __restrict__ rowptr_last, int PB)
{
  __shared__ int s[256];
  int t = threadIdx.x;
  int v = (t < PB) ? bpart[t] : 0;
  s[t] = v;
  __syncthreads();
  for (int o = 1; o < 256; o <<= 1) {
    int u = (t >= o) ? s[t - o] : 0;
    __syncthreads();
    s[t] += u;
    __syncthreads();
  }
  if (t < PB) bbase[t] = s[t] - v;      // exclusive base per block
  if (t == 255) *rowptr_last = s[255];  // total = rowptr[N]
}

__global__ __launch_bounds__(256) void k_rowptr(
    const int* __restrict__ deg, const int* __restrict__ bbase,
    int* __restrict__ rowptr, int* __restrict__ wofs, int N)
{
  __shared__ int s[256];
  int t = threadIdx.x;
  int i = blockIdx.x * 256 + t;
  int v = (i < N) ? deg[i] : 0;
  s[t] = v;
  __syncthreads();
  for (int o = 1; o < 256; o <<= 1) {
    int u = (t >= o) ? s[t - o] : 0;
    __syncthreads();
    s[t] += u;
    __syncthreads();
  }
  if (i < N) {
    int ex = bbase[blockIdx.x] + s[t] - v;
    rowptr[i] = ex;
    wofs[i]   = ex;
  }
}

__global__ __launch_bounds__(256) void k_scatter(
    const int* __restrict__ ei, int* __restrict__ wofs,
    int* __restrict__ eidx, int E)
{
  int e = blockIdx.x * 256 + threadIdx.x;
  if (e >= E) return;
  int pos = atomicAdd(&wofs[ei[(size_t)E + e]], 1);
  eidx[pos] = e;
}

// ---------- per-iteration edge pipeline, MFMA + bf16 storage ----------
// LAST: fused edge_out = ef' @ Weh^T + beh via LDS row exchange
template <bool LAST>
__global__ __launch_bounds__(256) void k_edge_mfma(
    const unsigned short* __restrict__ nf16, unsigned short* __restrict__ ef16,
    const int* __restrict__ ei,
    const unsigned short* __restrict__ Bp1, const float* __restrict__ battn,
    const unsigned short* __restrict__ Bp2, const float* __restrict__ bvo,
    const float* __restrict__ Weh, const float* __restrict__ beh,
    float* __restrict__ edge_out, int E)
{
  __shared__ __align__(16) unsigned short c_lds[4 * 32 * 64];
  const int tid   = threadIdx.x;
  const int wave  = tid >> 6;
  const int lane  = tid & 63;
  const int er    = lane & 31;   // A row (edge) / D col (feature)
  const int kh    = lane >> 5;   // k-half selector
  const int ebase = blockIdx.x * 128 + wave * 32;

  int e = ebase + er;
  if (e >= E) e = E - 1;
  const int src = ei[e];
  const int dst = ei[(size_t)E + e];
  const unsigned short* ns = nf16 + (size_t)src * HH;
  const unsigned short* nd = nf16 + (size_t)dst * HH;

  f32x16 acc0 = {0,0,0,0,0,0,0,0,0,0,0,0,0,0,0,0};
  f32x16 acc1 = {0,0,0,0,0,0,0,0,0,0,0,0,0,0,0,0};

  // GEMM1: K=128 over 8 steps of 16 (0-3 from ns, 4-7 from nd)
  #pragma unroll
  for (int s = 0; s < 8; ++s) {
    const unsigned short* ap = (s < 4) ? ns : nd;
    bf16x8 a = *(const bf16x8*)(ap + (s & 3) * 16 + kh * 8);
    bf16x8 b0 = *(const bf16x8*)(Bp1 + (size_t)((s * 2 + 0) * 64 + lane) * 8);
    bf16x8 b1 = *(const bf16x8*)(Bp1 + (size_t)((s * 2 + 1) * 64 + lane) * 8);
    acc0 = __builtin_amdgcn_mfma_f32_32x32x16_bf16(a, b0, acc0, 0, 0, 0);
    acc1 = __builtin_amdgcn_mfma_f32_32x32x16_bf16(a, b1, acc1, 0, 0, 0);
  }

  // c = acc + battn -> LDS bf16, row-XOR swizzle
  const float bt0 = battn[er], bt1 = battn[32 + er];
  unsigned short* cw = c_lds + wave * 2048;
  #pragma unroll
  for (int r = 0; r < 16; ++r) {
    const int m  = (r & 3) + 8 * (r >> 2) + 4 * kh;
    const int sw = (m & 7) << 3;
    cw[m * 64 + ((er     ) ^ sw)] = f2bf(acc0[r] + bt0);
    cw[m * 64 + ((32 + er) ^ sw)] = f2bf(acc1[r] + bt1);
  }
  asm volatile("s_waitcnt lgkmcnt(0)" ::: "memory");
  __builtin_amdgcn_sched_barrier(0);

  // GEMM2: K=64 over 4 steps, A from LDS
  f32x16 d0 = {0,0,0,0,0,0,0,0,0,0,0,0,0,0,0,0};
  f32x16 d1 = {0,0,0,0,0,0,0,0,0,0,0,0,0,0,0,0};
  #pragma unroll
  for (int s = 0; s < 4; ++s) {
    const int k0 = s * 16 + kh * 8;
    bf16x8 a2 = *(const bf16x8*)(cw + er * 64 + (k0 ^ ((er & 7) << 3)));
    bf16x8 b0 = *(const bf16x8*)(Bp2 + (size_t)((s * 2 + 0) * 64 + lane) * 8);
    bf16x8 b1 = *(const bf16x8*)(Bp2 + (size_t)((s * 2 + 1) * 64 + lane) * 8);
    d0 = __builtin_amdgcn_mfma_f32_32x32x16_bf16(a2, b0, d0, 0, 0, 0);
    d1 = __builtin_amdgcn_mfma_f32_32x32x16_bf16(a2, b1, d1, 0, 0, 0);
  }

  // epilogue: ef = relu(ef + msg), bf16 RMW; LAST also spills e1 rows to LDS
  const float bv0 = bvo[er], bv1 = bvo[32 + er];
  #pragma unroll
  for (int r = 0; r < 16; ++r) {
    const int m  = (r & 3) + 8 * (r >> 2) + 4 * kh;
    const int eg = ebase + m;
    if (eg < E) {
      unsigned short* p = ef16 + (size_t)eg * HH + er;
      float o0 = bf2f(p[0]), o1 = bf2f(p[32]);
      unsigned short q0 = f2bf(fmaxf(o0 + d0[r] + bv0, 0.f));
      unsigned short q1 = f2bf(fmaxf(o1 + d1[r] + bv1, 0.f));
      p[0]  = q0;
      p[32] = q1;
      if (LAST) {
        const int sw = (m & 7) << 3;
        cw[m * 64 + ((er     ) ^ sw)] = q0;  // overwrite c_lds (GEMM2 done)
        cw[m * 64 + ((32 + er) ^ sw)] = q1;
      }
    }
  }

  if (LAST) {
    // same-wave LDS producer->consumer (rule #18)
    asm volatile("s_waitcnt lgkmcnt(0)" ::: "memory");
    __builtin_amdgcn_sched_barrier(0);
    // lanes 0-31: one edge row each -> 5 outputs
    if (lane < 32) {
      const int eg = ebase + lane;
      if (eg < E) {
        float a0 = beh[0], a1 = beh[1], a2 = beh[2], a3 = beh[3], a4 = beh[4];
        const int sw = (lane & 7) << 3;
        const unsigned short* row = cw + lane * 64;
        #pragma unroll
        for (int f = 0; f < HH; ++f) {
          float x = bf2f(row[f ^ sw]);
          a0 = fmaf(x, Weh[0 * HH + f], a0);
          a1 = fmaf(x, Weh[1 * HH + f], a1);
          a2 = fmaf(x, Weh[2 * HH + f], a2);
          a3 = fmaf(x, Weh[3 * HH + f], a3);
          a4 = fmaf(x, Weh[4 * HH + f], a4);
        }
        float* o = edge_out + (size_t)eg * 5;
        o[0] = a0; o[1] = a1; o[2] = a2; o[3] = a3; o[4] = a4;
      }
    }
  }
}

// ---------- node aggregation via CSR gather (bf16 inputs, f32 agg out) ----------
__global__ __launch_bounds__(256) void k_node_agg(
    const unsigned short* __restrict__ nf16, const unsigned short* __restrict__ ef16,
    const int* __restrict__ ei, const int* __restrict__ rowptr,
    const int* __restrict__ eidx, float* __restrict__ agg, int N, int E)
{
  int gid = blockIdx.x * 256 + threadIdx.x;
  int i = gid >> 4;
  int l = gid & 15;
  if (i >= N) return;
  int b = rowptr[i];
  int t = rowptr[i + 1];
  const int fo = l * 4;
  ushx4 hv = *(const ushx4*)(nf16 + (size_t)i * HH + fo);
  float h0 = bf2f(hv[0]), h1 = bf2f(hv[1]), h2 = bf2f(hv[2]), h3 = bf2f(hv[3]);
  for (int p = b; p < t; ++p) {
    int e = eidx[p];
    int src = ei[e];
    ushx4 ev = *(const ushx4*)(ef16 + (size_t)e * HH + fo);
    ushx4 sv = *(const ushx4*)(nf16 + (size_t)src * HH + fo);
    h0 += fmaxf(bf2f(sv[0]) + bf2f(ev[0]), 0.f);
    h1 += fmaxf(bf2f(sv[1]) + bf2f(ev[1]), 0.f);
    h2 += fmaxf(bf2f(sv[2]) + bf2f(ev[2]), 0.f);
    h3 += fmaxf(bf2f(sv[3]) + bf2f(ev[3]), 0.f);
  }
  float4 out = {h0, h1, h2, h3};
  *(float4*)(agg + (size_t)i * HH + fo) = out;
}

// ---------- node update ----------
template <bool LAST>
__global__ __launch_bounds__(256) void k_node_update(
    const float* __restrict__ Wg1T, const float* __restrict__ bg1,
    const float* __restrict__ Wg2,  const float* __restrict__ bg2,
    const float* __restrict__ WnhT, const float* __restrict__ bnh,
    unsigned short* __restrict__ nf16, const float* __restrict__ agg,
    float* __restrict__ node_out, int N)
{
  int i = blockIdx.x * 256 + threadIdx.x;
  if (i >= N) return;
  const size_t ib = (size_t)i * HH;

  float t1[HH];
  #pragma unroll
  for (int j = 0; j < HH; ++j) t1[j] = bg1[j];

  #pragma unroll 1
  for (int k4 = 0; k4 < 16; ++k4) {
    float4 f = *(const float4*)(agg + ib + k4 * 4);
    #pragma unroll
    for (int u = 0; u < 4; ++u) {
      float x = (&f.x)[u];
      const float* wr = Wg1T + (k4 * 4 + u) * HH;
      #pragma unroll
      for (int j = 0; j < HH; ++j) t1[j] = fmaf(x, wr[j], t1[j]);
    }
  }
  #pragma unroll
  for (int j = 0; j < HH; ++j) t1[j] = fmaxf(t1[j], 0.f);

  float no[10];
  if (LAST) {
    #pragma unroll
    for (int cc = 0; cc < 10; ++cc) no[cc] = bnh[cc];
  }

  #pragma unroll 1
  for (int j8 = 0; j8 < 8; ++j8) {
    bf16x8 ov;
    #pragma unroll
    for (int u = 0; u < 8; ++u) {
      int j = j8 * 8 + u;
      const float* wr = Wg2 + j * HH;
      float a0 = bg2[j], a1 = 0.f, a2 = 0.f, a3 = 0.f;
      #pragma unroll
      for (int k = 0; k < HH; k += 4) {
        a0 = fmaf(t1[k    ], wr[k    ], a0);
        a1 = fmaf(t1[k + 1], wr[k + 1], a1);
        a2 = fmaf(t1[k + 2], wr[k + 2], a2);
        a3 = fmaf(t1[k + 3], wr[k + 3], a3);
      }
      float v = fmaxf((a0 + a1) + (a2 + a3), 0.f);
      ov[u] = (short)f2bf(v);
      if (LAST) {
        const float* wn = WnhT + j * 10;
        #pragma unroll
        for (int cc = 0; cc < 10; ++cc) no[cc] = fmaf(v, wn[cc], no[cc]);
      }
    }
    if (!LAST) *(bf16x8*)(nf16 + ib + j8 * 8) = ov;
  }
  if (LAST) {
    #pragma unroll
    for (int cc = 0; cc < 10; ++cc) node_out[(size_t)i * 10 + cc] = no[cc];
  }
}

extern "C" void kernel_launch(void* const* d_in, const int* in_sizes, int n_in,
                              void* d_out, int out_size, void* d_ws, size_t ws_size,
                              hipStream_t stream)
{
  const float* node_logits = (const float*)d_in[0];
  const float* edge_logits = (const float*)d_in[1];
  const int*   ei          = (const int*)d_in[2];
  const float* Wproj = (const float*)d_in[3];
  const float* bproj = (const float*)d_in[4];
  const float* We1   = (const float*)d_in[5];
  const float* be1   = (const float*)d_in[6];
  const float* We2   = (const float*)d_in[7];
  const float* be2   = (const float*)d_in[8];
  const float* Wg1   = (const float*)d_in[9];
  const float* bg1   = (const float*)d_in[10];
  const float* Wg2   = (const float*)d_in[11];
  const float* bg2   = (const float*)d_in[12];
  const float* Wv    = (const float*)d_in[13];
  const float* bv    = (const float*)d_in[14];
  const float* Wo    = (const float*)d_in[15];
  const float* bo    = (const float*)d_in[16];
  const float* Wattn = (const float*)d_in[17];
  const float* battn = (const float*)d_in[18];
  const float* Wnh   = (const float*)d_in[19];
  const float* bnh   = (const float*)d_in[20];
  const float* Weh   = (const float*)d_in[21];
  const float* beh   = (const float*)d_in[22];

  const int N = in_sizes[0] / 10;
  const int E = in_sizes[1] / 5;

  float* ws = (float*)d_ws;
  size_t off = 0;
  unsigned short* nf16 = (unsigned short*)(ws + off); off += (size_t)N * (HH / 2);
  unsigned short* ef16 = (unsigned short*)(ws + off); off += (size_t)E * (HH / 2);
  float* agg  = ws + off; off += (size_t)N * HH;
  float* Wg1T = ws + off; off += 64 * 64;
  float* WnhT = ws + off; off += 640;
  float* Wvo  = ws + off; off += 64 * 64;
  float* bvo  = ws + off; off += 64;
  unsigned short* Bp1 = (unsigned short*)(ws + off); off += 4096;  // 8192 bf16
  unsigned short* Bp2 = (unsigned short*)(ws + off); off += 2048;  // 4096 bf16
  unsigned short* Bp3 = (unsigned short*)(ws + off); off += 2048;  // 4096 bf16
  int* deg    = (int*)(ws + off); off += N;
  int* rowptr = (int*)(ws + off); off += N + 1;
  int* wofs   = (int*)(ws + off); off += N;
  int* eidx   = (int*)(ws + off); off += E;
  int* bpart  = (int*)(ws + off); off += 256;
  int* bbase  = (int*)(ws + off); off += 256;

  float* node_out = (float*)d_out;
  float* edge_out = node_out + (size_t)N * 10;

  const int nb_n    = (N + 255) / 256;
  const int nb_e    = (E + 255) / 256;
  const int nb_a    = ((N * 16) + 255) / 256;
  const int nb_e128 = (E + 127) / 128;
  const int PB      = (N + 255) / 256;   // scan partial blocks (<=256 for N<=65536)

  k_prep<<<32, 256, 0, stream>>>(Wattn, Wg1, Wnh, Wo, Wv, bv, bo, We2,
                                 Wg1T, WnhT, Wvo, bvo, Bp1, Bp3);
  k_prep2<<<16, 256, 0, stream>>>(Wvo, Bp2);
  k_zero<<<nb_n, 256, 0, stream>>>(deg, N);
  k_node_init<<<nb_n, 256, 0, stream>>>(node_logits, Wproj, bproj, nf16, N);
  k_edge_init_mfma<<<nb_e128, 256, 0, stream>>>(edge_logits, We1, be1, Bp3, be2,
                                                ef16, E);
  k_deg<<<nb_e, 256, 0, stream>>>(ei, deg, E);
  k_part<<<PB, 256, 0, stream>>>(deg, bpart, N);
  k_scanpart<<<1, 256, 0, stream>>>(bpart, bbase, rowptr + N, PB);
  k_rowptr<<<PB, 256, 0, stream>>>(deg, bbase, rowptr, wofs, N);
  k_scatter<<<nb_e, 256, 0, stream>>>(ei, wofs, eidx, E);

  // iteration 1
  k_edge_mfma<false><<<nb_e128, 256, 0, stream>>>(nf16, ef16, ei, Bp1, battn,
                                                  Bp2, bvo, Weh, beh, edge_out, E);
  k_node_agg<<<nb_a, 256, 0, stream>>>(nf16, ef16, ei, rowptr, eidx, agg, N, E);
  k_node_update<false><<<nb_n, 256, 0, stream>>>(Wg1T, bg1, Wg2, bg2, WnhT, bnh,
                                                 nf16, agg, node_out, N);
  // iteration 2
  k_edge_mfma<true><<<nb_e128, 256, 0, stream>>>(nf16, ef16, ei, Bp1, battn,
                                                 Bp2, bvo, Weh, beh, edge_out, E);
  k_node_agg<<<nb_a, 256, 0, stream>>>(nf16, ef16, ei, rowptr, eidx, agg, N, E);
  k_node_update<true><<<nb_n, 256, 0, stream>>>(Wg1T, bg1, Wg2, bg2, WnhT, bnh,
                                                nf16, agg, node_out, N);
}

// Round 7
// 472.056 us; speedup vs baseline: 12.8111x; 1.3854x over previous
//
#include <hip/hip_runtime.h>

#define HH 64

typedef __attribute__((ext_vector_type(8))) short bf16x8;
typedef __attribute__((ext_vector_type(16))) float f32x16;
typedef __attribute__((ext_vector_type(4))) unsigned short ushx4;
typedef __attribute__((ext_vector_type(8))) unsigned short ushx8;

__device__ __forceinline__ unsigned short f2bf(float f) {
  unsigned u = __builtin_bit_cast(unsigned, f);
  return (unsigned short)((u + 0x7FFFu + ((u >> 16) & 1u)) >> 16);
}
__device__ __forceinline__ float bf2f(unsigned short h) {
  unsigned u = ((unsigned)h) << 16;
  return __builtin_bit_cast(float, u);
}

// ---------- prep: Wvo = Wo@Wv, bvo = Wo@bv + bo, B-fragment packs ----------
// pack formula (validated r3-r5): for W[n][k] row-major, 64x64:
//   idx = ((s*2+t)*64 + ln)*8 + e8 ; n = t*32 + (ln&31); k = s*16 + (ln>>5)*8 + e8
__global__ __launch_bounds__(256) void k_prep(
    const float* __restrict__ Wattn, const float* __restrict__ Wg1,
    const float* __restrict__ Wg2,   const float* __restrict__ Wnh,
    const float* __restrict__ Wo,    const float* __restrict__ Wv,
    const float* __restrict__ bv,    const float* __restrict__ bo,
    const float* __restrict__ We2,
    float* __restrict__ Wvo, float* __restrict__ bvo,
    unsigned short* __restrict__ Bp1, unsigned short* __restrict__ Bp3,
    unsigned short* __restrict__ Bp4, unsigned short* __restrict__ Bp5,
    unsigned short* __restrict__ Bp6)
{
  int idx = blockIdx.x * 256 + threadIdx.x;
  if (idx < 4096) {                // Wvo[j][k] = sum_l Wo[j][l] Wv[l][k]
    int j = idx >> 6, k = idx & 63;
    float a = 0.f;
    #pragma unroll 4
    for (int l = 0; l < 64; ++l) a = fmaf(Wo[j * 64 + l], Wv[l * 64 + k], a);
    Wvo[idx] = a;
  }
  if (idx < 64) {                  // bvo[j] = sum_l Wo[j][l] bv[l] + bo[j]
    float a = bo[idx];
    for (int l = 0; l < 64; ++l) a = fmaf(Wo[idx * 64 + l], bv[l], a);
    bvo[idx] = a;
  }
  if (idx < 8192) {                // Bp1: Wattn (K=128)
    int e8 = idx & 7, ln = (idx >> 3) & 63, t = (idx >> 9) & 1, s = idx >> 10;
    int n = t * 32 + (ln & 31);
    int k = s * 16 + (ln >> 5) * 8 + e8;
    Bp1[idx] = f2bf(Wattn[n * 128 + k]);
  }
  if (idx < 4096) {                // Bp3: We2, Bp4: Wg1, Bp5: Wg2 (K=64)
    int e8 = idx & 7, ln = (idx >> 3) & 63, t = (idx >> 9) & 1, s = idx >> 10;
    int n = t * 32 + (ln & 31);
    int k = s * 16 + (ln >> 5) * 8 + e8;
    Bp3[idx] = f2bf(We2[n * 64 + k]);
    Bp4[idx] = f2bf(Wg1[n * 64 + k]);
    Bp5[idx] = f2bf(Wg2[n * 64 + k]);
  }
  if (idx < 2048) {                // Bp6: Wnh zero-padded to 32 cols (t=0 only)
    int e8 = idx & 7, ln = (idx >> 3) & 63, s = idx >> 9;
    int n = ln & 31;
    int k = s * 16 + (ln >> 5) * 8 + e8;
    Bp6[idx] = (n < 10) ? f2bf(Wnh[n * 64 + k]) : (unsigned short)0;
  }
}

// ---------- prep2: Bp2 from Wvo (after k_prep) ----------
__global__ __launch_bounds__(256) void k_prep2(
    const float* __restrict__ Wvo, unsigned short* __restrict__ Bp2)
{
  int idx = blockIdx.x * 256 + threadIdx.x;
  if (idx < 4096) {
    int e8 = idx & 7, ln = (idx >> 3) & 63, t = (idx >> 9) & 1, s = idx >> 10;
    int n = t * 32 + (ln & 31);
    int k = s * 16 + (ln >> 5) * 8 + e8;
    Bp2[idx] = f2bf(Wvo[n * 64 + k]);
  }
}

// ---------- node init: nf16 = bf16(nl @ Wproj^T + bproj) ----------
__global__ __launch_bounds__(256) void k_node_init(
    const float* __restrict__ nl, const float* __restrict__ Wproj,
    const float* __restrict__ bproj, unsigned short* __restrict__ nf16, int N)
{
  int i = blockIdx.x * 256 + threadIdx.x;
  if (i >= N) return;
  float x[10];
  #pragma unroll
  for (int k = 0; k < 10; ++k) x[k] = nl[(size_t)i * 10 + k];
  const size_t ib = (size_t)i * HH;
  #pragma unroll 1
  for (int j8 = 0; j8 < 8; ++j8) {
    bf16x8 v;
    #pragma unroll
    for (int u = 0; u < 8; ++u) {
      int j = j8 * 8 + u;
      float a = bproj[j];
      #pragma unroll
      for (int k = 0; k < 10; ++k) a = fmaf(x[k], Wproj[j * 10 + k], a);
      v[u] = (short)f2bf(a);
    }
    *(bf16x8*)(nf16 + ib + j8 * 8) = v;
  }
}

// ---------- CSR build ----------
__global__ __launch_bounds__(256) void k_zero(int* __restrict__ p, int n)
{
  int i = blockIdx.x * 256 + threadIdx.x;
  if (i < n) p[i] = 0;
}

__global__ __launch_bounds__(256) void k_deg(
    const int* __restrict__ ei, int* __restrict__ deg, int E)
{
  int e = blockIdx.x * 256 + threadIdx.x;
  if (e >= E) return;
  atomicAdd(&deg[ei[(size_t)E + e]], 1);
}

__global__ __launch_bounds__(256) void k_part(
    const int* __restrict__ deg, int* __restrict__ bpart, int N)
{
  __shared__ int s[256];
  int t = threadIdx.x;
  int i = blockIdx.x * 256 + t;
  s[t] = (i < N) ? deg[i] : 0;
  __syncthreads();
  #pragma unroll
  for (int o = 128; o > 0; o >>= 1) {
    if (t < o) s[t] += s[t + o];
    __syncthreads();
  }
  if (t == 0) bpart[blockIdx.x] = s[0];
}

__global__ __launch_bounds__(256) void k_scanpart(
    const int* __restrict__ bpart, int* __restrict__ bbase,
    int* __restrict__ rowptr_last, int PB)
{
  __shared__ int s[256];
  int t = threadIdx.x;
  int v = (t < PB) ? bpart[t] : 0;
  s[t] = v;
  __syncthreads();
  for (int o = 1; o < 256; o <<= 1) {
    int u = (t >= o) ? s[t - o] : 0;
    __syncthreads();
    s[t] += u;
    __syncthreads();
  }
  if (t < PB) bbase[t] = s[t] - v;
  if (t == 255) *rowptr_last = s[255];
}

__global__ __launch_bounds__(256) void k_rowptr(
    const int* __restrict__ deg, const int* __restrict__ bbase,
    int* __restrict__ rowptr, int* __restrict__ wofs, int N)
{
  __shared__ int s[256];
  int t = threadIdx.x;
  int i = blockIdx.x * 256 + t;
  int v = (i < N) ? deg[i] : 0;
  s[t] = v;
  __syncthreads();
  for (int o = 1; o < 256; o <<= 1) {
    int u = (t >= o) ? s[t - o] : 0;
    __syncthreads();
    s[t] += u;
    __syncthreads();
  }
  if (i < N) {
    int ex = bbase[blockIdx.x] + s[t] - v;
    rowptr[i] = ex;
    wofs[i]   = ex;
  }
}

// scatter into CSR slots: slot arrays srcp/dstp/eorig
__global__ __launch_bounds__(256) void k_scatter(
    const int* __restrict__ ei, int* __restrict__ wofs,
    int* __restrict__ eorig, int* __restrict__ srcp, int* __restrict__ dstp,
    int E)
{
  int e = blockIdx.x * 256 + threadIdx.x;
  if (e >= E) return;
  int src = ei[e];
  int dst = ei[(size_t)E + e];
  int pos = atomicAdd(&wofs[dst], 1);
  eorig[pos] = e;
  srcp[pos]  = src;
  dstp[pos]  = dst;
}

// ---------- edge init (CSR slot order): ef16[p] = bf16(relu(el[eorig[p]]@We1^T+be1)@We2^T+be2) ----------
__global__ __launch_bounds__(256) void k_edge_init_mfma(
    const float* __restrict__ el, const float* __restrict__ We1,
    const float* __restrict__ be1, const unsigned short* __restrict__ Bp3,
    const float* __restrict__ be2, const int* __restrict__ eorig,
    unsigned short* __restrict__ ef16, int E)
{
  const int tid   = threadIdx.x;
  const int wave  = tid >> 6;
  const int lane  = tid & 63;
  const int er    = lane & 31;
  const int kh    = lane >> 5;
  const int ebase = blockIdx.x * 128 + wave * 32;

  int p = ebase + er;
  if (p >= E) p = E - 1;
  const int eo = eorig[p];
  const float x0 = el[(size_t)eo * 5 + 0], x1 = el[(size_t)eo * 5 + 1],
              x2 = el[(size_t)eo * 5 + 2], x3 = el[(size_t)eo * 5 + 3],
              x4 = el[(size_t)eo * 5 + 4];

  bf16x8 afr[4];
  #pragma unroll
  for (int s = 0; s < 4; ++s) {
    #pragma unroll
    for (int u = 0; u < 8; ++u) {
      const int k = s * 16 + kh * 8 + u;
      float a = be1[k];
      a = fmaf(x0, We1[k * 5 + 0], a);
      a = fmaf(x1, We1[k * 5 + 1], a);
      a = fmaf(x2, We1[k * 5 + 2], a);
      a = fmaf(x3, We1[k * 5 + 3], a);
      a = fmaf(x4, We1[k * 5 + 4], a);
      afr[s][u] = (short)f2bf(fmaxf(a, 0.f));
    }
  }

  f32x16 d0 = {0,0,0,0,0,0,0,0,0,0,0,0,0,0,0,0};
  f32x16 d1 = {0,0,0,0,0,0,0,0,0,0,0,0,0,0,0,0};
  #pragma unroll
  for (int s = 0; s < 4; ++s) {
    bf16x8 b0 = *(const bf16x8*)(Bp3 + (size_t)((s * 2 + 0) * 64 + lane) * 8);
    bf16x8 b1 = *(const bf16x8*)(Bp3 + (size_t)((s * 2 + 1) * 64 + lane) * 8);
    d0 = __builtin_amdgcn_mfma_f32_32x32x16_bf16(afr[s], b0, d0, 0, 0, 0);
    d1 = __builtin_amdgcn_mfma_f32_32x32x16_bf16(afr[s], b1, d1, 0, 0, 0);
  }

  const float b20 = be2[er], b21 = be2[32 + er];
  #pragma unroll
  for (int r = 0; r < 16; ++r) {
    const int m  = (r & 3) + 8 * (r >> 2) + 4 * kh;
    const int pg = ebase + m;
    if (pg < E) {
      unsigned short* q = ef16 + (size_t)pg * HH + er;
      q[0]  = f2bf(d0[r] + b20);
      q[32] = f2bf(d1[r] + b21);
    }
  }
}

// ---------- per-iteration edge pipeline (CSR slots, prefetched vector RMW) ----------
template <bool LAST>
__global__ __launch_bounds__(256) void k_edge_mfma(
    const unsigned short* __restrict__ nf16, unsigned short* __restrict__ ef16,
    const int* __restrict__ srcp, const int* __restrict__ dstp,
    const int* __restrict__ eorig,
    const unsigned short* __restrict__ Bp1, const float* __restrict__ battn,
    const unsigned short* __restrict__ Bp2, const float* __restrict__ bvo,
    const float* __restrict__ Weh, const float* __restrict__ beh,
    float* __restrict__ edge_out, int E)
{
  __shared__ __align__(16) unsigned short c_lds[4 * 32 * 64];
  const int tid   = threadIdx.x;
  const int wave  = tid >> 6;
  const int lane  = tid & 63;
  const int er    = lane & 31;   // A row (slot) / D col (feature)
  const int kh    = lane >> 5;
  const int ebase = blockIdx.x * 128 + wave * 32;

  // --- prefetch this wave's ef rows (linear layout: lane -> row lane>>1, half lane&1)
  const int rm = lane >> 1;           // RMW row 0..31
  const int hb = lane & 1;            // RMW half 0/1
  int rslot = ebase + rm;
  if (rslot >= E) rslot = E - 1;
  const size_t rbase = (size_t)rslot * HH + hb * 32;
  ushx8 efp[4];
  #pragma unroll
  for (int j = 0; j < 4; ++j)
    efp[j] = *(const ushx8*)(ef16 + rbase + j * 8);

  int p = ebase + er;
  if (p >= E) p = E - 1;
  const int src = srcp[p];
  const int dst = dstp[p];
  const unsigned short* ns = nf16 + (size_t)src * HH;
  const unsigned short* nd = nf16 + (size_t)dst * HH;

  f32x16 acc0 = {0,0,0,0,0,0,0,0,0,0,0,0,0,0,0,0};
  f32x16 acc1 = {0,0,0,0,0,0,0,0,0,0,0,0,0,0,0,0};

  #pragma unroll
  for (int s = 0; s < 8; ++s) {
    const unsigned short* ap = (s < 4) ? ns : nd;
    bf16x8 a = *(const bf16x8*)(ap + (s & 3) * 16 + kh * 8);
    bf16x8 b0 = *(const bf16x8*)(Bp1 + (size_t)((s * 2 + 0) * 64 + lane) * 8);
    bf16x8 b1 = *(const bf16x8*)(Bp1 + (size_t)((s * 2 + 1) * 64 + lane) * 8);
    acc0 = __builtin_amdgcn_mfma_f32_32x32x16_bf16(a, b0, acc0, 0, 0, 0);
    acc1 = __builtin_amdgcn_mfma_f32_32x32x16_bf16(a, b1, acc1, 0, 0, 0);
  }

  // c -> LDS (bf16, row-XOR swizzle)
  const float bt0 = battn[er], bt1 = battn[32 + er];
  unsigned short* cw = c_lds + wave * 2048;
  #pragma unroll
  for (int r = 0; r < 16; ++r) {
    const int m  = (r & 3) + 8 * (r >> 2) + 4 * kh;
    const int sw = (m & 7) << 3;
    cw[m * 64 + ((er     ) ^ sw)] = f2bf(acc0[r] + bt0);
    cw[m * 64 + ((32 + er) ^ sw)] = f2bf(acc1[r] + bt1);
  }
  asm volatile("s_waitcnt lgkmcnt(0)" ::: "memory");
  __builtin_amdgcn_sched_barrier(0);

  f32x16 d0 = {0,0,0,0,0,0,0,0,0,0,0,0,0,0,0,0};
  f32x16 d1 = {0,0,0,0,0,0,0,0,0,0,0,0,0,0,0,0};
  #pragma unroll
  for (int s = 0; s < 4; ++s) {
    const int k0 = s * 16 + kh * 8;
    bf16x8 a2 = *(const bf16x8*)(cw + er * 64 + (k0 ^ ((er & 7) << 3)));
    bf16x8 b0 = *(const bf16x8*)(Bp2 + (size_t)((s * 2 + 0) * 64 + lane) * 8);
    bf16x8 b1 = *(const bf16x8*)(Bp2 + (size_t)((s * 2 + 1) * 64 + lane) * 8);
    d0 = __builtin_amdgcn_mfma_f32_32x32x16_bf16(a2, b0, d0, 0, 0, 0);
    d1 = __builtin_amdgcn_mfma_f32_32x32x16_bf16(a2, b1, d1, 0, 0, 0);
  }

  // spill msg' = d + bvo into cw (GEMM2 reads done; same-wave DS is in-order)
  asm volatile("s_waitcnt lgkmcnt(0)" ::: "memory");
  const float bv0 = bvo[er], bv1 = bvo[32 + er];
  #pragma unroll
  for (int r = 0; r < 16; ++r) {
    const int m  = (r & 3) + 8 * (r >> 2) + 4 * kh;
    const int sw = (m & 7) << 3;
    cw[m * 64 + ((er     ) ^ sw)] = f2bf(d0[r] + bv0);
    cw[m * 64 + ((32 + er) ^ sw)] = f2bf(d1[r] + bv1);
  }
  asm volatile("s_waitcnt lgkmcnt(0)" ::: "memory");
  __builtin_amdgcn_sched_barrier(0);

  // RMW: ef = relu(ef + msg), vectorized; optional head partials for LAST
  float a0 = 0.f, a1 = 0.f, a2s = 0.f, a3 = 0.f, a4 = 0.f;
  const int r7 = rm & 7;
  #pragma unroll
  for (int j = 0; j < 4; ++j) {
    const int g = hb * 4 + j;
    ushx8 mg = *(const ushx8*)(cw + rm * 64 + ((g ^ r7) << 3));
    ushx8 q;
    #pragma unroll
    for (int u = 0; u < 8; ++u) {
      float x = fmaxf(bf2f(efp[j][u]) + bf2f(mg[u]), 0.f);
      unsigned short xq = f2bf(x);
      q[u] = xq;
      if (LAST) {
        const int f = hb * 32 + j * 8 + u;
        float xv = bf2f(xq);
        a0 = fmaf(xv, Weh[0 * HH + f], a0);
        a1 = fmaf(xv, Weh[1 * HH + f], a1);
        a2s = fmaf(xv, Weh[2 * HH + f], a2s);
        a3 = fmaf(xv, Weh[3 * HH + f], a3);
        a4 = fmaf(xv, Weh[4 * HH + f], a4);
      }
    }
    if (ebase + rm < E)
      *(ushx8*)(ef16 + rbase + j * 8) = q;
  }

  if (LAST) {
    a0 += __shfl_xor(a0, 1);
    a1 += __shfl_xor(a1, 1);
    a2s += __shfl_xor(a2s, 1);
    a3 += __shfl_xor(a3, 1);
    a4 += __shfl_xor(a4, 1);
    if (hb == 0 && ebase + rm < E) {
      const int eo = eorig[ebase + rm];
      float* o = edge_out + (size_t)eo * 5;
      o[0] = a0 + beh[0]; o[1] = a1 + beh[1]; o[2] = a2s + beh[2];
      o[3] = a3 + beh[3]; o[4] = a4 + beh[4];
    }
  }
}

// ---------- node aggregation: sequential CSR rows, bf16 out ----------
__global__ __launch_bounds__(256) void k_node_agg(
    const unsigned short* __restrict__ nf16, const unsigned short* __restrict__ ef16,
    const int* __restrict__ srcp, const int* __restrict__ rowptr,
    unsigned short* __restrict__ agg16, int N)
{
  int gid = blockIdx.x * 256 + threadIdx.x;
  int i = gid >> 4;
  int l = gid & 15;
  if (i >= N) return;
  int b = rowptr[i];
  int t = rowptr[i + 1];
  const int fo = l * 4;
  ushx4 hv = *(const ushx4*)(nf16 + (size_t)i * HH + fo);
  float h0 = bf2f(hv[0]), h1 = bf2f(hv[1]), h2 = bf2f(hv[2]), h3 = bf2f(hv[3]);
  for (int p = b; p < t; ++p) {
    int src = srcp[p];
    ushx4 ev = *(const ushx4*)(ef16 + (size_t)p * HH + fo);
    ushx4 sv = *(const ushx4*)(nf16 + (size_t)src * HH + fo);
    h0 += fmaxf(bf2f(sv[0]) + bf2f(ev[0]), 0.f);
    h1 += fmaxf(bf2f(sv[1]) + bf2f(ev[1]), 0.f);
    h2 += fmaxf(bf2f(sv[2]) + bf2f(ev[2]), 0.f);
    h3 += fmaxf(bf2f(sv[3]) + bf2f(ev[3]), 0.f);
  }
  ushx4 out = { f2bf(h0), f2bf(h1), f2bf(h2), f2bf(h3) };
  *(ushx4*)(agg16 + (size_t)i * HH + fo) = out;
}

// ---------- node MLP via MFMA: nf' = relu(relu(agg@Wg1^T+bg1)@Wg2^T+bg2) ----------
// LAST: node_out = nf' @ Wnh^T + bnh via zero-padded head GEMM
template <bool LAST>
__global__ __launch_bounds__(256) void k_node_mlp(
    const unsigned short* __restrict__ agg16,
    const unsigned short* __restrict__ Bp4, const float* __restrict__ bg1,
    const unsigned short* __restrict__ Bp5, const float* __restrict__ bg2,
    const unsigned short* __restrict__ Bp6, const float* __restrict__ bnh,
    unsigned short* __restrict__ nf16, float* __restrict__ node_out, int N)
{
  __shared__ __align__(16) unsigned short c_lds[4 * 32 * 64];
  const int tid   = threadIdx.x;
  const int wave  = tid >> 6;
  const int lane  = tid & 63;
  const int er    = lane & 31;
  const int kh    = lane >> 5;
  const int nbase = blockIdx.x * 128 + wave * 32;
  if (nbase >= N) return;

  int node = nbase + er;
  if (node >= N) node = N - 1;
  const unsigned short* ar = agg16 + (size_t)node * HH;

  // GEMM g1: t1 = agg @ Wg1^T (K=64)
  f32x16 acc0 = {0,0,0,0,0,0,0,0,0,0,0,0,0,0,0,0};
  f32x16 acc1 = {0,0,0,0,0,0,0,0,0,0,0,0,0,0,0,0};
  #pragma unroll
  for (int s = 0; s < 4; ++s) {
    bf16x8 a = *(const bf16x8*)(ar + s * 16 + kh * 8);
    bf16x8 b0 = *(const bf16x8*)(Bp4 + (size_t)((s * 2 + 0) * 64 + lane) * 8);
    bf16x8 b1 = *(const bf16x8*)(Bp4 + (size_t)((s * 2 + 1) * 64 + lane) * 8);
    acc0 = __builtin_amdgcn_mfma_f32_32x32x16_bf16(a, b0, acc0, 0, 0, 0);
    acc1 = __builtin_amdgcn_mfma_f32_32x32x16_bf16(a, b1, acc1, 0, 0, 0);
  }

  // t1 = relu(acc + bg1) -> LDS swizzled
  const float bg10 = bg1[er], bg11 = bg1[32 + er];
  unsigned short* cw = c_lds + wave * 2048;
  #pragma unroll
  for (int r = 0; r < 16; ++r) {
    const int m  = (r & 3) + 8 * (r >> 2) + 4 * kh;
    const int sw = (m & 7) << 3;
    cw[m * 64 + ((er     ) ^ sw)] = f2bf(fmaxf(acc0[r] + bg10, 0.f));
    cw[m * 64 + ((32 + er) ^ sw)] = f2bf(fmaxf(acc1[r] + bg11, 0.f));
  }
  asm volatile("s_waitcnt lgkmcnt(0)" ::: "memory");
  __builtin_amdgcn_sched_barrier(0);

  // GEMM g2
  f32x16 d0 = {0,0,0,0,0,0,0,0,0,0,0,0,0,0,0,0};
  f32x16 d1 = {0,0,0,0,0,0,0,0,0,0,0,0,0,0,0,0};
  #pragma unroll
  for (int s = 0; s < 4; ++s) {
    const int k0 = s * 16 + kh * 8;
    bf16x8 a2 = *(const bf16x8*)(cw + er * 64 + (k0 ^ ((er & 7) << 3)));
    bf16x8 b0 = *(const bf16x8*)(Bp5 + (size_t)((s * 2 + 0) * 64 + lane) * 8);
    bf16x8 b1 = *(const bf16x8*)(Bp5 + (size_t)((s * 2 + 1) * 64 + lane) * 8);
    d0 = __builtin_amdgcn_mfma_f32_32x32x16_bf16(a2, b0, d0, 0, 0, 0);
    d1 = __builtin_amdgcn_mfma_f32_32x32x16_bf16(a2, b1, d1, 0, 0, 0);
  }

  const float bg20 = bg2[er], bg21 = bg2[32 + er];
  if (!LAST) {
    // write nf16 rows in D-layout (64B contiguous per instr)
    #pragma unroll
    for (int r = 0; r < 16; ++r) {
      const int m  = (r & 3) + 8 * (r >> 2) + 4 * kh;
      const int ng = nbase + m;
      if (ng < N) {
        unsigned short* q = nf16 + (size_t)ng * HH + er;
        q[0]  = f2bf(fmaxf(d0[r] + bg20, 0.f));
        q[32] = f2bf(fmaxf(d1[r] + bg21, 0.f));
      }
    }
  } else {
    // spill v -> LDS, head GEMM with zero-padded Wnh
    asm volatile("s_waitcnt lgkmcnt(0)" ::: "memory");
    #pragma unroll
    for (int r = 0; r < 16; ++r) {
      const int m  = (r & 3) + 8 * (r >> 2) + 4 * kh;
      const int sw = (m & 7) << 3;
      cw[m * 64 + ((er     ) ^ sw)] = f2bf(fmaxf(d0[r] + bg20, 0.f));
      cw[m * 64 + ((32 + er) ^ sw)] = f2bf(fmaxf(d1[r] + bg21, 0.f));
    }
    asm volatile("s_waitcnt lgkmcnt(0)" ::: "memory");
    __builtin_amdgcn_sched_barrier(0);

    f32x16 hacc = {0,0,0,0,0,0,0,0,0,0,0,0,0,0,0,0};
    #pragma unroll
    for (int s = 0; s < 4; ++s) {
      const int k0 = s * 16 + kh * 8;
      bf16x8 a2 = *(const bf16x8*)(cw + er * 64 + (k0 ^ ((er & 7) << 3)));
      bf16x8 b = *(const bf16x8*)(Bp6 + (size_t)(s * 64 + lane) * 8);
      hacc = __builtin_amdgcn_mfma_f32_32x32x16_bf16(a2, b, hacc, 0, 0, 0);
    }
    if (er < 10) {
      const float bn = bnh[er];
      #pragma unroll
      for (int r = 0; r < 16; ++r) {
        const int m  = (r & 3) + 8 * (r >> 2) + 4 * kh;
        const int ng = nbase + m;
        if (ng < N) node_out[(size_t)ng * 10 + er] = hacc[r] + bn;
      }
    }
  }
}

extern "C" void kernel_launch(void* const* d_in, const int* in_sizes, int n_in,
                              void* d_out, int out_size, void* d_ws, size_t ws_size,
                              hipStream_t stream)
{
  const float* node_logits = (const float*)d_in[0];
  const float* edge_logits = (const float*)d_in[1];
  const int*   ei          = (const int*)d_in[2];
  const float* Wproj = (const float*)d_in[3];
  const float* bproj = (const float*)d_in[4];
  const float* We1   = (const float*)d_in[5];
  const float* be1   = (const float*)d_in[6];
  const float* We2   = (const float*)d_in[7];
  const float* be2   = (const float*)d_in[8];
  const float* Wg1   = (const float*)d_in[9];
  const float* bg1   = (const float*)d_in[10];
  const float* Wg2   = (const float*)d_in[11];
  const float* bg2   = (const float*)d_in[12];
  const float* Wv    = (const float*)d_in[13];
  const float* bv    = (const float*)d_in[14];
  const float* Wo    = (const float*)d_in[15];
  const float* bo    = (const float*)d_in[16];
  const float* Wattn = (const float*)d_in[17];
  const float* battn = (const float*)d_in[18];
  const float* Wnh   = (const float*)d_in[19];
  const float* bnh   = (const float*)d_in[20];
  const float* Weh   = (const float*)d_in[21];
  const float* beh   = (const float*)d_in[22];

  const int N = in_sizes[0] / 10;
  const int E = in_sizes[1] / 5;

  float* ws = (float*)d_ws;
  size_t off = 0;
  unsigned short* nf16  = (unsigned short*)(ws + off); off += (size_t)N * (HH / 2);
  unsigned short* ef16  = (unsigned short*)(ws + off); off += (size_t)E * (HH / 2);
  unsigned short* agg16 = (unsigned short*)(ws + off); off += (size_t)N * (HH / 2);
  float* Wvo = ws + off; off += 64 * 64;
  float* bvo = ws + off; off += 64;
  unsigned short* Bp1 = (unsigned short*)(ws + off); off += 4096;  // 8192 bf16
  unsigned short* Bp2 = (unsigned short*)(ws + off); off += 2048;
  unsigned short* Bp3 = (unsigned short*)(ws + off); off += 2048;
  unsigned short* Bp4 = (unsigned short*)(ws + off); off += 2048;
  unsigned short* Bp5 = (unsigned short*)(ws + off); off += 2048;
  unsigned short* Bp6 = (unsigned short*)(ws + off); off += 1024;  // 2048 bf16
  int* deg    = (int*)(ws + off); off += N;
  int* rowptr = (int*)(ws + off); off += N + 1;
  int* wofs   = (int*)(ws + off); off += N;
  int* eorig  = (int*)(ws + off); off += E;
  int* srcp   = (int*)(ws + off); off += E;
  int* dstp   = (int*)(ws + off); off += E;
  int* bpart  = (int*)(ws + off); off += 256;
  int* bbase  = (int*)(ws + off); off += 256;

  float* node_out = (float*)d_out;
  float* edge_out = node_out + (size_t)N * 10;

  const int nb_n    = (N + 255) / 256;
  const int nb_e    = (E + 255) / 256;
  const int nb_a    = ((N * 16) + 255) / 256;
  const int nb_e128 = (E + 127) / 128;
  const int nb_n128 = (N + 127) / 128;
  const int PB      = (N + 255) / 256;

  k_prep<<<32, 256, 0, stream>>>(Wattn, Wg1, Wg2, Wnh, Wo, Wv, bv, bo, We2,
                                 Wvo, bvo, Bp1, Bp3, Bp4, Bp5, Bp6);
  k_prep2<<<16, 256, 0, stream>>>(Wvo, Bp2);
  k_zero<<<nb_n, 256, 0, stream>>>(deg, N);
  k_node_init<<<nb_n, 256, 0, stream>>>(node_logits, Wproj, bproj, nf16, N);
  k_deg<<<nb_e, 256, 0, stream>>>(ei, deg, E);
  k_part<<<PB, 256, 0, stream>>>(deg, bpart, N);
  k_scanpart<<<1, 256, 0, stream>>>(bpart, bbase, rowptr + N, PB);
  k_rowptr<<<PB, 256, 0, stream>>>(deg, bbase, rowptr, wofs, N);
  k_scatter<<<nb_e, 256, 0, stream>>>(ei, wofs, eorig, srcp, dstp, E);
  k_edge_init_mfma<<<nb_e128, 256, 0, stream>>>(edge_logits, We1, be1, Bp3, be2,
                                                eorig, ef16, E);

  // iteration 1
  k_edge_mfma<false><<<nb_e128, 256, 0, stream>>>(nf16, ef16, srcp, dstp, eorig,
                                                  Bp1, battn, Bp2, bvo,
                                                  Weh, beh, edge_out, E);
  k_node_agg<<<nb_a, 256, 0, stream>>>(nf16, ef16, srcp, rowptr, agg16, N);
  k_node_mlp<false><<<nb_n128, 256, 0, stream>>>(agg16, Bp4, bg1, Bp5, bg2,
                                                 Bp6, bnh, nf16, node_out, N);
  // iteration 2
  k_edge_mfma<true><<<nb_e128, 256, 0, stream>>>(nf16, ef16, srcp, dstp, eorig,
                                                 Bp1, battn, Bp2, bvo,
                                                 Weh, beh, edge_out, E);
  k_node_agg<<<nb_a, 256, 0, stream>>>(nf16, ef16, srcp, rowptr, agg16, N);
  k_node_mlp<true><<<nb_n128, 256, 0, stream>>>(agg16, Bp4, bg1, Bp5, bg2,
                                                Bp6, bnh, nf16, node_out, N);
}

// Round 8
// 456.018 us; speedup vs baseline: 13.2617x; 1.0352x over previous
//
#include <hip/hip_runtime.h>

#define HH 64

typedef __attribute__((ext_vector_type(8))) short bf16x8;
typedef __attribute__((ext_vector_type(16))) float f32x16;
typedef __attribute__((ext_vector_type(4))) unsigned short ushx4;

__device__ __forceinline__ unsigned short f2bf(float f) {
  unsigned u = __builtin_bit_cast(unsigned, f);
  return (unsigned short)((u + 0x7FFFu + ((u >> 16) & 1u)) >> 16);
}
__device__ __forceinline__ float bf2f(unsigned short h) {
  unsigned u = ((unsigned)h) << 16;
  return __builtin_bit_cast(float, u);
}

// ---------- prep ----------
// EVEN/ODD B-fragment pack: tile t=0 -> even output features, t=1 -> odd.
//   n = 2*(ln&31) + t ; k = s*16 + (ln>>5)*8 + e8
// => acc0 col er = feature 2er, acc1 col er = feature 2er+1 (adjacent, one u32).
__global__ __launch_bounds__(256) void k_prep(
    const float* __restrict__ Wattn, const float* __restrict__ Wg1,
    const float* __restrict__ Wg2,   const float* __restrict__ Wnh,
    const float* __restrict__ Wo,    const float* __restrict__ Wv,
    const float* __restrict__ bv,    const float* __restrict__ bo,
    const float* __restrict__ We2,
    float* __restrict__ Wvo, float* __restrict__ bvo,
    unsigned short* __restrict__ Bp1, unsigned short* __restrict__ Bp3,
    unsigned short* __restrict__ Bp4, unsigned short* __restrict__ Bp5,
    unsigned short* __restrict__ Bp6)
{
  int idx = blockIdx.x * 256 + threadIdx.x;
  if (idx < 4096) {                // Wvo[j][k] = sum_l Wo[j][l] Wv[l][k]
    int j = idx >> 6, k = idx & 63;
    float a = 0.f;
    #pragma unroll 4
    for (int l = 0; l < 64; ++l) a = fmaf(Wo[j * 64 + l], Wv[l * 64 + k], a);
    Wvo[idx] = a;
  }
  if (idx < 64) {                  // bvo[j] = sum_l Wo[j][l] bv[l] + bo[j]
    float a = bo[idx];
    for (int l = 0; l < 64; ++l) a = fmaf(Wo[idx * 64 + l], bv[l], a);
    bvo[idx] = a;
  }
  if (idx < 8192) {                // Bp1: Wattn (K=128), even/odd pack
    int e8 = idx & 7, ln = (idx >> 3) & 63, t = (idx >> 9) & 1, s = idx >> 10;
    int n = 2 * (ln & 31) + t;
    int k = s * 16 + (ln >> 5) * 8 + e8;
    Bp1[idx] = f2bf(Wattn[n * 128 + k]);
  }
  if (idx < 4096) {                // Bp3: We2, Bp4: Wg1, Bp5: Wg2 (K=64), even/odd
    int e8 = idx & 7, ln = (idx >> 3) & 63, t = (idx >> 9) & 1, s = idx >> 10;
    int n = 2 * (ln & 31) + t;
    int k = s * 16 + (ln >> 5) * 8 + e8;
    Bp3[idx] = f2bf(We2[n * 64 + k]);
    Bp4[idx] = f2bf(Wg1[n * 64 + k]);
    Bp5[idx] = f2bf(Wg2[n * 64 + k]);
  }
  if (idx < 2048) {                // Bp6: Wnh zero-padded (single tile, natural cols)
    int e8 = idx & 7, ln = (idx >> 3) & 63, s = idx >> 9;
    int n = ln & 31;
    int k = s * 16 + (ln >> 5) * 8 + e8;
    Bp6[idx] = (n < 10) ? f2bf(Wnh[n * 64 + k]) : (unsigned short)0;
  }
}

// ---------- prep2: Bp2 from Wvo (after k_prep), even/odd pack ----------
__global__ __launch_bounds__(256) void k_prep2(
    const float* __restrict__ Wvo, unsigned short* __restrict__ Bp2)
{
  int idx = blockIdx.x * 256 + threadIdx.x;
  if (idx < 4096) {
    int e8 = idx & 7, ln = (idx >> 3) & 63, t = (idx >> 9) & 1, s = idx >> 10;
    int n = 2 * (ln & 31) + t;
    int k = s * 16 + (ln >> 5) * 8 + e8;
    Bp2[idx] = f2bf(Wvo[n * 64 + k]);
  }
}

// ---------- node init ----------
__global__ __launch_bounds__(256) void k_node_init(
    const float* __restrict__ nl, const float* __restrict__ Wproj,
    const float* __restrict__ bproj, unsigned short* __restrict__ nf16, int N)
{
  int i = blockIdx.x * 256 + threadIdx.x;
  if (i >= N) return;
  float x[10];
  #pragma unroll
  for (int k = 0; k < 10; ++k) x[k] = nl[(size_t)i * 10 + k];
  const size_t ib = (size_t)i * HH;
  #pragma unroll 1
  for (int j8 = 0; j8 < 8; ++j8) {
    bf16x8 v;
    #pragma unroll
    for (int u = 0; u < 8; ++u) {
      int j = j8 * 8 + u;
      float a = bproj[j];
      #pragma unroll
      for (int k = 0; k < 10; ++k) a = fmaf(x[k], Wproj[j * 10 + k], a);
      v[u] = (short)f2bf(a);
    }
    *(bf16x8*)(nf16 + ib + j8 * 8) = v;
  }
}

// ---------- CSR build ----------
__global__ __launch_bounds__(256) void k_zero(int* __restrict__ p, int n)
{
  int i = blockIdx.x * 256 + threadIdx.x;
  if (i < n) p[i] = 0;
}

__global__ __launch_bounds__(256) void k_deg(
    const int* __restrict__ ei, int* __restrict__ deg, int E)
{
  int e = blockIdx.x * 256 + threadIdx.x;
  if (e >= E) return;
  atomicAdd(&deg[ei[(size_t)E + e]], 1);
}

__global__ __launch_bounds__(256) void k_part(
    const int* __restrict__ deg, int* __restrict__ bpart, int N)
{
  __shared__ int s[256];
  int t = threadIdx.x;
  int i = blockIdx.x * 256 + t;
  s[t] = (i < N) ? deg[i] : 0;
  __syncthreads();
  #pragma unroll
  for (int o = 128; o > 0; o >>= 1) {
    if (t < o) s[t] += s[t + o];
    __syncthreads();
  }
  if (t == 0) bpart[blockIdx.x] = s[0];
}

__global__ __launch_bounds__(256) void k_scanpart(
    const int* __restrict__ bpart, int* __restrict__ bbase,
    int* __restrict__ rowptr_last, int PB)
{
  __shared__ int s[256];
  int t = threadIdx.x;
  int v = (t < PB) ? bpart[t] : 0;
  s[t] = v;
  __syncthreads();
  for (int o = 1; o < 256; o <<= 1) {
    int u = (t >= o) ? s[t - o] : 0;
    __syncthreads();
    s[t] += u;
    __syncthreads();
  }
  if (t < PB) bbase[t] = s[t] - v;
  if (t == 255) *rowptr_last = s[255];
}

__global__ __launch_bounds__(256) void k_rowptr(
    const int* __restrict__ deg, const int* __restrict__ bbase,
    int* __restrict__ rowptr, int* __restrict__ wofs, int N)
{
  __shared__ int s[256];
  int t = threadIdx.x;
  int i = blockIdx.x * 256 + t;
  int v = (i < N) ? deg[i] : 0;
  s[t] = v;
  __syncthreads();
  for (int o = 1; o < 256; o <<= 1) {
    int u = (t >= o) ? s[t - o] : 0;
    __syncthreads();
    s[t] += u;
    __syncthreads();
  }
  if (i < N) {
    int ex = bbase[blockIdx.x] + s[t] - v;
    rowptr[i] = ex;
    wofs[i]   = ex;
  }
}

__global__ __launch_bounds__(256) void k_scatter(
    const int* __restrict__ ei, int* __restrict__ wofs,
    int* __restrict__ eorig, int* __restrict__ srcp, int* __restrict__ dstp,
    int E)
{
  int e = blockIdx.x * 256 + threadIdx.x;
  if (e >= E) return;
  int src = ei[e];
  int dst = ei[(size_t)E + e];
  int pos = atomicAdd(&wofs[dst], 1);
  eorig[pos] = e;
  srcp[pos]  = src;
  dstp[pos]  = dst;
}

// ---------- edge init (CSR slot order, even/odd pack, u32 stores) ----------
__global__ __launch_bounds__(256) void k_edge_init_mfma(
    const float* __restrict__ el, const float* __restrict__ We1,
    const float* __restrict__ be1, const unsigned short* __restrict__ Bp3,
    const float* __restrict__ be2, const int* __restrict__ eorig,
    unsigned short* __restrict__ ef16, int E)
{
  const int tid   = threadIdx.x;
  const int wave  = tid >> 6;
  const int lane  = tid & 63;
  const int er    = lane & 31;
  const int kh    = lane >> 5;
  const int ebase = blockIdx.x * 128 + wave * 32;

  int p = ebase + er;
  if (p >= E) p = E - 1;
  const int eo = eorig[p];
  const float x0 = el[(size_t)eo * 5 + 0], x1 = el[(size_t)eo * 5 + 1],
              x2 = el[(size_t)eo * 5 + 2], x3 = el[(size_t)eo * 5 + 3],
              x4 = el[(size_t)eo * 5 + 4];

  bf16x8 afr[4];
  #pragma unroll
  for (int s = 0; s < 4; ++s) {
    #pragma unroll
    for (int u = 0; u < 8; ++u) {
      const int k = s * 16 + kh * 8 + u;
      float a = be1[k];
      a = fmaf(x0, We1[k * 5 + 0], a);
      a = fmaf(x1, We1[k * 5 + 1], a);
      a = fmaf(x2, We1[k * 5 + 2], a);
      a = fmaf(x3, We1[k * 5 + 3], a);
      a = fmaf(x4, We1[k * 5 + 4], a);
      afr[s][u] = (short)f2bf(fmaxf(a, 0.f));
    }
  }

  f32x16 d0 = {0,0,0,0,0,0,0,0,0,0,0,0,0,0,0,0};
  f32x16 d1 = {0,0,0,0,0,0,0,0,0,0,0,0,0,0,0,0};
  #pragma unroll
  for (int s = 0; s < 4; ++s) {
    bf16x8 b0 = *(const bf16x8*)(Bp3 + (size_t)((s * 2 + 0) * 64 + lane) * 8);
    bf16x8 b1 = *(const bf16x8*)(Bp3 + (size_t)((s * 2 + 1) * 64 + lane) * 8);
    d0 = __builtin_amdgcn_mfma_f32_32x32x16_bf16(afr[s], b0, d0, 0, 0, 0);
    d1 = __builtin_amdgcn_mfma_f32_32x32x16_bf16(afr[s], b1, d1, 0, 0, 0);
  }

  const float b20 = be2[2 * er], b21 = be2[2 * er + 1];
  #pragma unroll
  for (int r = 0; r < 16; ++r) {
    const int m  = (r & 3) + 8 * (r >> 2) + 4 * kh;
    const int pg = ebase + m;
    if (pg < E) {
      unsigned q = (unsigned)f2bf(d0[r] + b20) | ((unsigned)f2bf(d1[r] + b21) << 16);
      *((unsigned*)(ef16 + (size_t)pg * HH) + er) = q;
    }
  }
}

// ---------- per-iteration edge pipeline ----------
// GEMM1 (K=128) -> c u32-spill to LDS (row-major + 16B-chunk XOR swizzle)
// -> GEMM2 (K=64) -> streamed u32 RMW of ef16. LAST: fused edge head.
template <bool LAST>
__global__ __launch_bounds__(256) void k_edge_mfma(
    const unsigned short* __restrict__ nf16, unsigned short* __restrict__ ef16,
    const int* __restrict__ srcp, const int* __restrict__ dstp,
    const int* __restrict__ eorig,
    const unsigned short* __restrict__ Bp1, const float* __restrict__ battn,
    const unsigned short* __restrict__ Bp2, const float* __restrict__ bvo,
    const float* __restrict__ Weh, const float* __restrict__ beh,
    float* __restrict__ edge_out, int E)
{
  __shared__ __align__(16) unsigned short c_lds[4 * 32 * 64];
  const int tid   = threadIdx.x;
  const int wave  = tid >> 6;
  const int lane  = tid & 63;
  const int er    = lane & 31;   // A row (slot) / D col pair base
  const int kh    = lane >> 5;
  const int ebase = blockIdx.x * 128 + wave * 32;

  int p = ebase + er;
  if (p >= E) p = E - 1;
  const int src = srcp[p];
  const int dst = dstp[p];
  const unsigned short* ns = nf16 + (size_t)src * HH;
  const unsigned short* nd = nf16 + (size_t)dst * HH;

  f32x16 acc0 = {0,0,0,0,0,0,0,0,0,0,0,0,0,0,0,0};
  f32x16 acc1 = {0,0,0,0,0,0,0,0,0,0,0,0,0,0,0,0};

  #pragma unroll
  for (int s = 0; s < 8; ++s) {
    const unsigned short* ap = (s < 4) ? ns : nd;
    bf16x8 a = *(const bf16x8*)(ap + (s & 3) * 16 + kh * 8);
    bf16x8 b0 = *(const bf16x8*)(Bp1 + (size_t)((s * 2 + 0) * 64 + lane) * 8);
    bf16x8 b1 = *(const bf16x8*)(Bp1 + (size_t)((s * 2 + 1) * 64 + lane) * 8);
    acc0 = __builtin_amdgcn_mfma_f32_32x32x16_bf16(a, b0, acc0, 0, 0, 0);
    acc1 = __builtin_amdgcn_mfma_f32_32x32x16_bf16(a, b1, acc1, 0, 0, 0);
  }

  // c -> LDS: u32 packs features (2er, 2er+1); row-major [32][64]bf16,
  // 16B-chunk XOR swizzle (chunk ^= row&7) -> write side conflict-free.
  unsigned short* cw = c_lds + wave * 2048;
  unsigned* cw32 = (unsigned*)cw;
  const float bt0 = battn[2 * er], bt1 = battn[2 * er + 1];
  #pragma unroll
  for (int r = 0; r < 16; ++r) {
    const int m = (r & 3) + 8 * (r >> 2) + 4 * kh;
    unsigned q = (unsigned)f2bf(acc0[r] + bt0) | ((unsigned)f2bf(acc1[r] + bt1) << 16);
    cw32[m * 32 + (((er >> 2) ^ (m & 7)) << 2) + (er & 3)] = q;
  }
  asm volatile("s_waitcnt lgkmcnt(0)" ::: "memory");
  __builtin_amdgcn_sched_barrier(0);

  // GEMM2: A row er, 16B chunk g = s*2+kh, swizzled g^(er&7)
  f32x16 d0 = {0,0,0,0,0,0,0,0,0,0,0,0,0,0,0,0};
  f32x16 d1 = {0,0,0,0,0,0,0,0,0,0,0,0,0,0,0,0};
  #pragma unroll
  for (int s = 0; s < 4; ++s) {
    const int g = s * 2 + kh;
    bf16x8 a2 = *(const bf16x8*)(cw + er * 64 + ((g ^ (er & 7)) << 3));
    bf16x8 b0 = *(const bf16x8*)(Bp2 + (size_t)((s * 2 + 0) * 64 + lane) * 8);
    bf16x8 b1 = *(const bf16x8*)(Bp2 + (size_t)((s * 2 + 1) * 64 + lane) * 8);
    d0 = __builtin_amdgcn_mfma_f32_32x32x16_bf16(a2, b0, d0, 0, 0, 0);
    d1 = __builtin_amdgcn_mfma_f32_32x32x16_bf16(a2, b1, d1, 0, 0, 0);
  }

  // RMW: ef = relu(ef + msg), one u32 per lane per row (coalesced 128B/row)
  const float bv0 = bvo[2 * er], bv1 = bvo[2 * er + 1];
  #pragma unroll
  for (int r = 0; r < 16; ++r) {
    const int m  = (r & 3) + 8 * (r >> 2) + 4 * kh;
    const int eg = ebase + m;
    if (eg < E) {
      unsigned* prow = (unsigned*)(ef16 + (size_t)eg * HH) + er;
      unsigned old = *prow;
      float x0 = fmaxf(bf2f((unsigned short)(old & 0xffff)) + d0[r] + bv0, 0.f);
      float x1 = fmaxf(bf2f((unsigned short)(old >> 16))    + d1[r] + bv1, 0.f);
      unsigned q = (unsigned)f2bf(x0) | ((unsigned)f2bf(x1) << 16);
      *prow = q;
      if (LAST)
        cw32[m * 32 + (((er >> 2) ^ (m & 7)) << 2) + (er & 3)] = q;
    }
  }

  if (LAST) {
    asm volatile("s_waitcnt lgkmcnt(0)" ::: "memory");
    __builtin_amdgcn_sched_barrier(0);
    if (lane < 32) {
      const int eg = ebase + lane;
      if (eg < E) {
        float a0 = beh[0], a1 = beh[1], a2 = beh[2], a3 = beh[3], a4 = beh[4];
        const int l7 = lane & 7;
        #pragma unroll
        for (int f = 0; f < HH; ++f) {
          float x = bf2f(cw[lane * 64 + (((f >> 3) ^ l7) << 3) + (f & 7)]);
          a0 = fmaf(x, Weh[0 * HH + f], a0);
          a1 = fmaf(x, Weh[1 * HH + f], a1);
          a2 = fmaf(x, Weh[2 * HH + f], a2);
          a3 = fmaf(x, Weh[3 * HH + f], a3);
          a4 = fmaf(x, Weh[4 * HH + f], a4);
        }
        const int eo = eorig[eg];
        float* o = edge_out + (size_t)eo * 5;
        o[0] = a0; o[1] = a1; o[2] = a2; o[3] = a3; o[4] = a4;
      }
    }
  }
}

// ---------- node aggregation: sequential CSR rows, bf16 out ----------
__global__ __launch_bounds__(256) void k_node_agg(
    const unsigned short* __restrict__ nf16, const unsigned short* __restrict__ ef16,
    const int* __restrict__ srcp, const int* __restrict__ rowptr,
    unsigned short* __restrict__ agg16, int N)
{
  int gid = blockIdx.x * 256 + threadIdx.x;
  int i = gid >> 4;
  int l = gid & 15;
  if (i >= N) return;
  int b = rowptr[i];
  int t = rowptr[i + 1];
  const int fo = l * 4;
  ushx4 hv = *(const ushx4*)(nf16 + (size_t)i * HH + fo);
  float h0 = bf2f(hv[0]), h1 = bf2f(hv[1]), h2 = bf2f(hv[2]), h3 = bf2f(hv[3]);
  for (int p = b; p < t; ++p) {
    int src = srcp[p];
    ushx4 ev = *(const ushx4*)(ef16 + (size_t)p * HH + fo);
    ushx4 sv = *(const ushx4*)(nf16 + (size_t)src * HH + fo);
    h0 += fmaxf(bf2f(sv[0]) + bf2f(ev[0]), 0.f);
    h1 += fmaxf(bf2f(sv[1]) + bf2f(ev[1]), 0.f);
    h2 += fmaxf(bf2f(sv[2]) + bf2f(ev[2]), 0.f);
    h3 += fmaxf(bf2f(sv[3]) + bf2f(ev[3]), 0.f);
  }
  ushx4 out = { f2bf(h0), f2bf(h1), f2bf(h2), f2bf(h3) };
  *(ushx4*)(agg16 + (size_t)i * HH + fo) = out;
}

// ---------- node MLP via MFMA (even/odd pack) ----------
template <bool LAST>
__global__ __launch_bounds__(256) void k_node_mlp(
    const unsigned short* __restrict__ agg16,
    const unsigned short* __restrict__ Bp4, const float* __restrict__ bg1,
    const unsigned short* __restrict__ Bp5, const float* __restrict__ bg2,
    const unsigned short* __restrict__ Bp6, const float* __restrict__ bnh,
    unsigned short* __restrict__ nf16, float* __restrict__ node_out, int N)
{
  __shared__ __align__(16) unsigned short c_lds[4 * 32 * 64];
  const int tid   = threadIdx.x;
  const int wave  = tid >> 6;
  const int lane  = tid & 63;
  const int er    = lane & 31;
  const int kh    = lane >> 5;
  const int nbase = blockIdx.x * 128 + wave * 32;
  if (nbase >= N) return;

  int node = nbase + er;
  if (node >= N) node = N - 1;
  const unsigned short* ar = agg16 + (size_t)node * HH;

  // GEMM g1 (K=64)
  f32x16 acc0 = {0,0,0,0,0,0,0,0,0,0,0,0,0,0,0,0};
  f32x16 acc1 = {0,0,0,0,0,0,0,0,0,0,0,0,0,0,0,0};
  #pragma unroll
  for (int s = 0; s < 4; ++s) {
    bf16x8 a = *(const bf16x8*)(ar + s * 16 + kh * 8);
    bf16x8 b0 = *(const bf16x8*)(Bp4 + (size_t)((s * 2 + 0) * 64 + lane) * 8);
    bf16x8 b1 = *(const bf16x8*)(Bp4 + (size_t)((s * 2 + 1) * 64 + lane) * 8);
    acc0 = __builtin_amdgcn_mfma_f32_32x32x16_bf16(a, b0, acc0, 0, 0, 0);
    acc1 = __builtin_amdgcn_mfma_f32_32x32x16_bf16(a, b1, acc1, 0, 0, 0);
  }

  // t1 = relu(acc + bg1) -> LDS u32 spill
  unsigned short* cw = c_lds + wave * 2048;
  unsigned* cw32 = (unsigned*)cw;
  const float bg10 = bg1[2 * er], bg11 = bg1[2 * er + 1];
  #pragma unroll
  for (int r = 0; r < 16; ++r) {
    const int m = (r & 3) + 8 * (r >> 2) + 4 * kh;
    unsigned q = (unsigned)f2bf(fmaxf(acc0[r] + bg10, 0.f))
               | ((unsigned)f2bf(fmaxf(acc1[r] + bg11, 0.f)) << 16);
    cw32[m * 32 + (((er >> 2) ^ (m & 7)) << 2) + (er & 3)] = q;
  }
  asm volatile("s_waitcnt lgkmcnt(0)" ::: "memory");
  __builtin_amdgcn_sched_barrier(0);

  // GEMM g2
  f32x16 d0 = {0,0,0,0,0,0,0,0,0,0,0,0,0,0,0,0};
  f32x16 d1 = {0,0,0,0,0,0,0,0,0,0,0,0,0,0,0,0};
  #pragma unroll
  for (int s = 0; s < 4; ++s) {
    const int g = s * 2 + kh;
    bf16x8 a2 = *(const bf16x8*)(cw + er * 64 + ((g ^ (er & 7)) << 3));
    bf16x8 b0 = *(const bf16x8*)(Bp5 + (size_t)((s * 2 + 0) * 64 + lane) * 8);
    bf16x8 b1 = *(const bf16x8*)(Bp5 + (size_t)((s * 2 + 1) * 64 + lane) * 8);
    d0 = __builtin_amdgcn_mfma_f32_32x32x16_bf16(a2, b0, d0, 0, 0, 0);
    d1 = __builtin_amdgcn_mfma_f32_32x32x16_bf16(a2, b1, d1, 0, 0, 0);
  }

  const float bg20 = bg2[2 * er], bg21 = bg2[2 * er + 1];
  if (!LAST) {
    #pragma unroll
    for (int r = 0; r < 16; ++r) {
      const int m  = (r & 3) + 8 * (r >> 2) + 4 * kh;
      const int ng = nbase + m;
      if (ng < N) {
        unsigned q = (unsigned)f2bf(fmaxf(d0[r] + bg20, 0.f))
                   | ((unsigned)f2bf(fmaxf(d1[r] + bg21, 0.f)) << 16);
        *((unsigned*)(nf16 + (size_t)ng * HH) + er) = q;
      }
    }
  } else {
    // spill v -> LDS, head GEMM with zero-padded Wnh (natural col order)
    #pragma unroll
    for (int r = 0; r < 16; ++r) {
      const int m = (r & 3) + 8 * (r >> 2) + 4 * kh;
      unsigned q = (unsigned)f2bf(fmaxf(d0[r] + bg20, 0.f))
                 | ((unsigned)f2bf(fmaxf(d1[r] + bg21, 0.f)) << 16);
      cw32[m * 32 + (((er >> 2) ^ (m & 7)) << 2) + (er & 3)] = q;
    }
    asm volatile("s_waitcnt lgkmcnt(0)" ::: "memory");
    __builtin_amdgcn_sched_barrier(0);

    f32x16 hacc = {0,0,0,0,0,0,0,0,0,0,0,0,0,0,0,0};
    #pragma unroll
    for (int s = 0; s < 4; ++s) {
      const int g = s * 2 + kh;
      bf16x8 a2 = *(const bf16x8*)(cw + er * 64 + ((g ^ (er & 7)) << 3));
      bf16x8 b = *(const bf16x8*)(Bp6 + (size_t)(s * 64 + lane) * 8);
      hacc = __builtin_amdgcn_mfma_f32_32x32x16_bf16(a2, b, hacc, 0, 0, 0);
    }
    if (er < 10) {
      const float bn = bnh[er];
      #pragma unroll
      for (int r = 0; r < 16; ++r) {
        const int m  = (r & 3) + 8 * (r >> 2) + 4 * kh;
        const int ng = nbase + m;
        if (ng < N) node_out[(size_t)ng * 10 + er] = hacc[r] + bn;
      }
    }
  }
}

extern "C" void kernel_launch(void* const* d_in, const int* in_sizes, int n_in,
                              void* d_out, int out_size, void* d_ws, size_t ws_size,
                              hipStream_t stream)
{
  const float* node_logits = (const float*)d_in[0];
  const float* edge_logits = (const float*)d_in[1];
  const int*   ei          = (const int*)d_in[2];
  const float* Wproj = (const float*)d_in[3];
  const float* bproj = (const float*)d_in[4];
  const float* We1   = (const float*)d_in[5];
  const float* be1   = (const float*)d_in[6];
  const float* We2   = (const float*)d_in[7];
  const float* be2   = (const float*)d_in[8];
  const float* Wg1   = (const float*)d_in[9];
  const float* bg1   = (const float*)d_in[10];
  const float* Wg2   = (const float*)d_in[11];
  const float* bg2   = (const float*)d_in[12];
  const float* Wv    = (const float*)d_in[13];
  const float* bv    = (const float*)d_in[14];
  const float* Wo    = (const float*)d_in[15];
  const float* bo    = (const float*)d_in[16];
  const float* Wattn = (const float*)d_in[17];
  const float* battn = (const float*)d_in[18];
  const float* Wnh   = (const float*)d_in[19];
  const float* bnh   = (const float*)d_in[20];
  const float* Weh   = (const float*)d_in[21];
  const float* beh   = (const float*)d_in[22];

  const int N = in_sizes[0] / 10;
  const int E = in_sizes[1] / 5;

  float* ws = (float*)d_ws;
  size_t off = 0;
  unsigned short* nf16  = (unsigned short*)(ws + off); off += (size_t)N * (HH / 2);
  unsigned short* ef16  = (unsigned short*)(ws + off); off += (size_t)E * (HH / 2);
  unsigned short* agg16 = (unsigned short*)(ws + off); off += (size_t)N * (HH / 2);
  float* Wvo = ws + off; off += 64 * 64;
  float* bvo = ws + off; off += 64;
  unsigned short* Bp1 = (unsigned short*)(ws + off); off += 4096;  // 8192 bf16
  unsigned short* Bp2 = (unsigned short*)(ws + off); off += 2048;
  unsigned short* Bp3 = (unsigned short*)(ws + off); off += 2048;
  unsigned short* Bp4 = (unsigned short*)(ws + off); off += 2048;
  unsigned short* Bp5 = (unsigned short*)(ws + off); off += 2048;
  unsigned short* Bp6 = (unsigned short*)(ws + off); off += 1024;  // 2048 bf16
  int* deg    = (int*)(ws + off); off += N;
  int* rowptr = (int*)(ws + off); off += N + 1;
  int* wofs   = (int*)(ws + off); off += N;
  int* eorig  = (int*)(ws + off); off += E;
  int* srcp   = (int*)(ws + off); off += E;
  int* dstp   = (int*)(ws + off); off += E;
  int* bpart  = (int*)(ws + off); off += 256;
  int* bbase  = (int*)(ws + off); off += 256;

  float* node_out = (float*)d_out;
  float* edge_out = node_out + (size_t)N * 10;

  const int nb_n    = (N + 255) / 256;
  const int nb_e    = (E + 255) / 256;
  const int nb_a    = ((N * 16) + 255) / 256;
  const int nb_e128 = (E + 127) / 128;
  const int nb_n128 = (N + 127) / 128;
  const int PB      = (N + 255) / 256;

  k_prep<<<32, 256, 0, stream>>>(Wattn, Wg1, Wg2, Wnh, Wo, Wv, bv, bo, We2,
                                 Wvo, bvo, Bp1, Bp3, Bp4, Bp5, Bp6);
  k_prep2<<<16, 256, 0, stream>>>(Wvo, Bp2);
  k_zero<<<nb_n, 256, 0, stream>>>(deg, N);
  k_node_init<<<nb_n, 256, 0, stream>>>(node_logits, Wproj, bproj, nf16, N);
  k_deg<<<nb_e, 256, 0, stream>>>(ei, deg, E);
  k_part<<<PB, 256, 0, stream>>>(deg, bpart, N);
  k_scanpart<<<1, 256, 0, stream>>>(bpart, bbase, rowptr + N, PB);
  k_rowptr<<<PB, 256, 0, stream>>>(deg, bbase, rowptr, wofs, N);
  k_scatter<<<nb_e, 256, 0, stream>>>(ei, wofs, eorig, srcp, dstp, E);
  k_edge_init_mfma<<<nb_e128, 256, 0, stream>>>(edge_logits, We1, be1, Bp3, be2,
                                                eorig, ef16, E);

  // iteration 1
  k_edge_mfma<false><<<nb_e128, 256, 0, stream>>>(nf16, ef16, srcp, dstp, eorig,
                                                  Bp1, battn, Bp2, bvo,
                                                  Weh, beh, edge_out, E);
  k_node_agg<<<nb_a, 256, 0, stream>>>(nf16, ef16, srcp, rowptr, agg16, N);
  k_node_mlp<false><<<nb_n128, 256, 0, stream>>>(agg16, Bp4, bg1, Bp5, bg2,
                                                 Bp6, bnh, nf16, node_out, N);
  // iteration 2
  k_edge_mfma<true><<<nb_e128, 256, 0, stream>>>(nf16, ef16, srcp, dstp, eorig,
                                                 Bp1, battn, Bp2, bvo,
                                                 Weh, beh, edge_out, E);
  k_node_agg<<<nb_a, 256, 0, stream>>>(nf16, ef16, srcp, rowptr, agg16, N);
  k_node_mlp<true><<<nb_n128, 256, 0, stream>>>(agg16, Bp4, bg1, Bp5, bg2,
                                                Bp6, bnh, nf16, node_out, N);
}

// Round 9
// 444.295 us; speedup vs baseline: 13.6116x; 1.0264x over previous
//
#include <hip/hip_runtime.h>

#define HH 64

typedef __attribute__((ext_vector_type(8))) short bf16x8;
typedef __attribute__((ext_vector_type(16))) float f32x16;
typedef __attribute__((ext_vector_type(4))) unsigned short ushx4;

__device__ __forceinline__ unsigned short f2bf(float f) {
  unsigned u = __builtin_bit_cast(unsigned, f);
  return (unsigned short)((u + 0x7FFFu + ((u >> 16) & 1u)) >> 16);
}
__device__ __forceinline__ float bf2f(unsigned short h) {
  unsigned u = ((unsigned)h) << 16;
  return __builtin_bit_cast(float, u);
}

// ---------- prep ----------
// EVEN/ODD B-fragment pack: tile t=0 -> even output features, t=1 -> odd.
//   n = 2*(ln&31) + t ; k = s*16 + (ln>>5)*8 + e8
// => acc0 col er = feature 2er, acc1 col er = feature 2er+1 (adjacent, one u32).
__global__ __launch_bounds__(256) void k_prep(
    const float* __restrict__ Wattn, const float* __restrict__ Wg1,
    const float* __restrict__ Wg2,   const float* __restrict__ Wnh,
    const float* __restrict__ Wo,    const float* __restrict__ Wv,
    const float* __restrict__ bv,    const float* __restrict__ bo,
    const float* __restrict__ We2,
    float* __restrict__ Wvo, float* __restrict__ bvo,
    unsigned short* __restrict__ Bp1, unsigned short* __restrict__ Bp3,
    unsigned short* __restrict__ Bp4, unsigned short* __restrict__ Bp5,
    unsigned short* __restrict__ Bp6)
{
  int idx = blockIdx.x * 256 + threadIdx.x;
  if (idx < 4096) {                // Wvo[j][k] = sum_l Wo[j][l] Wv[l][k]
    int j = idx >> 6, k = idx & 63;
    float a = 0.f;
    #pragma unroll 4
    for (int l = 0; l < 64; ++l) a = fmaf(Wo[j * 64 + l], Wv[l * 64 + k], a);
    Wvo[idx] = a;
  }
  if (idx < 64) {                  // bvo[j] = sum_l Wo[j][l] bv[l] + bo[j]
    float a = bo[idx];
    for (int l = 0; l < 64; ++l) a = fmaf(Wo[idx * 64 + l], bv[l], a);
    bvo[idx] = a;
  }
  if (idx < 8192) {                // Bp1: Wattn (K=128), even/odd pack
    int e8 = idx & 7, ln = (idx >> 3) & 63, t = (idx >> 9) & 1, s = idx >> 10;
    int n = 2 * (ln & 31) + t;
    int k = s * 16 + (ln >> 5) * 8 + e8;
    Bp1[idx] = f2bf(Wattn[n * 128 + k]);
  }
  if (idx < 4096) {                // Bp3: We2, Bp4: Wg1, Bp5: Wg2 (K=64), even/odd
    int e8 = idx & 7, ln = (idx >> 3) & 63, t = (idx >> 9) & 1, s = idx >> 10;
    int n = 2 * (ln & 31) + t;
    int k = s * 16 + (ln >> 5) * 8 + e8;
    Bp3[idx] = f2bf(We2[n * 64 + k]);
    Bp4[idx] = f2bf(Wg1[n * 64 + k]);
    Bp5[idx] = f2bf(Wg2[n * 64 + k]);
  }
  if (idx < 2048) {                // Bp6: Wnh zero-padded (single tile, natural cols)
    int e8 = idx & 7, ln = (idx >> 3) & 63, s = idx >> 9;
    int n = ln & 31;
    int k = s * 16 + (ln >> 5) * 8 + e8;
    Bp6[idx] = (n < 10) ? f2bf(Wnh[n * 64 + k]) : (unsigned short)0;
  }
}

// ---------- prep2: Bp2 from Wvo (after k_prep), even/odd pack ----------
__global__ __launch_bounds__(256) void k_prep2(
    const float* __restrict__ Wvo, unsigned short* __restrict__ Bp2)
{
  int idx = blockIdx.x * 256 + threadIdx.x;
  if (idx < 4096) {
    int e8 = idx & 7, ln = (idx >> 3) & 63, t = (idx >> 9) & 1, s = idx >> 10;
    int n = 2 * (ln & 31) + t;
    int k = s * 16 + (ln >> 5) * 8 + e8;
    Bp2[idx] = f2bf(Wvo[n * 64 + k]);
  }
}

// ---------- node init ----------
__global__ __launch_bounds__(256) void k_node_init(
    const float* __restrict__ nl, const float* __restrict__ Wproj,
    const float* __restrict__ bproj, unsigned short* __restrict__ nf16, int N)
{
  int i = blockIdx.x * 256 + threadIdx.x;
  if (i >= N) return;
  float x[10];
  #pragma unroll
  for (int k = 0; k < 10; ++k) x[k] = nl[(size_t)i * 10 + k];
  const size_t ib = (size_t)i * HH;
  #pragma unroll 1
  for (int j8 = 0; j8 < 8; ++j8) {
    bf16x8 v;
    #pragma unroll
    for (int u = 0; u < 8; ++u) {
      int j = j8 * 8 + u;
      float a = bproj[j];
      #pragma unroll
      for (int k = 0; k < 10; ++k) a = fmaf(x[k], Wproj[j * 10 + k], a);
      v[u] = (short)f2bf(a);
    }
    *(bf16x8*)(nf16 + ib + j8 * 8) = v;
  }
}

// ---------- CSR build ----------
__global__ __launch_bounds__(256) void k_zero(int* __restrict__ p, int n)
{
  int i = blockIdx.x * 256 + threadIdx.x;
  if (i < n) p[i] = 0;
}

__global__ __launch_bounds__(256) void k_deg(
    const int* __restrict__ ei, int* __restrict__ deg, int E)
{
  int e = blockIdx.x * 256 + threadIdx.x;
  if (e >= E) return;
  atomicAdd(&deg[ei[(size_t)E + e]], 1);
}

__global__ __launch_bounds__(256) void k_part(
    const int* __restrict__ deg, int* __restrict__ bpart, int N)
{
  __shared__ int s[256];
  int t = threadIdx.x;
  int i = blockIdx.x * 256 + t;
  s[t] = (i < N) ? deg[i] : 0;
  __syncthreads();
  #pragma unroll
  for (int o = 128; o > 0; o >>= 1) {
    if (t < o) s[t] += s[t + o];
    __syncthreads();
  }
  if (t == 0) bpart[blockIdx.x] = s[0];
}

__global__ __launch_bounds__(256) void k_scanpart(
    const int* __restrict__ bpart, int* __restrict__ bbase,
    int* __restrict__ rowptr_last, int PB)
{
  __shared__ int s[256];
  int t = threadIdx.x;
  int v = (t < PB) ? bpart[t] : 0;
  s[t] = v;
  __syncthreads();
  for (int o = 1; o < 256; o <<= 1) {
    int u = (t >= o) ? s[t - o] : 0;
    __syncthreads();
    s[t] += u;
    __syncthreads();
  }
  if (t < PB) bbase[t] = s[t] - v;
  if (t == 255) *rowptr_last = s[255];
}

__global__ __launch_bounds__(256) void k_rowptr(
    const int* __restrict__ deg, const int* __restrict__ bbase,
    int* __restrict__ rowptr, int* __restrict__ wofs, int N)
{
  __shared__ int s[256];
  int t = threadIdx.x;
  int i = blockIdx.x * 256 + t;
  int v = (i < N) ? deg[i] : 0;
  s[t] = v;
  __syncthreads();
  for (int o = 1; o < 256; o <<= 1) {
    int u = (t >= o) ? s[t - o] : 0;
    __syncthreads();
    s[t] += u;
    __syncthreads();
  }
  if (i < N) {
    int ex = bbase[blockIdx.x] + s[t] - v;
    rowptr[i] = ex;
    wofs[i]   = ex;
  }
}

__global__ __launch_bounds__(256) void k_scatter(
    const int* __restrict__ ei, int* __restrict__ wofs,
    int* __restrict__ eorig, int* __restrict__ srcp, int* __restrict__ dstp,
    int E)
{
  int e = blockIdx.x * 256 + threadIdx.x;
  if (e >= E) return;
  int src = ei[e];
  int dst = ei[(size_t)E + e];
  int pos = atomicAdd(&wofs[dst], 1);
  eorig[pos] = e;
  srcp[pos]  = src;
  dstp[pos]  = dst;
}

// ---------- edge init (CSR slot order, even/odd pack, u32 stores) ----------
__global__ __launch_bounds__(256) void k_edge_init_mfma(
    const float* __restrict__ el, const float* __restrict__ We1,
    const float* __restrict__ be1, const unsigned short* __restrict__ Bp3,
    const float* __restrict__ be2, const int* __restrict__ eorig,
    unsigned short* __restrict__ ef16, int E)
{
  const int tid   = threadIdx.x;
  const int wave  = tid >> 6;
  const int lane  = tid & 63;
  const int er    = lane & 31;
  const int kh    = lane >> 5;
  const int ebase = blockIdx.x * 128 + wave * 32;

  int p = ebase + er;
  if (p >= E) p = E - 1;
  const int eo = eorig[p];
  const float x0 = el[(size_t)eo * 5 + 0], x1 = el[(size_t)eo * 5 + 1],
              x2 = el[(size_t)eo * 5 + 2], x3 = el[(size_t)eo * 5 + 3],
              x4 = el[(size_t)eo * 5 + 4];

  bf16x8 afr[4];
  #pragma unroll
  for (int s = 0; s < 4; ++s) {
    #pragma unroll
    for (int u = 0; u < 8; ++u) {
      const int k = s * 16 + kh * 8 + u;
      float a = be1[k];
      a = fmaf(x0, We1[k * 5 + 0], a);
      a = fmaf(x1, We1[k * 5 + 1], a);
      a = fmaf(x2, We1[k * 5 + 2], a);
      a = fmaf(x3, We1[k * 5 + 3], a);
      a = fmaf(x4, We1[k * 5 + 4], a);
      afr[s][u] = (short)f2bf(fmaxf(a, 0.f));
    }
  }

  f32x16 d0 = {0,0,0,0,0,0,0,0,0,0,0,0,0,0,0,0};
  f32x16 d1 = {0,0,0,0,0,0,0,0,0,0,0,0,0,0,0,0};
  #pragma unroll
  for (int s = 0; s < 4; ++s) {
    bf16x8 b0 = *(const bf16x8*)(Bp3 + (size_t)((s * 2 + 0) * 64 + lane) * 8);
    bf16x8 b1 = *(const bf16x8*)(Bp3 + (size_t)((s * 2 + 1) * 64 + lane) * 8);
    d0 = __builtin_amdgcn_mfma_f32_32x32x16_bf16(afr[s], b0, d0, 0, 0, 0);
    d1 = __builtin_amdgcn_mfma_f32_32x32x16_bf16(afr[s], b1, d1, 0, 0, 0);
  }

  const float b20 = be2[2 * er], b21 = be2[2 * er + 1];
  #pragma unroll
  for (int r = 0; r < 16; ++r) {
    const int m  = (r & 3) + 8 * (r >> 2) + 4 * kh;
    const int pg = ebase + m;
    if (pg < E) {
      unsigned q = (unsigned)f2bf(d0[r] + b20) | ((unsigned)f2bf(d1[r] + b21) << 16);
      *((unsigned*)(ef16 + (size_t)pg * HH) + er) = q;
    }
  }
}

// ---------- per-iteration edge pipeline ----------
// T14: prefetch ef rows at entry (issue-early) -> GEMM1 (K=128) -> c u32-spill
// to LDS -> GEMM2 (K=64) -> register-direct u32 RMW (consume-late).
template <bool LAST>
__global__ __launch_bounds__(256) void k_edge_mfma(
    const unsigned short* __restrict__ nf16, unsigned short* __restrict__ ef16,
    const int* __restrict__ srcp, const int* __restrict__ dstp,
    const int* __restrict__ eorig,
    const unsigned short* __restrict__ Bp1, const float* __restrict__ battn,
    const unsigned short* __restrict__ Bp2, const float* __restrict__ bvo,
    const float* __restrict__ Weh, const float* __restrict__ beh,
    float* __restrict__ edge_out, int E)
{
  __shared__ __align__(16) unsigned short c_lds[4 * 32 * 64];
  const int tid   = threadIdx.x;
  const int wave  = tid >> 6;
  const int lane  = tid & 63;
  const int er    = lane & 31;   // A row (slot) / D col pair base
  const int kh    = lane >> 5;
  const int ebase = blockIdx.x * 128 + wave * 32;

  // T14 prefetch: the 16 ef u32s this lane will RMW; independent of all else,
  // issued before the GEMM pipeline so HBM latency hides under it.
  unsigned efold[16];
  #pragma unroll
  for (int r = 0; r < 16; ++r) {
    const int m = (r & 3) + 8 * (r >> 2) + 4 * kh;
    int eg = ebase + m;
    if (eg >= E) eg = E - 1;
    efold[r] = *((const unsigned*)(ef16 + (size_t)eg * HH) + er);
  }

  int p = ebase + er;
  if (p >= E) p = E - 1;
  const int src = srcp[p];
  const int dst = dstp[p];
  const unsigned short* ns = nf16 + (size_t)src * HH;
  const unsigned short* nd = nf16 + (size_t)dst * HH;

  f32x16 acc0 = {0,0,0,0,0,0,0,0,0,0,0,0,0,0,0,0};
  f32x16 acc1 = {0,0,0,0,0,0,0,0,0,0,0,0,0,0,0,0};

  #pragma unroll
  for (int s = 0; s < 8; ++s) {
    const unsigned short* ap = (s < 4) ? ns : nd;
    bf16x8 a = *(const bf16x8*)(ap + (s & 3) * 16 + kh * 8);
    bf16x8 b0 = *(const bf16x8*)(Bp1 + (size_t)((s * 2 + 0) * 64 + lane) * 8);
    bf16x8 b1 = *(const bf16x8*)(Bp1 + (size_t)((s * 2 + 1) * 64 + lane) * 8);
    acc0 = __builtin_amdgcn_mfma_f32_32x32x16_bf16(a, b0, acc0, 0, 0, 0);
    acc1 = __builtin_amdgcn_mfma_f32_32x32x16_bf16(a, b1, acc1, 0, 0, 0);
  }

  // c -> LDS: u32 packs features (2er, 2er+1); row-major [32][64]bf16,
  // 16B-chunk XOR swizzle (chunk ^= row&7) -> write side conflict-free.
  unsigned short* cw = c_lds + wave * 2048;
  unsigned* cw32 = (unsigned*)cw;
  const float bt0 = battn[2 * er], bt1 = battn[2 * er + 1];
  #pragma unroll
  for (int r = 0; r < 16; ++r) {
    const int m = (r & 3) + 8 * (r >> 2) + 4 * kh;
    unsigned q = (unsigned)f2bf(acc0[r] + bt0) | ((unsigned)f2bf(acc1[r] + bt1) << 16);
    cw32[m * 32 + (((er >> 2) ^ (m & 7)) << 2) + (er & 3)] = q;
  }
  asm volatile("s_waitcnt lgkmcnt(0)" ::: "memory");
  __builtin_amdgcn_sched_barrier(0);

  // GEMM2: A row er, 16B chunk g = s*2+kh, swizzled g^(er&7)
  f32x16 d0 = {0,0,0,0,0,0,0,0,0,0,0,0,0,0,0,0};
  f32x16 d1 = {0,0,0,0,0,0,0,0,0,0,0,0,0,0,0,0};
  #pragma unroll
  for (int s = 0; s < 4; ++s) {
    const int g = s * 2 + kh;
    bf16x8 a2 = *(const bf16x8*)(cw + er * 64 + ((g ^ (er & 7)) << 3));
    bf16x8 b0 = *(const bf16x8*)(Bp2 + (size_t)((s * 2 + 0) * 64 + lane) * 8);
    bf16x8 b1 = *(const bf16x8*)(Bp2 + (size_t)((s * 2 + 1) * 64 + lane) * 8);
    d0 = __builtin_amdgcn_mfma_f32_32x32x16_bf16(a2, b0, d0, 0, 0, 0);
    d1 = __builtin_amdgcn_mfma_f32_32x32x16_bf16(a2, b1, d1, 0, 0, 0);
  }

  // RMW: ef = relu(ef + msg), register-direct (prefetched), one u32 per lane
  const float bv0 = bvo[2 * er], bv1 = bvo[2 * er + 1];
  #pragma unroll
  for (int r = 0; r < 16; ++r) {
    const int m  = (r & 3) + 8 * (r >> 2) + 4 * kh;
    const int eg = ebase + m;
    if (eg < E) {
      unsigned old = efold[r];
      float x0 = fmaxf(bf2f((unsigned short)(old & 0xffff)) + d0[r] + bv0, 0.f);
      float x1 = fmaxf(bf2f((unsigned short)(old >> 16))    + d1[r] + bv1, 0.f);
      unsigned q = (unsigned)f2bf(x0) | ((unsigned)f2bf(x1) << 16);
      *((unsigned*)(ef16 + (size_t)eg * HH) + er) = q;
      if (LAST)
        cw32[m * 32 + (((er >> 2) ^ (m & 7)) << 2) + (er & 3)] = q;
    }
  }

  if (LAST) {
    asm volatile("s_waitcnt lgkmcnt(0)" ::: "memory");
    __builtin_amdgcn_sched_barrier(0);
    if (lane < 32) {
      const int eg = ebase + lane;
      if (eg < E) {
        float a0 = beh[0], a1 = beh[1], a2 = beh[2], a3 = beh[3], a4 = beh[4];
        const int l7 = lane & 7;
        #pragma unroll
        for (int f = 0; f < HH; ++f) {
          float x = bf2f(cw[lane * 64 + (((f >> 3) ^ l7) << 3) + (f & 7)]);
          a0 = fmaf(x, Weh[0 * HH + f], a0);
          a1 = fmaf(x, Weh[1 * HH + f], a1);
          a2 = fmaf(x, Weh[2 * HH + f], a2);
          a3 = fmaf(x, Weh[3 * HH + f], a3);
          a4 = fmaf(x, Weh[4 * HH + f], a4);
        }
        const int eo = eorig[eg];
        float* o = edge_out + (size_t)eo * 5;
        o[0] = a0; o[1] = a1; o[2] = a2; o[3] = a3; o[4] = a4;
      }
    }
  }
}

// ---------- node aggregation: sequential CSR rows, bf16 out ----------
__global__ __launch_bounds__(256) void k_node_agg(
    const unsigned short* __restrict__ nf16, const unsigned short* __restrict__ ef16,
    const int* __restrict__ srcp, const int* __restrict__ rowptr,
    unsigned short* __restrict__ agg16, int N)
{
  int gid = blockIdx.x * 256 + threadIdx.x;
  int i = gid >> 4;
  int l = gid & 15;
  if (i >= N) return;
  int b = rowptr[i];
  int t = rowptr[i + 1];
  const int fo = l * 4;
  ushx4 hv = *(const ushx4*)(nf16 + (size_t)i * HH + fo);
  float h0 = bf2f(hv[0]), h1 = bf2f(hv[1]), h2 = bf2f(hv[2]), h3 = bf2f(hv[3]);
  #pragma unroll 2
  for (int p = b; p < t; ++p) {
    int src = srcp[p];
    ushx4 ev = *(const ushx4*)(ef16 + (size_t)p * HH + fo);
    ushx4 sv = *(const ushx4*)(nf16 + (size_t)src * HH + fo);
    h0 += fmaxf(bf2f(sv[0]) + bf2f(ev[0]), 0.f);
    h1 += fmaxf(bf2f(sv[1]) + bf2f(ev[1]), 0.f);
    h2 += fmaxf(bf2f(sv[2]) + bf2f(ev[2]), 0.f);
    h3 += fmaxf(bf2f(sv[3]) + bf2f(ev[3]), 0.f);
  }
  ushx4 out = { f2bf(h0), f2bf(h1), f2bf(h2), f2bf(h3) };
  *(ushx4*)(agg16 + (size_t)i * HH + fo) = out;
}

// ---------- node MLP via MFMA (even/odd pack) ----------
template <bool LAST>
__global__ __launch_bounds__(256) void k_node_mlp(
    const unsigned short* __restrict__ agg16,
    const unsigned short* __restrict__ Bp4, const float* __restrict__ bg1,
    const unsigned short* __restrict__ Bp5, const float* __restrict__ bg2,
    const unsigned short* __restrict__ Bp6, const float* __restrict__ bnh,
    unsigned short* __restrict__ nf16, float* __restrict__ node_out, int N)
{
  __shared__ __align__(16) unsigned short c_lds[4 * 32 * 64];
  const int tid   = threadIdx.x;
  const int wave  = tid >> 6;
  const int lane  = tid & 63;
  const int er    = lane & 31;
  const int kh    = lane >> 5;
  const int nbase = blockIdx.x * 128 + wave * 32;
  if (nbase >= N) return;

  int node = nbase + er;
  if (node >= N) node = N - 1;
  const unsigned short* ar = agg16 + (size_t)node * HH;

  // GEMM g1 (K=64)
  f32x16 acc0 = {0,0,0,0,0,0,0,0,0,0,0,0,0,0,0,0};
  f32x16 acc1 = {0,0,0,0,0,0,0,0,0,0,0,0,0,0,0,0};
  #pragma unroll
  for (int s = 0; s < 4; ++s) {
    bf16x8 a = *(const bf16x8*)(ar + s * 16 + kh * 8);
    bf16x8 b0 = *(const bf16x8*)(Bp4 + (size_t)((s * 2 + 0) * 64 + lane) * 8);
    bf16x8 b1 = *(const bf16x8*)(Bp4 + (size_t)((s * 2 + 1) * 64 + lane) * 8);
    acc0 = __builtin_amdgcn_mfma_f32_32x32x16_bf16(a, b0, acc0, 0, 0, 0);
    acc1 = __builtin_amdgcn_mfma_f32_32x32x16_bf16(a, b1, acc1, 0, 0, 0);
  }

  // t1 = relu(acc + bg1) -> LDS u32 spill
  unsigned short* cw = c_lds + wave * 2048;
  unsigned* cw32 = (unsigned*)cw;
  const float bg10 = bg1[2 * er], bg11 = bg1[2 * er + 1];
  #pragma unroll
  for (int r = 0; r < 16; ++r) {
    const int m = (r & 3) + 8 * (r >> 2) + 4 * kh;
    unsigned q = (unsigned)f2bf(fmaxf(acc0[r] + bg10, 0.f))
               | ((unsigned)f2bf(fmaxf(acc1[r] + bg11, 0.f)) << 16);
    cw32[m * 32 + (((er >> 2) ^ (m & 7)) << 2) + (er & 3)] = q;
  }
  asm volatile("s_waitcnt lgkmcnt(0)" ::: "memory");
  __builtin_amdgcn_sched_barrier(0);

  // GEMM g2
  f32x16 d0 = {0,0,0,0,0,0,0,0,0,0,0,0,0,0,0,0};
  f32x16 d1 = {0,0,0,0,0,0,0,0,0,0,0,0,0,0,0,0};
  #pragma unroll
  for (int s = 0; s < 4; ++s) {
    const int g = s * 2 + kh;
    bf16x8 a2 = *(const bf16x8*)(cw + er * 64 + ((g ^ (er & 7)) << 3));
    bf16x8 b0 = *(const bf16x8*)(Bp5 + (size_t)((s * 2 + 0) * 64 + lane) * 8);
    bf16x8 b1 = *(const bf16x8*)(Bp5 + (size_t)((s * 2 + 1) * 64 + lane) * 8);
    d0 = __builtin_amdgcn_mfma_f32_32x32x16_bf16(a2, b0, d0, 0, 0, 0);
    d1 = __builtin_amdgcn_mfma_f32_32x32x16_bf16(a2, b1, d1, 0, 0, 0);
  }

  const float bg20 = bg2[2 * er], bg21 = bg2[2 * er + 1];
  if (!LAST) {
    #pragma unroll
    for (int r = 0; r < 16; ++r) {
      const int m  = (r & 3) + 8 * (r >> 2) + 4 * kh;
      const int ng = nbase + m;
      if (ng < N) {
        unsigned q = (unsigned)f2bf(fmaxf(d0[r] + bg20, 0.f))
                   | ((unsigned)f2bf(fmaxf(d1[r] + bg21, 0.f)) << 16);
        *((unsigned*)(nf16 + (size_t)ng * HH) + er) = q;
      }
    }
  } else {
    // spill v -> LDS, head GEMM with zero-padded Wnh (natural col order)
    #pragma unroll
    for (int r = 0; r < 16; ++r) {
      const int m = (r & 3) + 8 * (r >> 2) + 4 * kh;
      unsigned q = (unsigned)f2bf(fmaxf(d0[r] + bg20, 0.f))
                 | ((unsigned)f2bf(fmaxf(d1[r] + bg21, 0.f)) << 16);
      cw32[m * 32 + (((er >> 2) ^ (m & 7)) << 2) + (er & 3)] = q;
    }
    asm volatile("s_waitcnt lgkmcnt(0)" ::: "memory");
    __builtin_amdgcn_sched_barrier(0);

    f32x16 hacc = {0,0,0,0,0,0,0,0,0,0,0,0,0,0,0,0};
    #pragma unroll
    for (int s = 0; s < 4; ++s) {
      const int g = s * 2 + kh;
      bf16x8 a2 = *(const bf16x8*)(cw + er * 64 + ((g ^ (er & 7)) << 3));
      bf16x8 b = *(const bf16x8*)(Bp6 + (size_t)(s * 64 + lane) * 8);
      hacc = __builtin_amdgcn_mfma_f32_32x32x16_bf16(a2, b, hacc, 0, 0, 0);
    }
    if (er < 10) {
      const float bn = bnh[er];
      #pragma unroll
      for (int r = 0; r < 16; ++r) {
        const int m  = (r & 3) + 8 * (r >> 2) + 4 * kh;
        const int ng = nbase + m;
        if (ng < N) node_out[(size_t)ng * 10 + er] = hacc[r] + bn;
      }
    }
  }
}

extern "C" void kernel_launch(void* const* d_in, const int* in_sizes, int n_in,
                              void* d_out, int out_size, void* d_ws, size_t ws_size,
                              hipStream_t stream)
{
  const float* node_logits = (const float*)d_in[0];
  const float* edge_logits = (const float*)d_in[1];
  const int*   ei          = (const int*)d_in[2];
  const float* Wproj = (const float*)d_in[3];
  const float* bproj = (const float*)d_in[4];
  const float* We1   = (const float*)d_in[5];
  const float* be1   = (const float*)d_in[6];
  const float* We2   = (const float*)d_in[7];
  const float* be2   = (const float*)d_in[8];
  const float* Wg1   = (const float*)d_in[9];
  const float* bg1   = (const float*)d_in[10];
  const float* Wg2   = (const float*)d_in[11];
  const float* bg2   = (const float*)d_in[12];
  const float* Wv    = (const float*)d_in[13];
  const float* bv    = (const float*)d_in[14];
  const float* Wo    = (const float*)d_in[15];
  const float* bo    = (const float*)d_in[16];
  const float* Wattn = (const float*)d_in[17];
  const float* battn = (const float*)d_in[18];
  const float* Wnh   = (const float*)d_in[19];
  const float* bnh   = (const float*)d_in[20];
  const float* Weh   = (const float*)d_in[21];
  const float* beh   = (const float*)d_in[22];

  const int N = in_sizes[0] / 10;
  const int E = in_sizes[1] / 5;

  float* ws = (float*)d_ws;
  size_t off = 0;
  unsigned short* nf16  = (unsigned short*)(ws + off); off += (size_t)N * (HH / 2);
  unsigned short* ef16  = (unsigned short*)(ws + off); off += (size_t)E * (HH / 2);
  unsigned short* agg16 = (unsigned short*)(ws + off); off += (size_t)N * (HH / 2);
  float* Wvo = ws + off; off += 64 * 64;
  float* bvo = ws + off; off += 64;
  unsigned short* Bp1 = (unsigned short*)(ws + off); off += 4096;  // 8192 bf16
  unsigned short* Bp2 = (unsigned short*)(ws + off); off += 2048;
  unsigned short* Bp3 = (unsigned short*)(ws + off); off += 2048;
  unsigned short* Bp4 = (unsigned short*)(ws + off); off += 2048;
  unsigned short* Bp5 = (unsigned short*)(ws + off); off += 2048;
  unsigned short* Bp6 = (unsigned short*)(ws + off); off += 1024;  // 2048 bf16
  int* deg    = (int*)(ws + off); off += N;
  int* rowptr = (int*)(ws + off); off += N + 1;
  int* wofs   = (int*)(ws + off); off += N;
  int* eorig  = (int*)(ws + off); off += E;
  int* srcp   = (int*)(ws + off); off += E;
  int* dstp   = (int*)(ws + off); off += E;
  int* bpart  = (int*)(ws + off); off += 256;
  int* bbase  = (int*)(ws + off); off += 256;

  float* node_out = (float*)d_out;
  float* edge_out = node_out + (size_t)N * 10;

  const int nb_n    = (N + 255) / 256;
  const int nb_e    = (E + 255) / 256;
  const int nb_a    = ((N * 16) + 255) / 256;
  const int nb_e128 = (E + 127) / 128;
  const int nb_n128 = (N + 127) / 128;
  const int PB      = (N + 255) / 256;

  k_prep<<<32, 256, 0, stream>>>(Wattn, Wg1, Wg2, Wnh, Wo, Wv, bv, bo, We2,
                                 Wvo, bvo, Bp1, Bp3, Bp4, Bp5, Bp6);
  k_prep2<<<16, 256, 0, stream>>>(Wvo, Bp2);
  k_zero<<<nb_n, 256, 0, stream>>>(deg, N);
  k_node_init<<<nb_n, 256, 0, stream>>>(node_logits, Wproj, bproj, nf16, N);
  k_deg<<<nb_e, 256, 0, stream>>>(ei, deg, E);
  k_part<<<PB, 256, 0, stream>>>(deg, bpart, N);
  k_scanpart<<<1, 256, 0, stream>>>(bpart, bbase, rowptr + N, PB);
  k_rowptr<<<PB, 256, 0, stream>>>(deg, bbase, rowptr, wofs, N);
  k_scatter<<<nb_e, 256, 0, stream>>>(ei, wofs, eorig, srcp, dstp, E);
  k_edge_init_mfma<<<nb_e128, 256, 0, stream>>>(edge_logits, We1, be1, Bp3, be2,
                                                eorig, ef16, E);

  // iteration 1
  k_edge_mfma<false><<<nb_e128, 256, 0, stream>>>(nf16, ef16, srcp, dstp, eorig,
                                                  Bp1, battn, Bp2, bvo,
                                                  Weh, beh, edge_out, E);
  k_node_agg<<<nb_a, 256, 0, stream>>>(nf16, ef16, srcp, rowptr, agg16, N);
  k_node_mlp<false><<<nb_n128, 256, 0, stream>>>(agg16, Bp4, bg1, Bp5, bg2,
                                                 Bp6, bnh, nf16, node_out, N);
  // iteration 2
  k_edge_mfma<true><<<nb_e128, 256, 0, stream>>>(nf16, ef16, srcp, dstp, eorig,
                                                 Bp1, battn, Bp2, bvo,
                                                 Weh, beh, edge_out, E);
  k_node_agg<<<nb_a, 256, 0, stream>>>(nf16, ef16, srcp, rowptr, agg16, N);
  k_node_mlp<true><<<nb_n128, 256, 0, stream>>>(agg16, Bp4, bg1, Bp5, bg2,
                                                Bp6, bnh, nf16, node_out, N);
}

// Round 10
// 423.430 us; speedup vs baseline: 14.2823x; 1.0493x over previous
//
#include <hip/hip_runtime.h>

#define HH 64

typedef __attribute__((ext_vector_type(8))) short bf16x8;
typedef __attribute__((ext_vector_type(16))) float f32x16;
typedef __attribute__((ext_vector_type(4))) unsigned short ushx4;
typedef __attribute__((ext_vector_type(4))) unsigned uintx4;
typedef __attribute__((ext_vector_type(2))) unsigned uintx2;

__device__ __forceinline__ unsigned short f2bf(float f) {
  unsigned u = __builtin_bit_cast(unsigned, f);
  return (unsigned short)((u + 0x7FFFu + ((u >> 16) & 1u)) >> 16);
}
__device__ __forceinline__ float bf2f(unsigned short h) {
  unsigned u = ((unsigned)h) << 16;
  return __builtin_bit_cast(float, u);
}
// single-instruction pack: lo -> bits[15:0], hi -> bits[31:16], RNE (== f2bf)
__device__ __forceinline__ unsigned pk2bf(float lo, float hi) {
  unsigned r;
  asm("v_cvt_pk_bf16_f32 %0, %1, %2" : "=v"(r) : "v"(lo), "v"(hi));
  return r;
}

// ---------- prep: Wvo = Wo@Wv, bvo = Wo@bv + bo, B-packs for We2/Wg1/Wg2/Wnh ----------
// EVEN/ODD B-fragment pack: tile t=0 -> even output features, t=1 -> odd.
//   n = 2*(ln&31) + t ; k = s*16 + (ln>>5)*8 + e8
__global__ __launch_bounds__(256) void k_prep(
    const float* __restrict__ Wg1, const float* __restrict__ Wg2,
    const float* __restrict__ Wnh, const float* __restrict__ Wo,
    const float* __restrict__ Wv,  const float* __restrict__ bv,
    const float* __restrict__ bo,  const float* __restrict__ We2,
    float* __restrict__ Wvo, float* __restrict__ bvo,
    unsigned short* __restrict__ Bp3, unsigned short* __restrict__ Bp4,
    unsigned short* __restrict__ Bp5, unsigned short* __restrict__ Bp6)
{
  int idx = blockIdx.x * 256 + threadIdx.x;
  if (idx < 4096) {                // Wvo[j][k] = sum_l Wo[j][l] Wv[l][k]
    int j = idx >> 6, k = idx & 63;
    float a = 0.f;
    #pragma unroll 4
    for (int l = 0; l < 64; ++l) a = fmaf(Wo[j * 64 + l], Wv[l * 64 + k], a);
    Wvo[idx] = a;
  }
  if (idx < 64) {                  // bvo[j] = sum_l Wo[j][l] bv[l] + bo[j]
    float a = bo[idx];
    for (int l = 0; l < 64; ++l) a = fmaf(Wo[idx * 64 + l], bv[l], a);
    bvo[idx] = a;
  }
  if (idx < 4096) {                // Bp3: We2, Bp4: Wg1, Bp5: Wg2 (K=64), even/odd
    int e8 = idx & 7, ln = (idx >> 3) & 63, t = (idx >> 9) & 1, s = idx >> 10;
    int n = 2 * (ln & 31) + t;
    int k = s * 16 + (ln >> 5) * 8 + e8;
    Bp3[idx] = f2bf(We2[n * 64 + k]);
    Bp4[idx] = f2bf(Wg1[n * 64 + k]);
    Bp5[idx] = f2bf(Wg2[n * 64 + k]);
  }
  if (idx < 2048) {                // Bp6: Wnh zero-padded (single tile, natural cols)
    int e8 = idx & 7, ln = (idx >> 3) & 63, s = idx >> 9;
    int n = ln & 31;
    int k = s * 16 + (ln >> 5) * 8 + e8;
    Bp6[idx] = (n < 10) ? f2bf(Wnh[n * 64 + k]) : (unsigned short)0;
  }
}

// ---------- prep2 (after k_prep): full linear edge-message fold ----------
// Wall = Wvo @ Wattn (64x128): msg = Wall @ [ns;nd] + ball,
// ball = Wvo @ battn + bvo. Packed directly into K=128 even/odd B-fragments.
__global__ __launch_bounds__(256) void k_prep2(
    const float* __restrict__ Wvo,  const float* __restrict__ bvo,
    const float* __restrict__ Wattn, const float* __restrict__ battn,
    unsigned short* __restrict__ Bpf, float* __restrict__ ball)
{
  int idx = blockIdx.x * 256 + threadIdx.x;
  if (idx < 8192) {                // Bpf[idx] = bf16(Wall[n][k]), even/odd pack
    int e8 = idx & 7, ln = (idx >> 3) & 63, t = (idx >> 9) & 1, s = idx >> 10;
    int n = 2 * (ln & 31) + t;
    int k = s * 16 + (ln >> 5) * 8 + e8;
    float a = 0.f;
    #pragma unroll 4
    for (int l = 0; l < 64; ++l)
      a = fmaf(Wvo[n * 64 + l], Wattn[l * 128 + k], a);
    Bpf[idx] = f2bf(a);
  }
  if (idx < 64) {
    float a = bvo[idx];
    for (int l = 0; l < 64; ++l) a = fmaf(Wvo[idx * 64 + l], battn[l], a);
    ball[idx] = a;
  }
}

// ---------- node init ----------
__global__ __launch_bounds__(256) void k_node_init(
    const float* __restrict__ nl, const float* __restrict__ Wproj,
    const float* __restrict__ bproj, unsigned short* __restrict__ nf16, int N)
{
  int i = blockIdx.x * 256 + threadIdx.x;
  if (i >= N) return;
  float x[10];
  #pragma unroll
  for (int k = 0; k < 10; ++k) x[k] = nl[(size_t)i * 10 + k];
  const size_t ib = (size_t)i * HH;
  #pragma unroll 1
  for (int j8 = 0; j8 < 8; ++j8) {
    float y[8];
    #pragma unroll
    for (int u = 0; u < 8; ++u) {
      int j = j8 * 8 + u;
      float a = bproj[j];
      #pragma unroll
      for (int k = 0; k < 10; ++k) a = fmaf(x[k], Wproj[j * 10 + k], a);
      y[u] = a;
    }
    uintx4 v = { pk2bf(y[0], y[1]), pk2bf(y[2], y[3]),
                 pk2bf(y[4], y[5]), pk2bf(y[6], y[7]) };
    *(uintx4*)(nf16 + ib + j8 * 8) = v;
  }
}

// ---------- CSR build ----------
__global__ __launch_bounds__(256) void k_zero(int* __restrict__ p, int n)
{
  int i = blockIdx.x * 256 + threadIdx.x;
  if (i < n) p[i] = 0;
}

__global__ __launch_bounds__(256) void k_deg(
    const int* __restrict__ ei, int* __restrict__ deg, int E)
{
  int e = blockIdx.x * 256 + threadIdx.x;
  if (e >= E) return;
  atomicAdd(&deg[ei[(size_t)E + e]], 1);
}

__global__ __launch_bounds__(256) void k_part(
    const int* __restrict__ deg, int* __restrict__ bpart, int N)
{
  __shared__ int s[256];
  int t = threadIdx.x;
  int i = blockIdx.x * 256 + t;
  s[t] = (i < N) ? deg[i] : 0;
  __syncthreads();
  #pragma unroll
  for (int o = 128; o > 0; o >>= 1) {
    if (t < o) s[t] += s[t + o];
    __syncthreads();
  }
  if (t == 0) bpart[blockIdx.x] = s[0];
}

__global__ __launch_bounds__(256) void k_scanpart(
    const int* __restrict__ bpart, int* __restrict__ bbase,
    int* __restrict__ rowptr_last, int PB)
{
  __shared__ int s[256];
  int t = threadIdx.x;
  int v = (t < PB) ? bpart[t] : 0;
  s[t] = v;
  __syncthreads();
  for (int o = 1; o < 256; o <<= 1) {
    int u = (t >= o) ? s[t - o] : 0;
    __syncthreads();
    s[t] += u;
    __syncthreads();
  }
  if (t < PB) bbase[t] = s[t] - v;
  if (t == 255) *rowptr_last = s[255];
}

__global__ __launch_bounds__(256) void k_rowptr(
    const int* __restrict__ deg, const int* __restrict__ bbase,
    int* __restrict__ rowptr, int* __restrict__ wofs, int N)
{
  __shared__ int s[256];
  int t = threadIdx.x;
  int i = blockIdx.x * 256 + t;
  int v = (i < N) ? deg[i] : 0;
  s[t] = v;
  __syncthreads();
  for (int o = 1; o < 256; o <<= 1) {
    int u = (t >= o) ? s[t - o] : 0;
    __syncthreads();
    s[t] += u;
    __syncthreads();
  }
  if (i < N) {
    int ex = bbase[blockIdx.x] + s[t] - v;
    rowptr[i] = ex;
    wofs[i]   = ex;
  }
}

__global__ __launch_bounds__(256) void k_scatter(
    const int* __restrict__ ei, int* __restrict__ wofs,
    int* __restrict__ eorig, int* __restrict__ srcp, int* __restrict__ dstp,
    int E)
{
  int e = blockIdx.x * 256 + threadIdx.x;
  if (e >= E) return;
  int src = ei[e];
  int dst = ei[(size_t)E + e];
  int pos = atomicAdd(&wofs[dst], 1);
  eorig[pos] = e;
  srcp[pos]  = src;
  dstp[pos]  = dst;
}

// ---------- edge init (CSR slot order, even/odd pack, u32 stores) ----------
__global__ __launch_bounds__(256) void k_edge_init_mfma(
    const float* __restrict__ el, const float* __restrict__ We1,
    const float* __restrict__ be1, const unsigned short* __restrict__ Bp3,
    const float* __restrict__ be2, const int* __restrict__ eorig,
    unsigned short* __restrict__ ef16, int E)
{
  const int tid   = threadIdx.x;
  const int wave  = tid >> 6;
  const int lane  = tid & 63;
  const int er    = lane & 31;
  const int kh    = lane >> 5;
  const int ebase = blockIdx.x * 128 + wave * 32;

  int p = ebase + er;
  if (p >= E) p = E - 1;
  const int eo = eorig[p];
  const float x0 = el[(size_t)eo * 5 + 0], x1 = el[(size_t)eo * 5 + 1],
              x2 = el[(size_t)eo * 5 + 2], x3 = el[(size_t)eo * 5 + 3],
              x4 = el[(size_t)eo * 5 + 4];

  bf16x8 afr[4];
  #pragma unroll
  for (int s = 0; s < 4; ++s) {
    float y[8];
    #pragma unroll
    for (int u = 0; u < 8; ++u) {
      const int k = s * 16 + kh * 8 + u;
      float a = be1[k];
      a = fmaf(x0, We1[k * 5 + 0], a);
      a = fmaf(x1, We1[k * 5 + 1], a);
      a = fmaf(x2, We1[k * 5 + 2], a);
      a = fmaf(x3, We1[k * 5 + 3], a);
      a = fmaf(x4, We1[k * 5 + 4], a);
      y[u] = fmaxf(a, 0.f);
    }
    uintx4 w = { pk2bf(y[0], y[1]), pk2bf(y[2], y[3]),
                 pk2bf(y[4], y[5]), pk2bf(y[6], y[7]) };
    afr[s] = __builtin_bit_cast(bf16x8, w);
  }

  f32x16 d0 = {0,0,0,0,0,0,0,0,0,0,0,0,0,0,0,0};
  f32x16 d1 = {0,0,0,0,0,0,0,0,0,0,0,0,0,0,0,0};
  #pragma unroll
  for (int s = 0; s < 4; ++s) {
    bf16x8 b0 = *(const bf16x8*)(Bp3 + (size_t)((s * 2 + 0) * 64 + lane) * 8);
    bf16x8 b1 = *(const bf16x8*)(Bp3 + (size_t)((s * 2 + 1) * 64 + lane) * 8);
    d0 = __builtin_amdgcn_mfma_f32_32x32x16_bf16(afr[s], b0, d0, 0, 0, 0);
    d1 = __builtin_amdgcn_mfma_f32_32x32x16_bf16(afr[s], b1, d1, 0, 0, 0);
  }

  const float b20 = be2[2 * er], b21 = be2[2 * er + 1];
  #pragma unroll
  for (int r = 0; r < 16; ++r) {
    const int m  = (r & 3) + 8 * (r >> 2) + 4 * kh;
    const int pg = ebase + m;
    if (pg < E)
      *((unsigned*)(ef16 + (size_t)pg * HH) + er) = pk2bf(d0[r] + b20, d1[r] + b21);
  }
}

// ---------- per-iteration edge pipeline: SINGLE fused GEMM (K=128) ----------
// msg = Wall @ [ns;nd] + ball  (edge MHA chain is linear -> prefolded).
// gather -> 16 MFMA -> streamed u32 RMW. LAST: fused edge head via LDS.
template <bool LAST>
__global__ __launch_bounds__(256) void k_edge_mfma(
    const unsigned short* __restrict__ nf16, unsigned short* __restrict__ ef16,
    const int* __restrict__ srcp, const int* __restrict__ dstp,
    const int* __restrict__ eorig,
    const unsigned short* __restrict__ Bpf, const float* __restrict__ ball,
    const float* __restrict__ Weh, const float* __restrict__ beh,
    float* __restrict__ edge_out, int E)
{
  __shared__ __align__(16) unsigned short c_lds[4 * 32 * 64];  // LAST only
  const int tid   = threadIdx.x;
  const int wave  = tid >> 6;
  const int lane  = tid & 63;
  const int er    = lane & 31;   // A row (slot) / D col pair base
  const int kh    = lane >> 5;
  const int ebase = blockIdx.x * 128 + wave * 32;

  int p = ebase + er;
  if (p >= E) p = E - 1;
  const int src = srcp[p];
  const int dst = dstp[p];
  const unsigned short* ns = nf16 + (size_t)src * HH;
  const unsigned short* nd = nf16 + (size_t)dst * HH;

  f32x16 acc0 = {0,0,0,0,0,0,0,0,0,0,0,0,0,0,0,0};
  f32x16 acc1 = {0,0,0,0,0,0,0,0,0,0,0,0,0,0,0,0};

  #pragma unroll
  for (int s = 0; s < 8; ++s) {
    const unsigned short* ap = (s < 4) ? ns : nd;
    bf16x8 a = *(const bf16x8*)(ap + (s & 3) * 16 + kh * 8);
    bf16x8 b0 = *(const bf16x8*)(Bpf + (size_t)((s * 2 + 0) * 64 + lane) * 8);
    bf16x8 b1 = *(const bf16x8*)(Bpf + (size_t)((s * 2 + 1) * 64 + lane) * 8);
    acc0 = __builtin_amdgcn_mfma_f32_32x32x16_bf16(a, b0, acc0, 0, 0, 0);
    acc1 = __builtin_amdgcn_mfma_f32_32x32x16_bf16(a, b1, acc1, 0, 0, 0);
  }

  // RMW: ef = relu(ef + msg), one u32 per lane per row (coalesced 128B/row)
  unsigned* cw32 = (unsigned*)(c_lds + wave * 2048);
  const float bt0 = ball[2 * er], bt1 = ball[2 * er + 1];
  #pragma unroll
  for (int r = 0; r < 16; ++r) {
    const int m  = (r & 3) + 8 * (r >> 2) + 4 * kh;
    const int eg = ebase + m;
    if (eg < E) {
      unsigned* prow = (unsigned*)(ef16 + (size_t)eg * HH) + er;
      unsigned old = *prow;
      float x0 = fmaxf(bf2f((unsigned short)(old & 0xffff)) + acc0[r] + bt0, 0.f);
      float x1 = fmaxf(bf2f((unsigned short)(old >> 16))    + acc1[r] + bt1, 0.f);
      unsigned q = pk2bf(x0, x1);
      *prow = q;
      if (LAST)
        cw32[m * 32 + (((er >> 2) ^ (m & 7)) << 2) + (er & 3)] = q;
    }
  }

  if (LAST) {
    // same-wave LDS producer->consumer (rule #18)
    asm volatile("s_waitcnt lgkmcnt(0)" ::: "memory");
    __builtin_amdgcn_sched_barrier(0);
    if (lane < 32) {
      const int eg = ebase + lane;
      if (eg < E) {
        const unsigned short* cw = c_lds + wave * 2048;
        float a0 = beh[0], a1 = beh[1], a2 = beh[2], a3 = beh[3], a4 = beh[4];
        const int l7 = lane & 7;
        #pragma unroll
        for (int f = 0; f < HH; ++f) {
          float x = bf2f(cw[lane * 64 + (((f >> 3) ^ l7) << 3) + (f & 7)]);
          a0 = fmaf(x, Weh[0 * HH + f], a0);
          a1 = fmaf(x, Weh[1 * HH + f], a1);
          a2 = fmaf(x, Weh[2 * HH + f], a2);
          a3 = fmaf(x, Weh[3 * HH + f], a3);
          a4 = fmaf(x, Weh[4 * HH + f], a4);
        }
        const int eo = eorig[eg];
        float* o = edge_out + (size_t)eo * 5;
        o[0] = a0; o[1] = a1; o[2] = a2; o[3] = a3; o[4] = a4;
      }
    }
  }
}

// ---------- node aggregation: sequential CSR rows, bf16 out ----------
__global__ __launch_bounds__(256) void k_node_agg(
    const unsigned short* __restrict__ nf16, const unsigned short* __restrict__ ef16,
    const int* __restrict__ srcp, const int* __restrict__ rowptr,
    unsigned short* __restrict__ agg16, int N)
{
  int gid = blockIdx.x * 256 + threadIdx.x;
  int i = gid >> 4;
  int l = gid & 15;
  if (i >= N) return;
  int b = rowptr[i];
  int t = rowptr[i + 1];
  const int fo = l * 4;
  ushx4 hv = *(const ushx4*)(nf16 + (size_t)i * HH + fo);
  float h0 = bf2f(hv[0]), h1 = bf2f(hv[1]), h2 = bf2f(hv[2]), h3 = bf2f(hv[3]);
  #pragma unroll 2
  for (int p = b; p < t; ++p) {
    int src = srcp[p];
    ushx4 ev = *(const ushx4*)(ef16 + (size_t)p * HH + fo);
    ushx4 sv = *(const ushx4*)(nf16 + (size_t)src * HH + fo);
    h0 += fmaxf(bf2f(sv[0]) + bf2f(ev[0]), 0.f);
    h1 += fmaxf(bf2f(sv[1]) + bf2f(ev[1]), 0.f);
    h2 += fmaxf(bf2f(sv[2]) + bf2f(ev[2]), 0.f);
    h3 += fmaxf(bf2f(sv[3]) + bf2f(ev[3]), 0.f);
  }
  uintx2 out = { pk2bf(h0, h1), pk2bf(h2, h3) };
  *(uintx2*)(agg16 + (size_t)i * HH + fo) = out;
}

// ---------- node MLP via MFMA (even/odd pack) ----------
template <bool LAST>
__global__ __launch_bounds__(256) void k_node_mlp(
    const unsigned short* __restrict__ agg16,
    const unsigned short* __restrict__ Bp4, const float* __restrict__ bg1,
    const unsigned short* __restrict__ Bp5, const float* __restrict__ bg2,
    const unsigned short* __restrict__ Bp6, const float* __restrict__ bnh,
    unsigned short* __restrict__ nf16, float* __restrict__ node_out, int N)
{
  __shared__ __align__(16) unsigned short c_lds[4 * 32 * 64];
  const int tid   = threadIdx.x;
  const int wave  = tid >> 6;
  const int lane  = tid & 63;
  const int er    = lane & 31;
  const int kh    = lane >> 5;
  const int nbase = blockIdx.x * 128 + wave * 32;
  if (nbase >= N) return;

  int node = nbase + er;
  if (node >= N) node = N - 1;
  const unsigned short* ar = agg16 + (size_t)node * HH;

  // GEMM g1 (K=64)
  f32x16 acc0 = {0,0,0,0,0,0,0,0,0,0,0,0,0,0,0,0};
  f32x16 acc1 = {0,0,0,0,0,0,0,0,0,0,0,0,0,0,0,0};
  #pragma unroll
  for (int s = 0; s < 4; ++s) {
    bf16x8 a = *(const bf16x8*)(ar + s * 16 + kh * 8);
    bf16x8 b0 = *(const bf16x8*)(Bp4 + (size_t)((s * 2 + 0) * 64 + lane) * 8);
    bf16x8 b1 = *(const bf16x8*)(Bp4 + (size_t)((s * 2 + 1) * 64 + lane) * 8);
    acc0 = __builtin_amdgcn_mfma_f32_32x32x16_bf16(a, b0, acc0, 0, 0, 0);
    acc1 = __builtin_amdgcn_mfma_f32_32x32x16_bf16(a, b1, acc1, 0, 0, 0);
  }

  // t1 = relu(acc + bg1) -> LDS u32 spill
  unsigned short* cw = c_lds + wave * 2048;
  unsigned* cw32 = (unsigned*)cw;
  const float bg10 = bg1[2 * er], bg11 = bg1[2 * er + 1];
  #pragma unroll
  for (int r = 0; r < 16; ++r) {
    const int m = (r & 3) + 8 * (r >> 2) + 4 * kh;
    unsigned q = pk2bf(fmaxf(acc0[r] + bg10, 0.f), fmaxf(acc1[r] + bg11, 0.f));
    cw32[m * 32 + (((er >> 2) ^ (m & 7)) << 2) + (er & 3)] = q;
  }
  asm volatile("s_waitcnt lgkmcnt(0)" ::: "memory");
  __builtin_amdgcn_sched_barrier(0);

  // GEMM g2
  f32x16 d0 = {0,0,0,0,0,0,0,0,0,0,0,0,0,0,0,0};
  f32x16 d1 = {0,0,0,0,0,0,0,0,0,0,0,0,0,0,0,0};
  #pragma unroll
  for (int s = 0; s < 4; ++s) {
    const int g = s * 2 + kh;
    bf16x8 a2 = *(const bf16x8*)(cw + er * 64 + ((g ^ (er & 7)) << 3));
    bf16x8 b0 = *(const bf16x8*)(Bp5 + (size_t)((s * 2 + 0) * 64 + lane) * 8);
    bf16x8 b1 = *(const bf16x8*)(Bp5 + (size_t)((s * 2 + 1) * 64 + lane) * 8);
    d0 = __builtin_amdgcn_mfma_f32_32x32x16_bf16(a2, b0, d0, 0, 0, 0);
    d1 = __builtin_amdgcn_mfma_f32_32x32x16_bf16(a2, b1, d1, 0, 0, 0);
  }

  const float bg20 = bg2[2 * er], bg21 = bg2[2 * er + 1];
  if (!LAST) {
    #pragma unroll
    for (int r = 0; r < 16; ++r) {
      const int m  = (r & 3) + 8 * (r >> 2) + 4 * kh;
      const int ng = nbase + m;
      if (ng < N) {
        unsigned q = pk2bf(fmaxf(d0[r] + bg20, 0.f), fmaxf(d1[r] + bg21, 0.f));
        *((unsigned*)(nf16 + (size_t)ng * HH) + er) = q;
      }
    }
  } else {
    // spill v -> LDS, head GEMM with zero-padded Wnh (natural col order)
    #pragma unroll
    for (int r = 0; r < 16; ++r) {
      const int m = (r & 3) + 8 * (r >> 2) + 4 * kh;
      unsigned q = pk2bf(fmaxf(d0[r] + bg20, 0.f), fmaxf(d1[r] + bg21, 0.f));
      cw32[m * 32 + (((er >> 2) ^ (m & 7)) << 2) + (er & 3)] = q;
    }
    asm volatile("s_waitcnt lgkmcnt(0)" ::: "memory");
    __builtin_amdgcn_sched_barrier(0);

    f32x16 hacc = {0,0,0,0,0,0,0,0,0,0,0,0,0,0,0,0};
    #pragma unroll
    for (int s = 0; s < 4; ++s) {
      const int g = s * 2 + kh;
      bf16x8 a2 = *(const bf16x8*)(cw + er * 64 + ((g ^ (er & 7)) << 3));
      bf16x8 b = *(const bf16x8*)(Bp6 + (size_t)(s * 64 + lane) * 8);
      hacc = __builtin_amdgcn_mfma_f32_32x32x16_bf16(a2, b, hacc, 0, 0, 0);
    }
    if (er < 10) {
      const float bn = bnh[er];
      #pragma unroll
      for (int r = 0; r < 16; ++r) {
        const int m  = (r & 3) + 8 * (r >> 2) + 4 * kh;
        const int ng = nbase + m;
        if (ng < N) node_out[(size_t)ng * 10 + er] = hacc[r] + bn;
      }
    }
  }
}

extern "C" void kernel_launch(void* const* d_in, const int* in_sizes, int n_in,
                              void* d_out, int out_size, void* d_ws, size_t ws_size,
                              hipStream_t stream)
{
  const float* node_logits = (const float*)d_in[0];
  const float* edge_logits = (const float*)d_in[1];
  const int*   ei          = (const int*)d_in[2];
  const float* Wproj = (const float*)d_in[3];
  const float* bproj = (const float*)d_in[4];
  const float* We1   = (const float*)d_in[5];
  const float* be1   = (const float*)d_in[6];
  const float* We2   = (const float*)d_in[7];
  const float* be2   = (const float*)d_in[8];
  const float* Wg1   = (const float*)d_in[9];
  const float* bg1   = (const float*)d_in[10];
  const float* Wg2   = (const float*)d_in[11];
  const float* bg2   = (const float*)d_in[12];
  const float* Wv    = (const float*)d_in[13];
  const float* bv    = (const float*)d_in[14];
  const float* Wo    = (const float*)d_in[15];
  const float* bo    = (const float*)d_in[16];
  const float* Wattn = (const float*)d_in[17];
  const float* battn = (const float*)d_in[18];
  const float* Wnh   = (const float*)d_in[19];
  const float* bnh   = (const float*)d_in[20];
  const float* Weh   = (const float*)d_in[21];
  const float* beh   = (const float*)d_in[22];

  const int N = in_sizes[0] / 10;
  const int E = in_sizes[1] / 5;

  float* ws = (float*)d_ws;
  size_t off = 0;
  unsigned short* nf16  = (unsigned short*)(ws + off); off += (size_t)N * (HH / 2);
  unsigned short* ef16  = (unsigned short*)(ws + off); off += (size_t)E * (HH / 2);
  unsigned short* agg16 = (unsigned short*)(ws + off); off += (size_t)N * (HH / 2);
  float* Wvo  = ws + off; off += 64 * 64;
  float* bvo  = ws + off; off += 64;
  float* ball = ws + off; off += 64;
  unsigned short* Bpf = (unsigned short*)(ws + off); off += 4096;  // 8192 bf16
  unsigned short* Bp3 = (unsigned short*)(ws + off); off += 2048;
  unsigned short* Bp4 = (unsigned short*)(ws + off); off += 2048;
  unsigned short* Bp5 = (unsigned short*)(ws + off); off += 2048;
  unsigned short* Bp6 = (unsigned short*)(ws + off); off += 1024;  // 2048 bf16
  int* deg    = (int*)(ws + off); off += N;
  int* rowptr = (int*)(ws + off); off += N + 1;
  int* wofs   = (int*)(ws + off); off += N;
  int* eorig  = (int*)(ws + off); off += E;
  int* srcp   = (int*)(ws + off); off += E;
  int* dstp   = (int*)(ws + off); off += E;
  int* bpart  = (int*)(ws + off); off += 256;
  int* bbase  = (int*)(ws + off); off += 256;

  float* node_out = (float*)d_out;
  float* edge_out = node_out + (size_t)N * 10;

  const int nb_n    = (N + 255) / 256;
  const int nb_e    = (E + 255) / 256;
  const int nb_a    = ((N * 16) + 255) / 256;
  const int nb_e128 = (E + 127) / 128;
  const int nb_n128 = (N + 127) / 128;
  const int PB      = (N + 255) / 256;

  k_prep<<<32, 256, 0, stream>>>(Wg1, Wg2, Wnh, Wo, Wv, bv, bo, We2,
                                 Wvo, bvo, Bp3, Bp4, Bp5, Bp6);
  k_prep2<<<32, 256, 0, stream>>>(Wvo, bvo, Wattn, battn, Bpf, ball);
  k_zero<<<nb_n, 256, 0, stream>>>(deg, N);
  k_node_init<<<nb_n, 256, 0, stream>>>(node_logits, Wproj, bproj, nf16, N);
  k_deg<<<nb_e, 256, 0, stream>>>(ei, deg, E);
  k_part<<<PB, 256, 0, stream>>>(deg, bpart, N);
  k_scanpart<<<1, 256, 0, stream>>>(bpart, bbase, rowptr + N, PB);
  k_rowptr<<<PB, 256, 0, stream>>>(deg, bbase, rowptr, wofs, N);
  k_scatter<<<nb_e, 256, 0, stream>>>(ei, wofs, eorig, srcp, dstp, E);
  k_edge_init_mfma<<<nb_e128, 256, 0, stream>>>(edge_logits, We1, be1, Bp3, be2,
                                                eorig, ef16, E);

  // iteration 1
  k_edge_mfma<false><<<nb_e128, 256, 0, stream>>>(nf16, ef16, srcp, dstp, eorig,
                                                  Bpf, ball, Weh, beh, edge_out, E);
  k_node_agg<<<nb_a, 256, 0, stream>>>(nf16, ef16, srcp, rowptr, agg16, N);
  k_node_mlp<false><<<nb_n128, 256, 0, stream>>>(agg16, Bp4, bg1, Bp5, bg2,
                                                 Bp6, bnh, nf16, node_out, N);
  // iteration 2
  k_edge_mfma<true><<<nb_e128, 256, 0, stream>>>(nf16, ef16, srcp, dstp, eorig,
                                                 Bpf, ball, Weh, beh, edge_out, E);
  k_node_agg<<<nb_a, 256, 0, stream>>>(nf16, ef16, srcp, rowptr, agg16, N);
  k_node_mlp<true><<<nb_n128, 256, 0, stream>>>(agg16, Bp4, bg1, Bp5, bg2,
                                                Bp6, bnh, nf16, node_out, N);
}

// Round 11
// 398.214 us; speedup vs baseline: 15.1867x; 1.0633x over previous
//
#include <hip/hip_runtime.h>

#define HH 64

typedef __attribute__((ext_vector_type(8))) short bf16x8;
typedef __attribute__((ext_vector_type(16))) float f32x16;
typedef __attribute__((ext_vector_type(4))) unsigned uintx4;

__device__ __forceinline__ unsigned short f2bf(float f) {
  unsigned u = __builtin_bit_cast(unsigned, f);
  return (unsigned short)((u + 0x7FFFu + ((u >> 16) & 1u)) >> 16);
}
__device__ __forceinline__ float bf2f(unsigned short h) {
  unsigned u = ((unsigned)h) << 16;
  return __builtin_bit_cast(float, u);
}
__device__ __forceinline__ unsigned pk2bf(float lo, float hi) {
  unsigned r;
  asm("v_cvt_pk_bf16_f32 %0, %1, %2" : "=v"(r) : "v"(lo), "v"(hi));
  return r;
}

// ---------- prep: Wvo = Wo@Wv, bvo = Wo@bv + bo, B-packs ----------
// EVEN/ODD pack: n = 2*(ln&31) + t ; k = s*16 + (ln>>5)*8 + e8
__global__ __launch_bounds__(256) void k_prep(
    const float* __restrict__ Wg1, const float* __restrict__ Wg2,
    const float* __restrict__ Wnh, const float* __restrict__ Wo,
    const float* __restrict__ Wv,  const float* __restrict__ bv,
    const float* __restrict__ bo,  const float* __restrict__ We2,
    float* __restrict__ Wvo, float* __restrict__ bvo,
    unsigned short* __restrict__ Bp3, unsigned short* __restrict__ Bp4,
    unsigned short* __restrict__ Bp5, unsigned short* __restrict__ Bp6)
{
  int idx = blockIdx.x * 256 + threadIdx.x;
  if (idx < 4096) {
    int j = idx >> 6, k = idx & 63;
    float a = 0.f;
    #pragma unroll 4
    for (int l = 0; l < 64; ++l) a = fmaf(Wo[j * 64 + l], Wv[l * 64 + k], a);
    Wvo[idx] = a;
  }
  if (idx < 64) {
    float a = bo[idx];
    for (int l = 0; l < 64; ++l) a = fmaf(Wo[idx * 64 + l], bv[l], a);
    bvo[idx] = a;
  }
  if (idx < 4096) {
    int e8 = idx & 7, ln = (idx >> 3) & 63, t = (idx >> 9) & 1, s = idx >> 10;
    int n = 2 * (ln & 31) + t;
    int k = s * 16 + (ln >> 5) * 8 + e8;
    Bp3[idx] = f2bf(We2[n * 64 + k]);
    Bp4[idx] = f2bf(Wg1[n * 64 + k]);
    Bp5[idx] = f2bf(Wg2[n * 64 + k]);
  }
  if (idx < 2048) {
    int e8 = idx & 7, ln = (idx >> 3) & 63, s = idx >> 9;
    int n = ln & 31;
    int k = s * 16 + (ln >> 5) * 8 + e8;
    Bp6[idx] = (n < 10) ? f2bf(Wnh[n * 64 + k]) : (unsigned short)0;
  }
}

// ---------- prep2: Wall = Wvo @ Wattn (K=128 pack), ball = Wvo@battn + bvo ----------
__global__ __launch_bounds__(256) void k_prep2(
    const float* __restrict__ Wvo,  const float* __restrict__ bvo,
    const float* __restrict__ Wattn, const float* __restrict__ battn,
    unsigned short* __restrict__ Bpf, float* __restrict__ ball)
{
  int idx = blockIdx.x * 256 + threadIdx.x;
  if (idx < 8192) {
    int e8 = idx & 7, ln = (idx >> 3) & 63, t = (idx >> 9) & 1, s = idx >> 10;
    int n = 2 * (ln & 31) + t;
    int k = s * 16 + (ln >> 5) * 8 + e8;
    float a = 0.f;
    #pragma unroll 4
    for (int l = 0; l < 64; ++l)
      a = fmaf(Wvo[n * 64 + l], Wattn[l * 128 + k], a);
    Bpf[idx] = f2bf(a);
  }
  if (idx < 64) {
    float a = bvo[idx];
    for (int l = 0; l < 64; ++l) a = fmaf(Wvo[idx * 64 + l], battn[l], a);
    ball[idx] = a;
  }
}

// ---------- node init: nf16 + agg(f32) = nl @ Wproj^T + bproj ----------
__global__ __launch_bounds__(256) void k_node_init(
    const float* __restrict__ nl, const float* __restrict__ Wproj,
    const float* __restrict__ bproj, unsigned short* __restrict__ nf16,
    float* __restrict__ agg, int N)
{
  int i = blockIdx.x * 256 + threadIdx.x;
  if (i >= N) return;
  float x[10];
  #pragma unroll
  for (int k = 0; k < 10; ++k) x[k] = nl[(size_t)i * 10 + k];
  const size_t ib = (size_t)i * HH;
  #pragma unroll 1
  for (int j8 = 0; j8 < 8; ++j8) {
    float y[8];
    #pragma unroll
    for (int u = 0; u < 8; ++u) {
      int j = j8 * 8 + u;
      float a = bproj[j];
      #pragma unroll
      for (int k = 0; k < 10; ++k) a = fmaf(x[k], Wproj[j * 10 + k], a);
      y[u] = a;
    }
    uintx4 v = { pk2bf(y[0], y[1]), pk2bf(y[2], y[3]),
                 pk2bf(y[4], y[5]), pk2bf(y[6], y[7]) };
    *(uintx4*)(nf16 + ib + j8 * 8) = v;
    float4 a0 = {y[0], y[1], y[2], y[3]};
    float4 a1 = {y[4], y[5], y[6], y[7]};
    *(float4*)(agg + ib + j8 * 8) = a0;
    *(float4*)(agg + ib + j8 * 8 + 4) = a1;
  }
}

// ---------- CSR build ----------
__global__ __launch_bounds__(256) void k_zero(int* __restrict__ p, int n)
{
  int i = blockIdx.x * 256 + threadIdx.x;
  if (i < n) p[i] = 0;
}

__global__ __launch_bounds__(256) void k_deg(
    const int* __restrict__ ei, int* __restrict__ deg, int E)
{
  int e = blockIdx.x * 256 + threadIdx.x;
  if (e >= E) return;
  atomicAdd(&deg[ei[(size_t)E + e]], 1);
}

__global__ __launch_bounds__(256) void k_part(
    const int* __restrict__ deg, int* __restrict__ bpart, int N)
{
  __shared__ int s[256];
  int t = threadIdx.x;
  int i = blockIdx.x * 256 + t;
  s[t] = (i < N) ? deg[i] : 0;
  __syncthreads();
  #pragma unroll
  for (int o = 128; o > 0; o >>= 1) {
    if (t < o) s[t] += s[t + o];
    __syncthreads();
  }
  if (t == 0) bpart[blockIdx.x] = s[0];
}

__global__ __launch_bounds__(256) void k_scanpart(
    const int* __restrict__ bpart, int* __restrict__ bbase,
    int* __restrict__ rowptr_last, int PB)
{
  __shared__ int s[256];
  int t = threadIdx.x;
  int v = (t < PB) ? bpart[t] : 0;
  s[t] = v;
  __syncthreads();
  for (int o = 1; o < 256; o <<= 1) {
    int u = (t >= o) ? s[t - o] : 0;
    __syncthreads();
    s[t] += u;
    __syncthreads();
  }
  if (t < PB) bbase[t] = s[t] - v;
  if (t == 255) *rowptr_last = s[255];
}

__global__ __launch_bounds__(256) void k_rowptr(
    const int* __restrict__ deg, const int* __restrict__ bbase,
    int* __restrict__ rowptr, int* __restrict__ wofs, int N)
{
  __shared__ int s[256];
  int t = threadIdx.x;
  int i = blockIdx.x * 256 + t;
  int v = (i < N) ? deg[i] : 0;
  s[t] = v;
  __syncthreads();
  for (int o = 1; o < 256; o <<= 1) {
    int u = (t >= o) ? s[t - o] : 0;
    __syncthreads();
    s[t] += u;
    __syncthreads();
  }
  if (i < N) {
    int ex = bbase[blockIdx.x] + s[t] - v;
    rowptr[i] = ex;
    wofs[i]   = ex;
  }
}

__global__ __launch_bounds__(256) void k_scatter(
    const int* __restrict__ ei, int* __restrict__ wofs,
    int* __restrict__ eorig, int* __restrict__ srcp, int* __restrict__ dstp,
    int E)
{
  int e = blockIdx.x * 256 + threadIdx.x;
  if (e >= E) return;
  int src = ei[e];
  int dst = ei[(size_t)E + e];
  int pos = atomicAdd(&wofs[dst], 1);
  eorig[pos] = e;
  srcp[pos]  = src;
  dstp[pos]  = dst;
}

// ---------- fused edge + aggregation kernel ----------
// FIRST: ef0 = We2-MLP(el) computed inline (8 MFMA into same acc; no ef read).
// Always: msg GEMM (16 MFMA, fused Wall), ef' = relu(base + acc + bias) -> store,
// m = relu(nf[src] + ef') -> LDS; block-level CSR-run reduction -> agg (f32).
// LAST: fused edge head edge_out = ef' @ Weh^T + beh.
template <bool FIRST, bool LAST>
__global__ __launch_bounds__(256) void k_edge_agg(
    const unsigned short* __restrict__ nf16, unsigned short* __restrict__ ef16,
    const int* __restrict__ srcp, const int* __restrict__ dstp,
    const int* __restrict__ eorig, const int* __restrict__ rowptr,
    const unsigned short* __restrict__ Bpf, const float* __restrict__ ball,
    const unsigned short* __restrict__ Bp3, const float* __restrict__ be2,
    const float* __restrict__ el, const float* __restrict__ We1,
    const float* __restrict__ be1,
    const float* __restrict__ Weh, const float* __restrict__ beh,
    float* __restrict__ edge_out, float* __restrict__ agg, int E)
{
  __shared__ unsigned m_lds[128][32];
  __shared__ __align__(16) unsigned short c_lds[LAST ? 4 * 32 * 64 : 4];
  const int tid    = threadIdx.x;
  const int wave   = tid >> 6;
  const int lane   = tid & 63;
  const int er     = lane & 31;
  const int kh     = lane >> 5;
  const int ebase0 = blockIdx.x * 128;
  const int ebase  = ebase0 + wave * 32;

  int p = ebase + er;
  if (p >= E) p = E - 1;
  const int src = srcp[p];
  const int dst = dstp[p];
  const unsigned short* ns = nf16 + (size_t)src * HH;
  const unsigned short* nd = nf16 + (size_t)dst * HH;

  f32x16 acc0 = {0,0,0,0,0,0,0,0,0,0,0,0,0,0,0,0};
  f32x16 acc1 = {0,0,0,0,0,0,0,0,0,0,0,0,0,0,0,0};

  if (FIRST) {
    // ef0 = relu(el@We1^T+be1) @ We2^T : layer1 VALU -> A-frags -> 8 MFMA
    const int eo = eorig[p];
    const float x0 = el[(size_t)eo * 5 + 0], x1 = el[(size_t)eo * 5 + 1],
                x2 = el[(size_t)eo * 5 + 2], x3 = el[(size_t)eo * 5 + 3],
                x4 = el[(size_t)eo * 5 + 4];
    #pragma unroll
    for (int s = 0; s < 4; ++s) {
      float y[8];
      #pragma unroll
      for (int u = 0; u < 8; ++u) {
        const int k = s * 16 + kh * 8 + u;
        float a = be1[k];
        a = fmaf(x0, We1[k * 5 + 0], a);
        a = fmaf(x1, We1[k * 5 + 1], a);
        a = fmaf(x2, We1[k * 5 + 2], a);
        a = fmaf(x3, We1[k * 5 + 3], a);
        a = fmaf(x4, We1[k * 5 + 4], a);
        y[u] = fmaxf(a, 0.f);
      }
      uintx4 w = { pk2bf(y[0], y[1]), pk2bf(y[2], y[3]),
                   pk2bf(y[4], y[5]), pk2bf(y[6], y[7]) };
      bf16x8 afr = __builtin_bit_cast(bf16x8, w);
      bf16x8 b0 = *(const bf16x8*)(Bp3 + (size_t)((s * 2 + 0) * 64 + lane) * 8);
      bf16x8 b1 = *(const bf16x8*)(Bp3 + (size_t)((s * 2 + 1) * 64 + lane) * 8);
      acc0 = __builtin_amdgcn_mfma_f32_32x32x16_bf16(afr, b0, acc0, 0, 0, 0);
      acc1 = __builtin_amdgcn_mfma_f32_32x32x16_bf16(afr, b1, acc1, 0, 0, 0);
    }
  }

  // msg GEMM: K=128 fused Wall (0-3 from ns, 4-7 from nd)
  #pragma unroll
  for (int s = 0; s < 8; ++s) {
    const unsigned short* ap = (s < 4) ? ns : nd;
    bf16x8 a = *(const bf16x8*)(ap + (s & 3) * 16 + kh * 8);
    bf16x8 b0 = *(const bf16x8*)(Bpf + (size_t)((s * 2 + 0) * 64 + lane) * 8);
    bf16x8 b1 = *(const bf16x8*)(Bpf + (size_t)((s * 2 + 1) * 64 + lane) * 8);
    acc0 = __builtin_amdgcn_mfma_f32_32x32x16_bf16(a, b0, acc0, 0, 0, 0);
    acc1 = __builtin_amdgcn_mfma_f32_32x32x16_bf16(a, b1, acc1, 0, 0, 0);
  }

  // epilogue: ef' = relu(base + acc + bias); store; m = relu(ns+ef') -> LDS
  unsigned* cw32 = (unsigned*)c_lds + wave * 1024;
  const float bt0 = ball[2 * er]     + (FIRST ? be2[2 * er]     : 0.f);
  const float bt1 = ball[2 * er + 1] + (FIRST ? be2[2 * er + 1] : 0.f);
  #pragma unroll
  for (int r = 0; r < 16; ++r) {
    const int m  = (r & 3) + 8 * (r >> 2) + 4 * kh;
    const int eg = ebase + m;
    if (eg < E) {
      float base0 = 0.f, base1 = 0.f;
      if (!FIRST) {
        unsigned old = *((const unsigned*)(ef16 + (size_t)eg * HH) + er);
        base0 = bf2f((unsigned short)(old & 0xffff));
        base1 = bf2f((unsigned short)(old >> 16));
      }
      float x0 = fmaxf(base0 + acc0[r] + bt0, 0.f);
      float x1 = fmaxf(base1 + acc1[r] + bt1, 0.f);
      unsigned q = pk2bf(x0, x1);
      *((unsigned*)(ef16 + (size_t)eg * HH) + er) = q;
      if (LAST)
        cw32[m * 32 + (((er >> 2) ^ (m & 7)) << 2) + (er & 3)] = q;
      // m = relu(nf[src_eg] + ef') ; broadcast row read, coalesced per half-wave
      const int se = srcp[eg];
      unsigned nsv = *((const unsigned*)(nf16 + (size_t)se * HH) + er);
      float m0 = fmaxf(bf2f((unsigned short)(nsv & 0xffff)) + x0, 0.f);
      float m1 = fmaxf(bf2f((unsigned short)(nsv >> 16))    + x1, 0.f);
      m_lds[wave * 32 + m][er] = pk2bf(m0, m1);
    }
  }

  if (LAST) {
    asm volatile("s_waitcnt lgkmcnt(0)" ::: "memory");
    __builtin_amdgcn_sched_barrier(0);
    if (lane < 32) {
      const int eg = ebase + lane;
      if (eg < E) {
        const unsigned short* cw = c_lds + wave * 2048;
        float a0 = beh[0], a1 = beh[1], a2 = beh[2], a3 = beh[3], a4 = beh[4];
        const int l7 = lane & 7;
        #pragma unroll
        for (int f = 0; f < HH; ++f) {
          float x = bf2f(cw[lane * 64 + (((f >> 3) ^ l7) << 3) + (f & 7)]);
          a0 = fmaf(x, Weh[0 * HH + f], a0);
          a1 = fmaf(x, Weh[1 * HH + f], a1);
          a2 = fmaf(x, Weh[2 * HH + f], a2);
          a3 = fmaf(x, Weh[3 * HH + f], a3);
          a4 = fmaf(x, Weh[4 * HH + f], a4);
        }
        const int eo2 = eorig[eg];
        float* o = edge_out + (size_t)eo2 * 5;
        o[0] = a0; o[1] = a1; o[2] = a2; o[3] = a3; o[4] = a4;
      }
    }
  }

  __syncthreads();

  // block reduction: CSR-contiguous dst runs over this block's 128 slots.
  // interior dst (all slots in-block) -> plain store nf+sum;
  // boundary dst -> atomicAdd partial (agg pre-initialized to nf).
  {
    const int g = tid >> 5;         // 8 groups
    const int l = tid & 31;         // feature pair 2l, 2l+1
    const int lastslot = min(ebase0 + 127, E - 1);
    const int i_lo = dstp[ebase0];
    const int i_hi = dstp[lastslot];
    for (int i = i_lo + g; i <= i_hi; i += 8) {
      const int rb = rowptr[i], re = rowptr[i + 1];
      const int lo = max(rb, ebase0);
      const int hi = min(re, ebase0 + 128);
      float s0 = 0.f, s1 = 0.f;
      for (int pp = lo; pp < hi; ++pp) {
        unsigned v = m_lds[pp - ebase0][l];
        s0 += bf2f((unsigned short)(v & 0xffff));
        s1 += bf2f((unsigned short)(v >> 16));
      }
      const bool interior = (rb >= ebase0) && (re <= ebase0 + 128);
      if (interior) {
        unsigned nv = *((const unsigned*)(nf16 + (size_t)i * HH) + l);
        float2 o = { bf2f((unsigned short)(nv & 0xffff)) + s0,
                     bf2f((unsigned short)(nv >> 16))    + s1 };
        *(float2*)(agg + (size_t)i * HH + 2 * l) = o;
      } else if (hi > lo) {
        atomicAdd(agg + (size_t)i * HH + 2 * l,     s0);
        atomicAdd(agg + (size_t)i * HH + 2 * l + 1, s1);
      }
    }
  }
}

// ---------- node MLP via MFMA (f32 agg input, even/odd pack) ----------
template <bool LAST>
__global__ __launch_bounds__(256) void k_node_mlp(
    const float* __restrict__ agg,
    const unsigned short* __restrict__ Bp4, const float* __restrict__ bg1,
    const unsigned short* __restrict__ Bp5, const float* __restrict__ bg2,
    const unsigned short* __restrict__ Bp6, const float* __restrict__ bnh,
    unsigned short* __restrict__ nf16, float* __restrict__ aggw,
    float* __restrict__ node_out, int N)
{
  __shared__ __align__(16) unsigned short c_lds[4 * 32 * 64];
  const int tid   = threadIdx.x;
  const int wave  = tid >> 6;
  const int lane  = tid & 63;
  const int er    = lane & 31;
  const int kh    = lane >> 5;
  const int nbase = blockIdx.x * 128 + wave * 32;
  if (nbase >= N) return;

  int node = nbase + er;
  if (node >= N) node = N - 1;
  const float* ar = agg + (size_t)node * HH;

  // GEMM g1 (K=64), A converted f32 -> bf16 fragments
  f32x16 acc0 = {0,0,0,0,0,0,0,0,0,0,0,0,0,0,0,0};
  f32x16 acc1 = {0,0,0,0,0,0,0,0,0,0,0,0,0,0,0,0};
  #pragma unroll
  for (int s = 0; s < 4; ++s) {
    float4 fa = *(const float4*)(ar + s * 16 + kh * 8);
    float4 fb = *(const float4*)(ar + s * 16 + kh * 8 + 4);
    uintx4 w = { pk2bf(fa.x, fa.y), pk2bf(fa.z, fa.w),
                 pk2bf(fb.x, fb.y), pk2bf(fb.z, fb.w) };
    bf16x8 a = __builtin_bit_cast(bf16x8, w);
    bf16x8 b0 = *(const bf16x8*)(Bp4 + (size_t)((s * 2 + 0) * 64 + lane) * 8);
    bf16x8 b1 = *(const bf16x8*)(Bp4 + (size_t)((s * 2 + 1) * 64 + lane) * 8);
    acc0 = __builtin_amdgcn_mfma_f32_32x32x16_bf16(a, b0, acc0, 0, 0, 0);
    acc1 = __builtin_amdgcn_mfma_f32_32x32x16_bf16(a, b1, acc1, 0, 0, 0);
  }

  // t1 = relu(acc + bg1) -> LDS u32 spill
  unsigned short* cw = c_lds + wave * 2048;
  unsigned* cw32 = (unsigned*)cw;
  const float bg10 = bg1[2 * er], bg11 = bg1[2 * er + 1];
  #pragma unroll
  for (int r = 0; r < 16; ++r) {
    const int m = (r & 3) + 8 * (r >> 2) + 4 * kh;
    unsigned q = pk2bf(fmaxf(acc0[r] + bg10, 0.f), fmaxf(acc1[r] + bg11, 0.f));
    cw32[m * 32 + (((er >> 2) ^ (m & 7)) << 2) + (er & 3)] = q;
  }
  asm volatile("s_waitcnt lgkmcnt(0)" ::: "memory");
  __builtin_amdgcn_sched_barrier(0);

  // GEMM g2
  f32x16 d0 = {0,0,0,0,0,0,0,0,0,0,0,0,0,0,0,0};
  f32x16 d1 = {0,0,0,0,0,0,0,0,0,0,0,0,0,0,0,0};
  #pragma unroll
  for (int s = 0; s < 4; ++s) {
    const int g = s * 2 + kh;
    bf16x8 a2 = *(const bf16x8*)(cw + er * 64 + ((g ^ (er & 7)) << 3));
    bf16x8 b0 = *(const bf16x8*)(Bp5 + (size_t)((s * 2 + 0) * 64 + lane) * 8);
    bf16x8 b1 = *(const bf16x8*)(Bp5 + (size_t)((s * 2 + 1) * 64 + lane) * 8);
    d0 = __builtin_amdgcn_mfma_f32_32x32x16_bf16(a2, b0, d0, 0, 0, 0);
    d1 = __builtin_amdgcn_mfma_f32_32x32x16_bf16(a2, b1, d1, 0, 0, 0);
  }

  const float bg20 = bg2[2 * er], bg21 = bg2[2 * er + 1];
  if (!LAST) {
    #pragma unroll
    for (int r = 0; r < 16; ++r) {
      const int m  = (r & 3) + 8 * (r >> 2) + 4 * kh;
      const int ng = nbase + m;
      if (ng < N) {
        float v0 = fmaxf(d0[r] + bg20, 0.f);
        float v1 = fmaxf(d1[r] + bg21, 0.f);
        *((unsigned*)(nf16 + (size_t)ng * HH) + er) = pk2bf(v0, v1);
        float2 o = { v0, v1 };
        *(float2*)(aggw + (size_t)ng * HH + 2 * er) = o;  // agg re-init for iter2
      }
    }
  } else {
    #pragma unroll
    for (int r = 0; r < 16; ++r) {
      const int m = (r & 3) + 8 * (r >> 2) + 4 * kh;
      unsigned q = pk2bf(fmaxf(d0[r] + bg20, 0.f), fmaxf(d1[r] + bg21, 0.f));
      cw32[m * 32 + (((er >> 2) ^ (m & 7)) << 2) + (er & 3)] = q;
    }
    asm volatile("s_waitcnt lgkmcnt(0)" ::: "memory");
    __builtin_amdgcn_sched_barrier(0);

    f32x16 hacc = {0,0,0,0,0,0,0,0,0,0,0,0,0,0,0,0};
    #pragma unroll
    for (int s = 0; s < 4; ++s) {
      const int g = s * 2 + kh;
      bf16x8 a2 = *(const bf16x8*)(cw + er * 64 + ((g ^ (er & 7)) << 3));
      bf16x8 b = *(const bf16x8*)(Bp6 + (size_t)(s * 64 + lane) * 8);
      hacc = __builtin_amdgcn_mfma_f32_32x32x16_bf16(a2, b, hacc, 0, 0, 0);
    }
    if (er < 10) {
      const float bn = bnh[er];
      #pragma unroll
      for (int r = 0; r < 16; ++r) {
        const int m  = (r & 3) + 8 * (r >> 2) + 4 * kh;
        const int ng = nbase + m;
        if (ng < N) node_out[(size_t)ng * 10 + er] = hacc[r] + bn;
      }
    }
  }
}

extern "C" void kernel_launch(void* const* d_in, const int* in_sizes, int n_in,
                              void* d_out, int out_size, void* d_ws, size_t ws_size,
                              hipStream_t stream)
{
  const float* node_logits = (const float*)d_in[0];
  const float* edge_logits = (const float*)d_in[1];
  const int*   ei          = (const int*)d_in[2];
  const float* Wproj = (const float*)d_in[3];
  const float* bproj = (const float*)d_in[4];
  const float* We1   = (const float*)d_in[5];
  const float* be1   = (const float*)d_in[6];
  const float* We2   = (const float*)d_in[7];
  const float* be2   = (const float*)d_in[8];
  const float* Wg1   = (const float*)d_in[9];
  const float* bg1   = (const float*)d_in[10];
  const float* Wg2   = (const float*)d_in[11];
  const float* bg2   = (const float*)d_in[12];
  const float* Wv    = (const float*)d_in[13];
  const float* bv    = (const float*)d_in[14];
  const float* Wo    = (const float*)d_in[15];
  const float* bo    = (const float*)d_in[16];
  const float* Wattn = (const float*)d_in[17];
  const float* battn = (const float*)d_in[18];
  const float* Wnh   = (const float*)d_in[19];
  const float* bnh   = (const float*)d_in[20];
  const float* Weh   = (const float*)d_in[21];
  const float* beh   = (const float*)d_in[22];

  const int N = in_sizes[0] / 10;
  const int E = in_sizes[1] / 5;

  float* ws = (float*)d_ws;
  size_t off = 0;
  unsigned short* nf16 = (unsigned short*)(ws + off); off += (size_t)N * (HH / 2);
  unsigned short* ef16 = (unsigned short*)(ws + off); off += (size_t)E * (HH / 2);
  float* agg  = ws + off; off += (size_t)N * HH;   // f32 now
  float* Wvo  = ws + off; off += 64 * 64;
  float* bvo  = ws + off; off += 64;
  float* ball = ws + off; off += 64;
  unsigned short* Bpf = (unsigned short*)(ws + off); off += 4096;  // 8192 bf16
  unsigned short* Bp3 = (unsigned short*)(ws + off); off += 2048;
  unsigned short* Bp4 = (unsigned short*)(ws + off); off += 2048;
  unsigned short* Bp5 = (unsigned short*)(ws + off); off += 2048;
  unsigned short* Bp6 = (unsigned short*)(ws + off); off += 1024;  // 2048 bf16
  int* deg    = (int*)(ws + off); off += N;
  int* rowptr = (int*)(ws + off); off += N + 1;
  int* wofs   = (int*)(ws + off); off += N;
  int* eorig  = (int*)(ws + off); off += E;
  int* srcp   = (int*)(ws + off); off += E;
  int* dstp   = (int*)(ws + off); off += E;
  int* bpart  = (int*)(ws + off); off += 256;
  int* bbase  = (int*)(ws + off); off += 256;

  float* node_out = (float*)d_out;
  float* edge_out = node_out + (size_t)N * 10;

  const int nb_n    = (N + 255) / 256;
  const int nb_e    = (E + 255) / 256;
  const int nb_e128 = (E + 127) / 128;
  const int nb_n128 = (N + 127) / 128;
  const int PB      = (N + 255) / 256;

  k_prep<<<32, 256, 0, stream>>>(Wg1, Wg2, Wnh, Wo, Wv, bv, bo, We2,
                                 Wvo, bvo, Bp3, Bp4, Bp5, Bp6);
  k_prep2<<<32, 256, 0, stream>>>(Wvo, bvo, Wattn, battn, Bpf, ball);
  k_zero<<<nb_n, 256, 0, stream>>>(deg, N);
  k_node_init<<<nb_n, 256, 0, stream>>>(node_logits, Wproj, bproj, nf16, agg, N);
  k_deg<<<nb_e, 256, 0, stream>>>(ei, deg, E);
  k_part<<<PB, 256, 0, stream>>>(deg, bpart, N);
  k_scanpart<<<1, 256, 0, stream>>>(bpart, bbase, rowptr + N, PB);
  k_rowptr<<<PB, 256, 0, stream>>>(deg, bbase, rowptr, wofs, N);
  k_scatter<<<nb_e, 256, 0, stream>>>(ei, wofs, eorig, srcp, dstp, E);

  // iteration 1 (edge-init fused; agg pre-initialized by k_node_init)
  k_edge_agg<true, false><<<nb_e128, 256, 0, stream>>>(
      nf16, ef16, srcp, dstp, eorig, rowptr, Bpf, ball, Bp3, be2,
      edge_logits, We1, be1, Weh, beh, edge_out, agg, E);
  k_node_mlp<false><<<nb_n128, 256, 0, stream>>>(agg, Bp4, bg1, Bp5, bg2,
                                                 Bp6, bnh, nf16, agg, node_out, N);
  // iteration 2 (agg re-initialized by k_node_mlp<false>)
  k_edge_agg<false, true><<<nb_e128, 256, 0, stream>>>(
      nf16, ef16, srcp, dstp, eorig, rowptr, Bpf, ball, Bp3, be2,
      edge_logits, We1, be1, Weh, beh, edge_out, agg, E);
  k_node_mlp<true><<<nb_n128, 256, 0, stream>>>(agg, Bp4, bg1, Bp5, bg2,
                                                Bp6, bnh, nf16, agg, node_out, N);
}